// Round 9
// baseline (589.267 us; speedup 1.0000x reference)
//
#include <hip/hip_runtime.h>
#include <hip/hip_bf16.h>

#define B 8
#define S 512
#define MM 64
#define T 576          // S + MM
#define H 768
#define NH 12
#define DH 64
#define FF 3072
#define E 512
#define NL 2

typedef __attribute__((ext_vector_type(8))) short bf16x8;
typedef __attribute__((ext_vector_type(4))) float f32x4;

__device__ inline unsigned short bf16_rne(float f) {
    unsigned u = __builtin_bit_cast(unsigned, f);
    unsigned r = u + 0x7FFFu + ((u >> 16) & 1u);
    return (unsigned short)(r >> 16);
}

__device__ inline f32x4 mfma16(bf16x8 a, bf16x8 b, f32x4 c) {
    return __builtin_amdgcn_mfma_f32_16x16x32_bf16(a, b, c, 0, 0, 0);
}

__device__ inline void load_lds16(const void* g, void* l) {
    __builtin_amdgcn_global_load_lds((const __attribute__((address_space(1))) void*)g,
                                     (__attribute__((address_space(3))) void*)l, 16, 0, 0);
}

// ---------------- order / argsort ----------------
__global__ void order_kernel(const int* __restrict__ mask, int* __restrict__ ord,
                             int* __restrict__ Larr) {
    __shared__ int ps[S];
    int b = blockIdx.x;
    int t = threadIdx.x;
    int mv = (mask[b * S + t] != 0) ? 1 : 0;
    ps[t] = mv;
    __syncthreads();
    for (int off = 1; off < S; off <<= 1) {
        int v = ps[t];
        int add = (t >= off) ? ps[t - off] : 0;
        __syncthreads();
        ps[t] = v + add;
        __syncthreads();
    }
    int L = ps[S - 1];
    int rank = mv ? (ps[t] - 1) : (L + (t - ps[t]));
    ord[b * S + rank] = t;
    if (t == 0) Larr[b] = L;
}

// ---------------- embedding + LN (writes f32 x and bf16 xb) ----------------
__global__ void embed_kernel(const int* __restrict__ ids, const int* __restrict__ toktype,
                             const int* __restrict__ ord, const int* __restrict__ Larr,
                             const float* __restrict__ word_emb, const float* __restrict__ pos_emb,
                             const float* __restrict__ type_emb, const float* __restrict__ memory,
                             const float* __restrict__ lns, const float* __restrict__ lnb,
                             float* __restrict__ x, unsigned short* __restrict__ xb,
                             int* __restrict__ ttarr) {
    int t = blockIdx.x;
    int b = blockIdx.y;
    int Lb = Larr[b];
    int tid = threadIdx.x;
    int tt;
    const float* src;
    if (t < Lb) {
        int sp = ord[b * S + t];
        tt = toktype[b * S + sp];
        src = &word_emb[(size_t)ids[b * S + sp] * H];
    } else if (t < Lb + MM) {
        tt = 1;
        src = &memory[(size_t)(t - Lb) * H];
    } else {
        int spp = t - MM;
        if (spp < 0) spp = 0;
        if (spp > S - 1) spp = S - 1;
        int sp = ord[b * S + spp];
        tt = 1;
        src = &word_emb[(size_t)ids[b * S + sp] * H];
    }
    __shared__ float row[H];
    __shared__ float r1[256], r2[256];
    float lsum = 0.f, lsq = 0.f;
    for (int hh = tid; hh < H; hh += 256) {
        float v = src[hh] + pos_emb[(size_t)t * H + hh] + type_emb[(size_t)tt * H + hh];
        row[hh] = v;
        lsum += v;
        lsq += v * v;
    }
    r1[tid] = lsum; r2[tid] = lsq;
    __syncthreads();
    for (int s = 128; s > 0; s >>= 1) {
        if (tid < s) { r1[tid] += r1[tid + s]; r2[tid] += r2[tid + s]; }
        __syncthreads();
    }
    float mu = r1[0] / H;
    float var = r2[0] / H - mu * mu;
    float inv = rsqrtf(var + 1e-12f);
    for (int hh = tid; hh < H; hh += 256) {
        float v = (row[hh] - mu) * inv * lns[hh] + lnb[hh];
        x[((size_t)b * T + t) * H + hh] = v;
        xb[((size_t)b * T + t) * H + hh] = bf16_rne(v);
    }
    if (tid == 0) ttarr[b * T + t] = tt;
}

// ---------------- activations ----------------
#define ACT_NONE 0
#define ACT_RELU 1
#define ACT_GELU 2
#define ACT_SIGMOID 3
#define ACT_TANH 4

template <int ACT>
__device__ inline float apply_act(float v) {
    if constexpr (ACT == ACT_RELU) return fmaxf(v, 0.f);
    else if constexpr (ACT == ACT_GELU) {
        // exact-form GELU with A-S 7.1.26 erf (|err| <= 1.5e-7), exp2-based
        float y = v * 0.70710678118654752f;
        float a = fabsf(y);
        float t = 1.f / (1.f + 0.3275911f * a);
        float poly = t * (0.254829592f + t * (-0.284496736f + t * (1.421413741f +
                     t * (-1.453152027f + t * 1.061405429f))));
        float e = poly * exp2f(-a * a * 1.4426950408889634f);
        float erfv = 1.f - e;
        erfv = (y < 0.f) ? -erfv : erfv;
        return 0.5f * v * (1.f + erfv);
    }
    else if constexpr (ACT == ACT_SIGMOID) return 1.f / (1.f + expf(-v));
    else if constexpr (ACT == ACT_TANH) return tanhf(v);
    else return v;
}

// ---------------- fused weight transpose set: W[K][N] f32 -> Wt[N][K] bf16 ----------------
struct TDesc { const float* src; unsigned dstoff; int Kd; int Nd; int tile0; };
struct TTab { TDesc d[10]; int n; };

__global__ __launch_bounds__(256) void transpose_all(TTab tab, unsigned short* __restrict__ dstbase) {
    int tile = blockIdx.x;
    int mi = 0;
    #pragma unroll
    for (int i = 1; i < 10; ++i)
        if (i < tab.n && tab.d[i].tile0 <= tile) mi = i;
    TDesc d = tab.d[mi];
    int rel = tile - d.tile0;
    int tilesK = d.Kd >> 5;
    int kt = rel % tilesK, nt = rel / tilesK;
    __shared__ float ts[32][33];
    int k0 = kt * 32, n0 = nt * 32;
    int tx = threadIdx.x & 31, ty = threadIdx.x >> 5;  // 32 x 8
    #pragma unroll
    for (int r = 0; r < 4; ++r) {
        int kk = ty + r * 8;
        ts[kk][tx] = d.src[(size_t)(k0 + kk) * d.Nd + n0 + tx];
    }
    __syncthreads();
    unsigned short* Wt = dstbase + d.dstoff;
    #pragma unroll
    for (int r = 0; r < 4; ++r) {
        int nn = ty + r * 8;
        Wt[(size_t)(n0 + nn) * d.Kd + k0 + tx] = bf16_rne(ts[tx][nn]);
    }
}

// ---------------- MFMA GEMM ----------------
// C[M,N] = act(A[M,K] @ Wt[N,K]^T + bias).  128x128 tile, BK=32, 4 waves,
// 2-deep LDS dbuf with counted vmcnt, bank swizzle, setprio.
// Block decode: m204 bijective XCD swizzle + COLUMN-MAJOR decode so each XCD
// owns few W-columns (L2-resident) and streams A via L3.
// NSPLIT=2: blockIdx.z halves K (z-plane counts are x8 so orig&7 unaffected).
#define EPI_F32   0
#define EPI_BF16  1
#define EPI_QKV   2
#define EPI_SPLIT2 3

template <int ACT, int EPI, int NSPLIT>
__global__ __launch_bounds__(256) void mfma_gemm(
    const unsigned short* __restrict__ A, const unsigned short* __restrict__ Bt,
    const float* __restrict__ b0, const float* __restrict__ b1, const float* __restrict__ b2,
    int sp1, int sp2,
    float* __restrict__ Cf, float* __restrict__ Cf2,
    unsigned short* __restrict__ Cb, unsigned short* __restrict__ Cb2,
    unsigned short* __restrict__ Vt, int n2w,
    int Mdim, int Ndim, int Kdim) {
    __shared__ unsigned short As[2][128 * 32];
    __shared__ unsigned short Bs[2][128 * 32];

    // bijective XCD swizzle (m204) + column-major decode
    const int gx = gridDim.x, gy = gridDim.y;
    const int nwg = gx * gy;
    int orig = blockIdx.y * gx + blockIdx.x;
    int q = nwg >> 3, r8 = nwg & 7;
    int xcd = orig & 7, idx = orig >> 3;
    int swz = (xcd < r8 ? xcd * (q + 1) : r8 * (q + 1) + (xcd - r8) * q) + idx;
    const int bn = (swz / gy) * 128, bm = (swz % gy) * 128;   // col-major: W-cols stay in XCD L2

    const int z = (NSPLIT > 1) ? blockIdx.z : 0;
    const int Klocal = Kdim / NSPLIT;
    const int koff = z * Klocal;

    const int tid = threadIdx.x;
    const int w = tid >> 6, lane = tid & 63;
    const int lr = lane & 15, g = lane >> 4;
    const int wr = w >> 1, wc = w & 1;
    f32x4 acc[4][4] = {};

    const int srow = w * 32 + (lane >> 2);
    const int kc = (((lane & 3) ^ ((lane >> 4) & 3)) * 8);
    const unsigned short* ga0 = A + (size_t)(bm + srow) * Kdim + kc;
    const unsigned short* ga1 = A + (size_t)(bm + srow + 16) * Kdim + kc;
    const unsigned short* gb0 = Bt + (size_t)(bn + srow) * Kdim + kc;
    const unsigned short* gb1 = Bt + (size_t)(bn + srow + 16) * Kdim + kc;
    const int d0 = (w * 32) * 32, d1 = (w * 32 + 16) * 32;

    const int sw = ((g ^ ((lr >> 2) & 3)) & 3) * 8;

    auto stage = [&](int pp, int k0) {
        load_lds16(ga0 + k0, &As[pp][d0]);
        load_lds16(ga1 + k0, &As[pp][d1]);
        load_lds16(gb0 + k0, &Bs[pp][d0]);
        load_lds16(gb1 + k0, &Bs[pp][d1]);
    };
    auto compute = [&](int pp) {
        bf16x8 af[4], bfr[4];
        #pragma unroll
        for (int i = 0; i < 4; ++i)
            af[i] = *(const bf16x8*)&As[pp][(wr * 64 + i * 16 + lr) * 32 + sw];
        #pragma unroll
        for (int j = 0; j < 4; ++j)
            bfr[j] = *(const bf16x8*)&Bs[pp][(wc * 64 + j * 16 + lr) * 32 + sw];
        __builtin_amdgcn_s_setprio(1);
        #pragma unroll
        for (int i = 0; i < 4; ++i)
            #pragma unroll
            for (int j = 0; j < 4; ++j)
                acc[i][j] = mfma16(af[i], bfr[j], acc[i][j]);
        __builtin_amdgcn_s_setprio(0);
    };

    const int nk = Klocal >> 5;
    stage(0, koff);
    int p = 0;
    for (int s = 0; s < nk; ++s) {
        if (s + 1 < nk) {
            stage(p ^ 1, koff + (s + 1) * 32);
            asm volatile("s_waitcnt vmcnt(4)" ::: "memory");
        } else {
            asm volatile("s_waitcnt vmcnt(0)" ::: "memory");
        }
        __builtin_amdgcn_s_barrier();
        __builtin_amdgcn_sched_barrier(0);
        compute(p);
        __builtin_amdgcn_sched_barrier(0);
        __builtin_amdgcn_s_barrier();
        __builtin_amdgcn_sched_barrier(0);
        p ^= 1;
    }

    float* Cdst = (NSPLIT > 1 && z == 1) ? Cf2 : Cf;
    #pragma unroll
    for (int i = 0; i < 4; ++i) {
        const int row0 = bm + wr * 64 + i * 16 + 4 * g;
        #pragma unroll
        for (int j = 0; j < 4; ++j) {
            const int col = bn + wc * 64 + j * 16 + lr;
            float bv = (NSPLIT > 1 && z == 1) ? 0.f
                     : ((col < sp1) ? b0[col] : (col < sp2 ? b1[col - sp1] : b2[col - sp2]));
            float vv[4];
            #pragma unroll
            for (int r = 0; r < 4; ++r) vv[r] = apply_act<ACT>(acc[i][j][r] + bv);
            if constexpr (EPI == EPI_F32) {
                #pragma unroll
                for (int r = 0; r < 4; ++r) Cdst[(size_t)(row0 + r) * Ndim + col] = vv[r];
            } else if constexpr (EPI == EPI_BF16) {
                #pragma unroll
                for (int r = 0; r < 4; ++r) Cb[(size_t)(row0 + r) * Ndim + col] = bf16_rne(vv[r]);
            } else if constexpr (EPI == EPI_QKV) {
                if (col < 1536) {
                    #pragma unroll
                    for (int r = 0; r < 4; ++r) Cb[(size_t)(row0 + r) * 1536 + col] = bf16_rne(vv[r]);
                } else {
                    int c2 = col - 1536;
                    int bb = row0 / T, t0 = row0 % T;
                    int hh2 = c2 >> 6, dd = c2 & 63;
                    unsigned lo = (unsigned)bf16_rne(vv[0]) | ((unsigned)bf16_rne(vv[1]) << 16);
                    unsigned hi = (unsigned)bf16_rne(vv[2]) | ((unsigned)bf16_rne(vv[3]) << 16);
                    size_t idxv = (((size_t)bb * NH + hh2) * DH + dd) * T + t0;
                    *(uint2*)&Vt[idxv] = make_uint2(lo, hi);
                }
            } else {  // EPI_SPLIT2
                if (col < sp1) {
                    #pragma unroll
                    for (int r = 0; r < 4; ++r) Cb[(size_t)(row0 + r) * sp1 + col] = bf16_rne(vv[r]);
                } else {
                    #pragma unroll
                    for (int r = 0; r < 4; ++r)
                        Cb2[(size_t)(row0 + r) * n2w + (col - sp1)] = bf16_rne(vv[r]);
                }
            }
        }
    }
}

// ---------------- MFMA flash attention ----------------
#define C2 0.180336880111116670f      // 0.125 * log2(e)
#define MB2 14426.950408889634f       // 10000 * log2(e)

__global__ __launch_bounds__(256) void attn_mfma(
    const unsigned short* __restrict__ QK, const unsigned short* __restrict__ Vt,
    const int* __restrict__ Larr, unsigned short* __restrict__ ctxb) {
    const int n = blockIdx.x;
    const int xcd = n & 7, k = n >> 3;
    const int p = xcd * 12 + k / 9, qt = k % 9;
    const int b = p / NH, h = p % NH;
    const int w = threadIdx.x >> 6, lane = threadIdx.x & 63;
    const int q0 = qt * 64 + w * 16;
    const int lr = lane & 15, g = lane >> 4;
    const int LbMM = Larr[b] + MM;
    const int ktend = min(T, (LbMM + 63) & ~63);
    __shared__ unsigned short P[4][16][72];
    const unsigned short* qrow = QK + (size_t)(b * T + q0 + lr) * 1536 + h * 64;
    bf16x8 qf0 = *(const bf16x8*)(qrow + 8 * g);
    bf16x8 qf1 = *(const bf16x8*)(qrow + 32 + 8 * g);
    f32x4 ctx[4] = {};
    float m_run = -1e30f, l_run = 0.f;
    const size_t vbase = ((size_t)b * NH + h) * DH;
    for (int kt = 0; kt < ktend; kt += 64) {
        f32x4 sf[4];
        #pragma unroll
        for (int i = 0; i < 4; ++i) {
            const unsigned short* krow =
                QK + (size_t)(b * T + kt + 16 * i + lr) * 1536 + 768 + h * 64;
            bf16x8 kf0 = *(const bf16x8*)(krow + 8 * g);
            bf16x8 kf1 = *(const bf16x8*)(krow + 32 + 8 * g);
            f32x4 s = {};
            s = mfma16(kf0, qf0, s);
            s = mfma16(kf1, qf1, s);
            sf[i] = s;
        }
        float tmax = -1e30f;
        #pragma unroll
        for (int i = 0; i < 4; ++i)
            #pragma unroll
            for (int r = 0; r < 4; ++r) {
                int key = kt + 16 * i + 4 * g + r;
                float v = sf[i][r] * C2 + (key < LbMM ? 0.f : -MB2);
                sf[i][r] = v;
                tmax = fmaxf(tmax, v);
            }
        tmax = fmaxf(tmax, __shfl_xor(tmax, 16));
        tmax = fmaxf(tmax, __shfl_xor(tmax, 32));
        float m_new = fmaxf(m_run, tmax);
        float scale = exp2f(m_run - m_new);
        m_run = m_new;
        float psum = 0.f;
        #pragma unroll
        for (int i = 0; i < 4; ++i)
            #pragma unroll
            for (int r = 0; r < 4; ++r) {
                float pv = exp2f(sf[i][r] - m_new);
                sf[i][r] = pv;
                psum += pv;
            }
        l_run = l_run * scale + psum;
        float f0 = __shfl(scale, 4 * g + 0);
        float f1 = __shfl(scale, 4 * g + 1);
        float f2 = __shfl(scale, 4 * g + 2);
        float f3 = __shfl(scale, 4 * g + 3);
        #pragma unroll
        for (int j = 0; j < 4; ++j) {
            ctx[j][0] *= f0; ctx[j][1] *= f1; ctx[j][2] *= f2; ctx[j][3] *= f3;
        }
        #pragma unroll
        for (int i = 0; i < 4; ++i) {
            unsigned lo = (unsigned)bf16_rne(sf[i][0]) | ((unsigned)bf16_rne(sf[i][1]) << 16);
            unsigned hi = (unsigned)bf16_rne(sf[i][2]) | ((unsigned)bf16_rne(sf[i][3]) << 16);
            *(unsigned*)&P[w][lr][16 * i + 4 * g] = lo;
            *(unsigned*)&P[w][lr][16 * i + 4 * g + 2] = hi;
        }
        asm volatile("s_waitcnt lgkmcnt(0)" ::: "memory");
        __builtin_amdgcn_sched_barrier(0);
        #pragma unroll
        for (int s2 = 0; s2 < 2; ++s2) {
            bf16x8 pa = *(const bf16x8*)&P[w][lr][32 * s2 + 8 * g];
            #pragma unroll
            for (int j = 0; j < 4; ++j) {
                const unsigned short* vrow =
                    Vt + (vbase + 16 * j + lr) * T + kt + 32 * s2 + 8 * g;
                bf16x8 vf = *(const bf16x8*)vrow;
                ctx[j] = mfma16(pa, vf, ctx[j]);
            }
        }
        asm volatile("s_waitcnt lgkmcnt(0)" ::: "memory");
        __builtin_amdgcn_sched_barrier(0);
    }
    l_run += __shfl_xor(l_run, 16);
    l_run += __shfl_xor(l_run, 32);
    float inv = 1.f / l_run;
    float i0 = __shfl(inv, 4 * g + 0);
    float i1 = __shfl(inv, 4 * g + 1);
    float i2 = __shfl(inv, 4 * g + 2);
    float i3 = __shfl(inv, 4 * g + 3);
    float sc[4] = {i0, i1, i2, i3};
    #pragma unroll
    for (int j = 0; j < 4; ++j)
        #pragma unroll
        for (int r = 0; r < 4; ++r)
            ctxb[(size_t)(b * T + q0 + 4 * g + r) * H + h * 64 + 16 * j + lr] =
                bf16_rne(ctx[j][r] * sc[r]);
}

// ---------------- residual + LN (delta = d1 + d2), float4-vectorized ----------------
__global__ void lnres_kernel(float* __restrict__ x, const float* __restrict__ d1,
                             const float* __restrict__ d2,
                             const float* __restrict__ s, const float* __restrict__ bvec,
                             unsigned short* __restrict__ xb) {
    int r = blockIdx.x;
    int tid = threadIdx.x;
    __shared__ float4 row[H / 4];
    __shared__ float r1[256], r2[256];
    float lsum = 0.f, lsq = 0.f;
    size_t off4 = (size_t)r * (H / 4);
    const float4* x4 = (const float4*)x;
    const float4* d14 = (const float4*)d1;
    const float4* d24 = (const float4*)d2;
    if (tid < H / 4) {
        float4 a = x4[off4 + tid], bb = d14[off4 + tid], cc = d24[off4 + tid];
        float4 v = make_float4(a.x + bb.x + cc.x, a.y + bb.y + cc.y,
                               a.z + bb.z + cc.z, a.w + bb.w + cc.w);
        row[tid] = v;
        lsum = v.x + v.y + v.z + v.w;
        lsq = v.x * v.x + v.y * v.y + v.z * v.z + v.w * v.w;
    }
    r1[tid] = lsum; r2[tid] = lsq;
    __syncthreads();
    for (int ss = 128; ss > 0; ss >>= 1) {
        if (tid < ss) { r1[tid] += r1[tid + ss]; r2[tid] += r2[tid + ss]; }
        __syncthreads();
    }
    float mu = r1[0] / H;
    float var = r2[0] / H - mu * mu;
    float inv = rsqrtf(var + 1e-12f);
    if (tid < H / 4) {
        float4 v = row[tid];
        const float4 sv = ((const float4*)s)[tid];
        const float4 bv = ((const float4*)bvec)[tid];
        float4 o = make_float4((v.x - mu) * inv * sv.x + bv.x,
                               (v.y - mu) * inv * sv.y + bv.y,
                               (v.z - mu) * inv * sv.z + bv.z,
                               (v.w - mu) * inv * sv.w + bv.w);
        ((float4*)x)[off4 + tid] = o;
        ushort4 ob = make_ushort4(bf16_rne(o.x), bf16_rne(o.y), bf16_rne(o.z), bf16_rne(o.w));
        *(ushort4*)&xb[(size_t)r * H + tid * 4] = ob;
    }
}

// ---------------- masked softmax pooling (sigmoid applied here; w = sigma(w0+w1)) ----------------
__global__ __launch_bounds__(256) void pool_kernel(
    const float* __restrict__ w0, const float* __restrict__ w1,
    const float* __restrict__ value,
    const int* __restrict__ ttarr, float* __restrict__ out) {
    int b = blockIdx.x;
    int le = threadIdx.x & 31;
    int e = blockIdx.y * 32 + le;
    int tg = threadIdx.x >> 5;  // 0..7
    __shared__ int ttl[T];
    __shared__ float red[8][33];
    for (int t = threadIdx.x; t < T; t += 256) ttl[t] = ttarr[b * T + t];
    __syncthreads();
    float mx = -1e30f;
    for (int t = tg; t < T; t += 8) {
        if (ttl[t] == 1) continue;
        size_t idx = ((size_t)b * T + t) * E + e;
        float w = 1.f / (1.f + expf(-(w0[idx] + w1[idx])));
        mx = fmaxf(mx, w);
    }
    red[tg][le] = mx;
    __syncthreads();
    #pragma unroll
    for (int i = 0; i < 8; ++i) mx = fmaxf(mx, red[i][le]);
    float den = 0.f, num = 0.f;
    for (int t = tg; t < T; t += 8) {
        if (ttl[t] == 1) continue;
        size_t idx = ((size_t)b * T + t) * E + e;
        float w = 1.f / (1.f + expf(-(w0[idx] + w1[idx])));
        float ew = expf(w - mx);
        den += ew;
        num = fmaf(ew, value[idx], num);
    }
    __syncthreads();
    red[tg][le] = den;
    __syncthreads();
    float dtot = 0.f;
    #pragma unroll
    for (int i = 0; i < 8; ++i) dtot += red[i][le];
    __syncthreads();
    red[tg][le] = num;
    __syncthreads();
    float ntot = 0.f;
    #pragma unroll
    for (int i = 0; i < 8; ++i) ntot += red[i][le];
    if (tg == 0) out[(size_t)b * E + e] = fmaxf(ntot / dtot, 0.f);
}

// ---------------- host-side launch ----------------
extern "C" void kernel_launch(void* const* d_in, const int* in_sizes, int n_in,
                              void* d_out, int out_size, void* d_ws, size_t ws_size,
                              hipStream_t stream) {
    const int*   input_ids  = (const int*)d_in[0];
    const int*   token_type = (const int*)d_in[1];
    const int*   attn_mask  = (const int*)d_in[2];
    const float* word_emb   = (const float*)d_in[3];
    const float* pos_emb    = (const float*)d_in[4];
    const float* type_emb   = (const float*)d_in[5];
    const float* emb_ln_s   = (const float*)d_in[6];
    const float* emb_ln_b   = (const float*)d_in[7];
    const float* memory     = (const float*)d_in[8];
    const float* q_w  = (const float*)d_in[9];
    const float* q_b  = (const float*)d_in[10];
    const float* k_w  = (const float*)d_in[11];
    const float* k_b  = (const float*)d_in[12];
    const float* v_w  = (const float*)d_in[13];
    const float* v_b  = (const float*)d_in[14];
    const float* o_w  = (const float*)d_in[15];
    const float* o_b  = (const float*)d_in[16];
    const float* ln1_s = (const float*)d_in[17];
    const float* ln1_b = (const float*)d_in[18];
    const float* f_w1  = (const float*)d_in[19];
    const float* f_b1  = (const float*)d_in[20];
    const float* f_w2  = (const float*)d_in[21];
    const float* f_b2  = (const float*)d_in[22];
    const float* ln2_s = (const float*)d_in[23];
    const float* ln2_b = (const float*)d_in[24];
    const float* key_w1 = (const float*)d_in[25];
    const float* key_b1 = (const float*)d_in[26];
    const float* key_w2 = (const float*)d_in[27];
    const float* key_b2 = (const float*)d_in[28];
    const float* val_w1 = (const float*)d_in[29];
    const float* val_b1 = (const float*)d_in[30];
    const float* val_w2 = (const float*)d_in[31];
    const float* val_b2 = (const float*)d_in[32];
    float* out = (float*)d_out;

    char* ws = (char*)d_ws;
    size_t off = 0;
    auto alloc = [&](size_t bytes) {
        void* p = ws + off;
        off += (bytes + 255) & ~(size_t)255;
        return p;
    };
    const size_t BT  = (size_t)B * T;      // 4608
    const size_t BTH = BT * H;             // 3538944

    int*   ord   = (int*)alloc((size_t)B * S * 4);
    int*   Larr  = (int*)alloc(64);
    int*   ttarr = (int*)alloc(BT * 4);
    float* x     = (float*)alloc(BTH * 4);
    unsigned short* xb   = (unsigned short*)alloc(BTH * 2);
    unsigned short* reg1 = (unsigned short*)alloc(BT * FF * 2);
    float* Bbuf  = (float*)alloc(BTH * 4);     // split-K partial z0
    float* part1 = (float*)alloc(BTH * 4);     // split-K partial z1
    // wt: per-layer region (7,077,888) + head region (3,276,800)
    unsigned short* wt = (unsigned short*)alloc((size_t)10354688 * 2);

    unsigned short* qkb  = reg1;                       // [BT][1536]
    unsigned short* Vtb  = reg1 + BT * 1536;           // [B][NH][DH][T]
    unsigned short* ctxb = reg1 + BT * 1536 + BTH;     // [BT][H]
    unsigned short* hb   = reg1;                       // [BT][FF] (FFN phase)
    unsigned short* key1b = reg1;                      // [BT][1536] (head phase)
    unsigned short* val1b = reg1 + BT * 1536;          // [BT][1024]
    float* valf = x;                                   // [BT][512] f32 (x dead by then)

    unsigned short* wt_qkv = wt;                       // [2304][768] (q|k|v)
    unsigned short* wt_o  = wt + (size_t)2304 * 768;   // [768][768]
    unsigned short* wt_f1 = wt_o + (size_t)768 * 768;  // [3072][768]
    unsigned short* wt_f2 = wt_f1 + (size_t)3072 * 768;// [768][3072]
    unsigned short* wt_head = wt + (size_t)7077888;    // head region
    unsigned short* wt_kv1 = wt_head;                  // [2560][768] (key1|val1)
    unsigned short* wt_k2 = wt_head + (size_t)2560 * 768;   // [512][1536]
    unsigned short* wt_v2 = wt_k2 + (size_t)512 * 1536;     // [512][1024]

    const int Mrows = (int)BT;  // 4608
    const size_t HH = (size_t)H * H;
    const int BIG = 1 << 30;

    hipLaunchKernelGGL(order_kernel, dim3(B), dim3(S), 0, stream, attn_mask, ord, Larr);
    hipLaunchKernelGGL(embed_kernel, dim3(T, B), dim3(256), 0, stream,
                       input_ids, token_type, ord, Larr, word_emb, pos_emb, type_emb,
                       memory, emb_ln_s, emb_ln_b, x, xb, ttarr);

    for (int l = 0; l < NL; ++l) {
        TTab tab;
        tab.d[0] = { q_w + l * HH,              0u,                              H,  H,  0    };
        tab.d[1] = { k_w + l * HH,              (unsigned)(768 * 768),           H,  H,  576  };
        tab.d[2] = { v_w + l * HH,              (unsigned)(1536 * 768),          H,  H,  1152 };
        tab.d[3] = { o_w + l * HH,              (unsigned)(2304 * 768),          H,  H,  1728 };
        tab.d[4] = { f_w1 + (size_t)l * H * FF, (unsigned)(3072 * 768),          H,  FF, 2304 };
        tab.d[5] = { f_w2 + (size_t)l * FF * H, (unsigned)(6144 * 768),          FF, H,  4608 };
        int ntiles = 6912;
        if (l == NL - 1) {
            tab.d[6] = { key_w1, 7077888u,                     H,     2 * H, 6912 };
            tab.d[7] = { val_w1, 7077888u + 1536u * 768u,      H,     2 * E, 8064 };
            tab.d[8] = { key_w2, 9043968u,                     2 * H, E,     8832 };
            tab.d[9] = { val_w2, 9830400u,                     2 * E, E,     9600 };
            tab.n = 10;
            ntiles = 10112;
        } else {
            tab.n = 6;
        }
        hipLaunchKernelGGL(transpose_all, dim3(ntiles), dim3(256), 0, stream, tab, wt);

        mfma_gemm<ACT_NONE, EPI_QKV, 1><<<dim3(18, 36), 256, 0, stream>>>(
            xb, wt_qkv, q_b + (size_t)l * H, k_b + (size_t)l * H, v_b + (size_t)l * H,
            768, 1536, nullptr, nullptr, qkb, nullptr, Vtb, 0, Mrows, 2304, H);
        hipLaunchKernelGGL(attn_mfma, dim3(864), dim3(256), 0, stream,
                           qkb, Vtb, Larr, ctxb);
        mfma_gemm<ACT_NONE, EPI_F32, 2><<<dim3(6, 36, 2), 256, 0, stream>>>(
            ctxb, wt_o, o_b + (size_t)l * H, nullptr, nullptr, BIG, BIG,
            Bbuf, part1, nullptr, nullptr, nullptr, 0, Mrows, H, H);
        hipLaunchKernelGGL(lnres_kernel, dim3((int)BT), dim3(256), 0, stream,
                           x, Bbuf, part1, ln1_s + (size_t)l * H, ln1_b + (size_t)l * H, xb);
        mfma_gemm<ACT_GELU, EPI_BF16, 1><<<dim3(24, 36), 256, 0, stream>>>(
            xb, wt_f1, f_b1 + (size_t)l * FF, nullptr, nullptr, BIG, BIG,
            nullptr, nullptr, hb, nullptr, nullptr, 0, Mrows, FF, H);
        mfma_gemm<ACT_NONE, EPI_F32, 2><<<dim3(6, 36, 2), 256, 0, stream>>>(
            hb, wt_f2, f_b2 + (size_t)l * H, nullptr, nullptr, BIG, BIG,
            Bbuf, part1, nullptr, nullptr, nullptr, 0, Mrows, H, FF);
        hipLaunchKernelGGL(lnres_kernel, dim3((int)BT), dim3(256), 0, stream,
                           x, Bbuf, part1, ln2_s + (size_t)l * H, ln2_b + (size_t)l * H, xb);
    }

    // fused key1|val1 GEMM: N=2560, split epilogue
    mfma_gemm<ACT_RELU, EPI_SPLIT2, 1><<<dim3(20, 36), 256, 0, stream>>>(
        xb, wt_kv1, key_b1, val_b1, nullptr, 1536, BIG,
        nullptr, nullptr, key1b, val1b, nullptr, 1024, Mrows, 2560, H);
    // key2: split-K, raw logits; sigmoid applied in pool
    mfma_gemm<ACT_NONE, EPI_F32, 2><<<dim3(4, 36, 2), 256, 0, stream>>>(
        key1b, wt_k2, key_b2, nullptr, nullptr, BIG, BIG,
        Bbuf, part1, nullptr, nullptr, nullptr, 0, Mrows, 512, 1536);
    // val2: unsplit, tanh epilogue
    mfma_gemm<ACT_TANH, EPI_F32, 1><<<dim3(4, 36), 256, 0, stream>>>(
        val1b, wt_v2, val_b2, nullptr, nullptr, BIG, BIG,
        valf, nullptr, nullptr, nullptr, nullptr, 0, Mrows, 512, 1024);
    hipLaunchKernelGGL(pool_kernel, dim3(B, E / 32), dim3(256), 0, stream,
                       Bbuf, part1, valf, ttarr, out);
}

// Round 10
// 562.843 us; speedup vs baseline: 1.0469x; 1.0469x over previous
//
#include <hip/hip_runtime.h>
#include <hip/hip_bf16.h>

#define B 8
#define S 512
#define MM 64
#define T 576          // S + MM
#define H 768
#define NH 12
#define DH 64
#define FF 3072
#define E 512
#define NL 2

typedef __attribute__((ext_vector_type(8))) short bf16x8;
typedef __attribute__((ext_vector_type(4))) float f32x4;

__device__ inline unsigned short bf16_rne(float f) {
    unsigned u = __builtin_bit_cast(unsigned, f);
    unsigned r = u + 0x7FFFu + ((u >> 16) & 1u);
    return (unsigned short)(r >> 16);
}

__device__ inline f32x4 mfma16(bf16x8 a, bf16x8 b, f32x4 c) {
    return __builtin_amdgcn_mfma_f32_16x16x32_bf16(a, b, c, 0, 0, 0);
}

__device__ inline void load_lds16(const void* g, void* l) {
    __builtin_amdgcn_global_load_lds((const __attribute__((address_space(1))) void*)g,
                                     (__attribute__((address_space(3))) void*)l, 16, 0, 0);
}

// ---------------- order / argsort ----------------
__global__ void order_kernel(const int* __restrict__ mask, int* __restrict__ ord,
                             int* __restrict__ Larr) {
    __shared__ int ps[S];
    int b = blockIdx.x;
    int t = threadIdx.x;
    int mv = (mask[b * S + t] != 0) ? 1 : 0;
    ps[t] = mv;
    __syncthreads();
    for (int off = 1; off < S; off <<= 1) {
        int v = ps[t];
        int add = (t >= off) ? ps[t - off] : 0;
        __syncthreads();
        ps[t] = v + add;
        __syncthreads();
    }
    int L = ps[S - 1];
    int rank = mv ? (ps[t] - 1) : (L + (t - ps[t]));
    ord[b * S + rank] = t;
    if (t == 0) Larr[b] = L;
}

// ---------------- compact-offset scan: boff[b] = sum_{b'<b}(L+MM); rowb[r] = batch of row r ----------------
__global__ void scan_kernel(const int* __restrict__ Larr, int* __restrict__ boff,
                            int* __restrict__ rowb) {
    __shared__ int sb[B + 1];
    if (threadIdx.x == 0) {
        int acc = 0;
        for (int b = 0; b < B; ++b) { sb[b] = acc; boff[b] = acc; acc += Larr[b] + MM; }
        sb[B] = acc; boff[B] = acc;
    }
    __syncthreads();
    for (int r = threadIdx.x; r < B * T; r += blockDim.x) {
        int bb = 0;
        #pragma unroll
        for (int b2 = 1; b2 < B; ++b2) bb += (r >= sb[b2]) ? 1 : 0;
        rowb[r] = bb;
    }
}

// ---------------- embedding + LN (COMPACT rows: row = boff[b]+t, t < Lb+MM only) ----------------
__global__ void embed_kernel(const int* __restrict__ ids, const int* __restrict__ toktype,
                             const int* __restrict__ ord, const int* __restrict__ Larr,
                             const int* __restrict__ boff,
                             const float* __restrict__ word_emb, const float* __restrict__ pos_emb,
                             const float* __restrict__ type_emb, const float* __restrict__ memory,
                             const float* __restrict__ lns, const float* __restrict__ lnb,
                             float* __restrict__ x, unsigned short* __restrict__ xb,
                             int* __restrict__ ttarr) {
    int t = blockIdx.x;
    int b = blockIdx.y;
    int Lb = Larr[b];
    if (t >= Lb + MM) return;            // tail rows are provably inert -> never computed
    int row = boff[b] + t;
    int tid = threadIdx.x;
    int tt;
    const float* src;
    if (t < Lb) {
        int sp = ord[b * S + t];
        tt = toktype[b * S + sp];
        src = &word_emb[(size_t)ids[b * S + sp] * H];
    } else {
        tt = 1;
        src = &memory[(size_t)(t - Lb) * H];
    }
    __shared__ float rowv[H];
    __shared__ float r1[256], r2[256];
    float lsum = 0.f, lsq = 0.f;
    for (int hh = tid; hh < H; hh += 256) {
        float v = src[hh] + pos_emb[(size_t)t * H + hh] + type_emb[(size_t)tt * H + hh];
        rowv[hh] = v;
        lsum += v;
        lsq += v * v;
    }
    r1[tid] = lsum; r2[tid] = lsq;
    __syncthreads();
    for (int s = 128; s > 0; s >>= 1) {
        if (tid < s) { r1[tid] += r1[tid + s]; r2[tid] += r2[tid + s]; }
        __syncthreads();
    }
    float mu = r1[0] / H;
    float var = r2[0] / H - mu * mu;
    float inv = rsqrtf(var + 1e-12f);
    for (int hh = tid; hh < H; hh += 256) {
        float v = (rowv[hh] - mu) * inv * lns[hh] + lnb[hh];
        x[(size_t)row * H + hh] = v;
        xb[(size_t)row * H + hh] = bf16_rne(v);
    }
    if (tid == 0) ttarr[row] = tt;
}

// ---------------- activations ----------------
#define ACT_NONE 0
#define ACT_RELU 1
#define ACT_GELU 2
#define ACT_SIGMOID 3
#define ACT_TANH 4

template <int ACT>
__device__ inline float apply_act(float v) {
    if constexpr (ACT == ACT_RELU) return fmaxf(v, 0.f);
    else if constexpr (ACT == ACT_GELU) {
        float y = v * 0.70710678118654752f;
        float a = fabsf(y);
        float t = 1.f / (1.f + 0.3275911f * a);
        float poly = t * (0.254829592f + t * (-0.284496736f + t * (1.421413741f +
                     t * (-1.453152027f + t * 1.061405429f))));
        float e = poly * exp2f(-a * a * 1.4426950408889634f);
        float erfv = 1.f - e;
        erfv = (y < 0.f) ? -erfv : erfv;
        return 0.5f * v * (1.f + erfv);
    }
    else if constexpr (ACT == ACT_SIGMOID) return 1.f / (1.f + expf(-v));
    else if constexpr (ACT == ACT_TANH) return tanhf(v);
    else return v;
}

// ---------------- fused weight transpose set: W[K][N] f32 -> Wt[N][K] bf16 ----------------
struct TDesc { const float* src; unsigned dstoff; int Kd; int Nd; int tile0; };
struct TTab { TDesc d[10]; int n; };

__global__ __launch_bounds__(256) void transpose_all(TTab tab, unsigned short* __restrict__ dstbase) {
    int tile = blockIdx.x;
    int mi = 0;
    #pragma unroll
    for (int i = 1; i < 10; ++i)
        if (i < tab.n && tab.d[i].tile0 <= tile) mi = i;
    TDesc d = tab.d[mi];
    int rel = tile - d.tile0;
    int tilesK = d.Kd >> 5;
    int kt = rel % tilesK, nt = rel / tilesK;
    __shared__ float ts[32][33];
    int k0 = kt * 32, n0 = nt * 32;
    int tx = threadIdx.x & 31, ty = threadIdx.x >> 5;  // 32 x 8
    #pragma unroll
    for (int r = 0; r < 4; ++r) {
        int kk = ty + r * 8;
        ts[kk][tx] = d.src[(size_t)(k0 + kk) * d.Nd + n0 + tx];
    }
    __syncthreads();
    unsigned short* Wt = dstbase + d.dstoff;
    #pragma unroll
    for (int r = 0; r < 4; ++r) {
        int nn = ty + r * 8;
        Wt[(size_t)(n0 + nn) * d.Kd + k0 + tx] = bf16_rne(ts[tx][nn]);
    }
}

// ---------------- MFMA GEMM (compact rows; early-exit past Mtot) ----------------
#define EPI_F32   0
#define EPI_BF16  1
#define EPI_QKV   2
#define EPI_SPLIT2 3

template <int ACT, int EPI, int NSPLIT>
__global__ __launch_bounds__(256) void mfma_gemm(
    const unsigned short* __restrict__ A, const unsigned short* __restrict__ Bt,
    const float* __restrict__ b0, const float* __restrict__ b1, const float* __restrict__ b2,
    int sp1, int sp2,
    float* __restrict__ Cf, float* __restrict__ Cf2,
    unsigned short* __restrict__ Cb, unsigned short* __restrict__ Cb2,
    unsigned short* __restrict__ Vt, int n2w,
    const int* __restrict__ boffs, const int* __restrict__ rowb,
    int Mdim, int Ndim, int Kdim) {
    __shared__ unsigned short As[2][128 * 32];
    __shared__ unsigned short Bs[2][128 * 32];

    // bijective XCD swizzle (m204), ROW-major decode (R8 layout — best measured)
    const int gx = gridDim.x;
    const int nwg = gx * gridDim.y;
    int orig = blockIdx.y * gx + blockIdx.x;
    int q = nwg >> 3, r8 = nwg & 7;
    int xcd = orig & 7, idx = orig >> 3;
    int swz = (xcd < r8 ? xcd * (q + 1) : r8 * (q + 1) + (xcd - r8) * q) + idx;
    const int bn = (swz % gx) * 128, bm = (swz / gx) * 128;

    const int Mtot = boffs[B];
    if (bm >= Mtot) return;              // compacted: blocks past live rows retire

    const int z = (NSPLIT > 1) ? blockIdx.z : 0;
    const int Klocal = Kdim / NSPLIT;
    const int koff = z * Klocal;

    const int tid = threadIdx.x;
    const int w = tid >> 6, lane = tid & 63;
    const int lr = lane & 15, g = lane >> 4;
    const int wr = w >> 1, wc = w & 1;
    f32x4 acc[4][4] = {};

    const int srow = w * 32 + (lane >> 2);
    const int kc = (((lane & 3) ^ ((lane >> 4) & 3)) * 8);
    const unsigned short* ga0 = A + (size_t)(bm + srow) * Kdim + kc;
    const unsigned short* ga1 = A + (size_t)(bm + srow + 16) * Kdim + kc;
    const unsigned short* gb0 = Bt + (size_t)(bn + srow) * Kdim + kc;
    const unsigned short* gb1 = Bt + (size_t)(bn + srow + 16) * Kdim + kc;
    const int d0 = (w * 32) * 32, d1 = (w * 32 + 16) * 32;

    const int sw = ((g ^ ((lr >> 2) & 3)) & 3) * 8;

    auto stage = [&](int pp, int k0) {
        load_lds16(ga0 + k0, &As[pp][d0]);
        load_lds16(ga1 + k0, &As[pp][d1]);
        load_lds16(gb0 + k0, &Bs[pp][d0]);
        load_lds16(gb1 + k0, &Bs[pp][d1]);
    };
    auto compute = [&](int pp) {
        bf16x8 af[4], bfr[4];
        #pragma unroll
        for (int i = 0; i < 4; ++i)
            af[i] = *(const bf16x8*)&As[pp][(wr * 64 + i * 16 + lr) * 32 + sw];
        #pragma unroll
        for (int j = 0; j < 4; ++j)
            bfr[j] = *(const bf16x8*)&Bs[pp][(wc * 64 + j * 16 + lr) * 32 + sw];
        __builtin_amdgcn_s_setprio(1);
        #pragma unroll
        for (int i = 0; i < 4; ++i)
            #pragma unroll
            for (int j = 0; j < 4; ++j)
                acc[i][j] = mfma16(af[i], bfr[j], acc[i][j]);
        __builtin_amdgcn_s_setprio(0);
    };

    const int nk = Klocal >> 5;
    stage(0, koff);
    int p = 0;
    for (int s = 0; s < nk; ++s) {
        if (s + 1 < nk) {
            stage(p ^ 1, koff + (s + 1) * 32);
            asm volatile("s_waitcnt vmcnt(4)" ::: "memory");
        } else {
            asm volatile("s_waitcnt vmcnt(0)" ::: "memory");
        }
        __builtin_amdgcn_s_barrier();
        __builtin_amdgcn_sched_barrier(0);
        compute(p);
        __builtin_amdgcn_sched_barrier(0);
        __builtin_amdgcn_s_barrier();
        __builtin_amdgcn_sched_barrier(0);
        p ^= 1;
    }

    float* Cdst = (NSPLIT > 1 && z == 1) ? Cf2 : Cf;
    #pragma unroll
    for (int i = 0; i < 4; ++i) {
        const int row0 = bm + wr * 64 + i * 16 + 4 * g;
        #pragma unroll
        for (int j = 0; j < 4; ++j) {
            const int col = bn + wc * 64 + j * 16 + lr;
            float bv = (NSPLIT > 1 && z == 1) ? 0.f
                     : ((col < sp1) ? b0[col] : (col < sp2 ? b1[col - sp1] : b2[col - sp2]));
            float vv[4];
            #pragma unroll
            for (int r = 0; r < 4; ++r) vv[r] = apply_act<ACT>(acc[i][j][r] + bv);
            if constexpr (EPI == EPI_F32) {
                #pragma unroll
                for (int r = 0; r < 4; ++r) Cdst[(size_t)(row0 + r) * Ndim + col] = vv[r];
            } else if constexpr (EPI == EPI_BF16) {
                #pragma unroll
                for (int r = 0; r < 4; ++r) Cb[(size_t)(row0 + r) * Ndim + col] = bf16_rne(vv[r]);
            } else if constexpr (EPI == EPI_QKV) {
                if (col < 1536) {
                    #pragma unroll
                    for (int r = 0; r < 4; ++r) Cb[(size_t)(row0 + r) * 1536 + col] = bf16_rne(vv[r]);
                } else {
                    // Vt epilogue: compact row -> (batch, local t) via rowb/boffs
                    int c2 = col - 1536;
                    int hh2 = c2 >> 6, dd = c2 & 63;
                    int bb = rowb[row0];
                    if (row0 + 3 < Mtot && rowb[row0 + 3] == bb) {
                        int t0 = row0 - boffs[bb];
                        unsigned lo = (unsigned)bf16_rne(vv[0]) | ((unsigned)bf16_rne(vv[1]) << 16);
                        unsigned hi = (unsigned)bf16_rne(vv[2]) | ((unsigned)bf16_rne(vv[3]) << 16);
                        size_t idxv = (((size_t)bb * NH + hh2) * DH + dd) * T + t0;
                        *(uint2*)&Vt[idxv] = make_uint2(lo, hi);
                    } else {
                        #pragma unroll
                        for (int r = 0; r < 4; ++r) {
                            int rr = row0 + r;
                            if (rr < Mtot) {
                                int b2 = rowb[rr];
                                int t2 = rr - boffs[b2];
                                Vt[(((size_t)b2 * NH + hh2) * DH + dd) * T + t2] = bf16_rne(vv[r]);
                            }
                        }
                    }
                }
            } else {  // EPI_SPLIT2
                if (col < sp1) {
                    #pragma unroll
                    for (int r = 0; r < 4; ++r) Cb[(size_t)(row0 + r) * sp1 + col] = bf16_rne(vv[r]);
                } else {
                    #pragma unroll
                    for (int r = 0; r < 4; ++r)
                        Cb2[(size_t)(row0 + r) * n2w + (col - sp1)] = bf16_rne(vv[r]);
                }
            }
        }
    }
}

// ---------------- MFMA flash attention (compact rows, per-batch base) ----------------
#define C2 0.180336880111116670f      // 0.125 * log2(e)
#define MB2 14426.950408889634f       // 10000 * log2(e)

__global__ __launch_bounds__(256) void attn_mfma(
    const unsigned short* __restrict__ QK, const unsigned short* __restrict__ Vt,
    const int* __restrict__ Larr, const int* __restrict__ boffs,
    unsigned short* __restrict__ ctxb) {
    const int n = blockIdx.x;
    const int xcd = n & 7, k = n >> 3;
    const int p = xcd * 12 + k / 9, qt = k % 9;
    const int b = p / NH, h = p % NH;
    const int LbMM = Larr[b] + MM;
    if (qt * 64 >= LbMM) return;                 // compacted: masked q-tiles gone
    const int w = threadIdx.x >> 6, lane = threadIdx.x & 63;
    const int q0 = qt * 64 + w * 16;
    if (q0 >= LbMM) return;                      // per-wave tail exit (no block barriers used)
    const int base = boffs[b];
    const int lr = lane & 15, g = lane >> 4;
    __shared__ unsigned short P[4][16][72];
    const unsigned short* qrow = QK + (size_t)(base + q0 + lr) * 1536 + h * 64;
    bf16x8 qf0 = *(const bf16x8*)(qrow + 8 * g);
    bf16x8 qf1 = *(const bf16x8*)(qrow + 32 + 8 * g);
    f32x4 ctx[4] = {};
    float m_run = -1e30f, l_run = 0.f;
    const size_t vbase = ((size_t)b * NH + h) * DH;
    for (int kt = 0; kt < LbMM; kt += 64) {
        f32x4 sf[4];
        #pragma unroll
        for (int i = 0; i < 4; ++i) {
            const unsigned short* krow =
                QK + (size_t)(base + kt + 16 * i + lr) * 1536 + 768 + h * 64;
            bf16x8 kf0 = *(const bf16x8*)(krow + 8 * g);
            bf16x8 kf1 = *(const bf16x8*)(krow + 32 + 8 * g);
            f32x4 s = {};
            s = mfma16(kf0, qf0, s);
            s = mfma16(kf1, qf1, s);
            sf[i] = s;
        }
        float tmax = -1e30f;
        #pragma unroll
        for (int i = 0; i < 4; ++i)
            #pragma unroll
            for (int r = 0; r < 4; ++r) {
                int key = kt + 16 * i + 4 * g + r;
                float v = sf[i][r] * C2 + (key < LbMM ? 0.f : -MB2);
                sf[i][r] = v;
                tmax = fmaxf(tmax, v);
            }
        tmax = fmaxf(tmax, __shfl_xor(tmax, 16));
        tmax = fmaxf(tmax, __shfl_xor(tmax, 32));
        float m_new = fmaxf(m_run, tmax);
        float scale = exp2f(m_run - m_new);
        m_run = m_new;
        float psum = 0.f;
        #pragma unroll
        for (int i = 0; i < 4; ++i)
            #pragma unroll
            for (int r = 0; r < 4; ++r) {
                float pv = exp2f(sf[i][r] - m_new);
                sf[i][r] = pv;
                psum += pv;
            }
        l_run = l_run * scale + psum;
        float f0 = __shfl(scale, 4 * g + 0);
        float f1 = __shfl(scale, 4 * g + 1);
        float f2 = __shfl(scale, 4 * g + 2);
        float f3 = __shfl(scale, 4 * g + 3);
        #pragma unroll
        for (int j = 0; j < 4; ++j) {
            ctx[j][0] *= f0; ctx[j][1] *= f1; ctx[j][2] *= f2; ctx[j][3] *= f3;
        }
        #pragma unroll
        for (int i = 0; i < 4; ++i) {
            unsigned lo = (unsigned)bf16_rne(sf[i][0]) | ((unsigned)bf16_rne(sf[i][1]) << 16);
            unsigned hi = (unsigned)bf16_rne(sf[i][2]) | ((unsigned)bf16_rne(sf[i][3]) << 16);
            *(unsigned*)&P[w][lr][16 * i + 4 * g] = lo;
            *(unsigned*)&P[w][lr][16 * i + 4 * g + 2] = hi;
        }
        asm volatile("s_waitcnt lgkmcnt(0)" ::: "memory");
        __builtin_amdgcn_sched_barrier(0);
        #pragma unroll
        for (int s2 = 0; s2 < 2; ++s2) {
            bf16x8 pa = *(const bf16x8*)&P[w][lr][32 * s2 + 8 * g];
            #pragma unroll
            for (int j = 0; j < 4; ++j) {
                const unsigned short* vrow =
                    Vt + (vbase + 16 * j + lr) * T + kt + 32 * s2 + 8 * g;
                bf16x8 vf = *(const bf16x8*)vrow;
                ctx[j] = mfma16(pa, vf, ctx[j]);
            }
        }
        asm volatile("s_waitcnt lgkmcnt(0)" ::: "memory");
        __builtin_amdgcn_sched_barrier(0);
    }
    l_run += __shfl_xor(l_run, 16);
    l_run += __shfl_xor(l_run, 32);
    float inv = 1.f / l_run;
    float i0 = __shfl(inv, 4 * g + 0);
    float i1 = __shfl(inv, 4 * g + 1);
    float i2 = __shfl(inv, 4 * g + 2);
    float i3 = __shfl(inv, 4 * g + 3);
    float sc[4] = {i0, i1, i2, i3};
    #pragma unroll
    for (int j = 0; j < 4; ++j)
        #pragma unroll
        for (int r = 0; r < 4; ++r) {
            int rl = q0 + 4 * g + r;
            if (rl < LbMM)
                ctxb[(size_t)(base + rl) * H + h * 64 + 16 * j + lr] =
                    bf16_rne(ctx[j][r] * sc[r]);
        }
}

// ---------------- residual + LN (delta = d1 + d2), float4, compact early-exit ----------------
__global__ void lnres_kernel(float* __restrict__ x, const float* __restrict__ d1,
                             const float* __restrict__ d2,
                             const float* __restrict__ s, const float* __restrict__ bvec,
                             unsigned short* __restrict__ xb, const int* __restrict__ mtotp) {
    int r = blockIdx.x;
    if (r >= mtotp[0]) return;
    int tid = threadIdx.x;
    __shared__ float4 row[H / 4];
    __shared__ float r1[256], r2[256];
    float lsum = 0.f, lsq = 0.f;
    size_t off4 = (size_t)r * (H / 4);
    const float4* x4 = (const float4*)x;
    const float4* d14 = (const float4*)d1;
    const float4* d24 = (const float4*)d2;
    if (tid < H / 4) {
        float4 a = x4[off4 + tid], bb = d14[off4 + tid], cc = d24[off4 + tid];
        float4 v = make_float4(a.x + bb.x + cc.x, a.y + bb.y + cc.y,
                               a.z + bb.z + cc.z, a.w + bb.w + cc.w);
        row[tid] = v;
        lsum = v.x + v.y + v.z + v.w;
        lsq = v.x * v.x + v.y * v.y + v.z * v.z + v.w * v.w;
    }
    r1[tid] = lsum; r2[tid] = lsq;
    __syncthreads();
    for (int ss = 128; ss > 0; ss >>= 1) {
        if (tid < ss) { r1[tid] += r1[tid + ss]; r2[tid] += r2[tid + ss]; }
        __syncthreads();
    }
    float mu = r1[0] / H;
    float var = r2[0] / H - mu * mu;
    float inv = rsqrtf(var + 1e-12f);
    if (tid < H / 4) {
        float4 v = row[tid];
        const float4 sv = ((const float4*)s)[tid];
        const float4 bv = ((const float4*)bvec)[tid];
        float4 o = make_float4((v.x - mu) * inv * sv.x + bv.x,
                               (v.y - mu) * inv * sv.y + bv.y,
                               (v.z - mu) * inv * sv.z + bv.z,
                               (v.w - mu) * inv * sv.w + bv.w);
        ((float4*)x)[off4 + tid] = o;
        ushort4 ob = make_ushort4(bf16_rne(o.x), bf16_rne(o.y), bf16_rne(o.z), bf16_rne(o.w));
        *(ushort4*)&xb[(size_t)r * H + tid * 4] = ob;
    }
}

// ---------------- masked softmax pooling (compact rows; sigmoid of w0+w1) ----------------
__global__ __launch_bounds__(256) void pool_kernel(
    const float* __restrict__ w0, const float* __restrict__ w1,
    const float* __restrict__ value, const int* __restrict__ ttarr,
    const int* __restrict__ boffs, float* __restrict__ out) {
    int b = blockIdx.x;
    int le = threadIdx.x & 31;
    int e = blockIdx.y * 32 + le;
    int tg = threadIdx.x >> 5;  // 0..7
    int base = boffs[b];
    int nrow = boffs[b + 1] - base;
    __shared__ int ttl[T];
    __shared__ float red[8][33];
    for (int t = threadIdx.x; t < nrow; t += 256) ttl[t] = ttarr[base + t];
    __syncthreads();
    float mx = -1e30f;
    for (int t = tg; t < nrow; t += 8) {
        if (ttl[t] == 1) continue;
        size_t idx = (size_t)(base + t) * E + e;
        float w = 1.f / (1.f + expf(-(w0[idx] + w1[idx])));
        mx = fmaxf(mx, w);
    }
    red[tg][le] = mx;
    __syncthreads();
    #pragma unroll
    for (int i = 0; i < 8; ++i) mx = fmaxf(mx, red[i][le]);
    float den = 0.f, num = 0.f;
    for (int t = tg; t < nrow; t += 8) {
        if (ttl[t] == 1) continue;
        size_t idx = (size_t)(base + t) * E + e;
        float w = 1.f / (1.f + expf(-(w0[idx] + w1[idx])));
        float ew = expf(w - mx);
        den += ew;
        num = fmaf(ew, value[idx], num);
    }
    __syncthreads();
    red[tg][le] = den;
    __syncthreads();
    float dtot = 0.f;
    #pragma unroll
    for (int i = 0; i < 8; ++i) dtot += red[i][le];
    __syncthreads();
    red[tg][le] = num;
    __syncthreads();
    float ntot = 0.f;
    #pragma unroll
    for (int i = 0; i < 8; ++i) ntot += red[i][le];
    if (tg == 0) out[(size_t)b * E + e] = fmaxf(ntot / dtot, 0.f);
}

// ---------------- host-side launch ----------------
extern "C" void kernel_launch(void* const* d_in, const int* in_sizes, int n_in,
                              void* d_out, int out_size, void* d_ws, size_t ws_size,
                              hipStream_t stream) {
    const int*   input_ids  = (const int*)d_in[0];
    const int*   token_type = (const int*)d_in[1];
    const int*   attn_mask  = (const int*)d_in[2];
    const float* word_emb   = (const float*)d_in[3];
    const float* pos_emb    = (const float*)d_in[4];
    const float* type_emb   = (const float*)d_in[5];
    const float* emb_ln_s   = (const float*)d_in[6];
    const float* emb_ln_b   = (const float*)d_in[7];
    const float* memory     = (const float*)d_in[8];
    const float* q_w  = (const float*)d_in[9];
    const float* q_b  = (const float*)d_in[10];
    const float* k_w  = (const float*)d_in[11];
    const float* k_b  = (const float*)d_in[12];
    const float* v_w  = (const float*)d_in[13];
    const float* v_b  = (const float*)d_in[14];
    const float* o_w  = (const float*)d_in[15];
    const float* o_b  = (const float*)d_in[16];
    const float* ln1_s = (const float*)d_in[17];
    const float* ln1_b = (const float*)d_in[18];
    const float* f_w1  = (const float*)d_in[19];
    const float* f_b1  = (const float*)d_in[20];
    const float* f_w2  = (const float*)d_in[21];
    const float* f_b2  = (const float*)d_in[22];
    const float* ln2_s = (const float*)d_in[23];
    const float* ln2_b = (const float*)d_in[24];
    const float* key_w1 = (const float*)d_in[25];
    const float* key_b1 = (const float*)d_in[26];
    const float* key_w2 = (const float*)d_in[27];
    const float* key_b2 = (const float*)d_in[28];
    const float* val_w1 = (const float*)d_in[29];
    const float* val_b1 = (const float*)d_in[30];
    const float* val_w2 = (const float*)d_in[31];
    const float* val_b2 = (const float*)d_in[32];
    float* out = (float*)d_out;

    char* ws = (char*)d_ws;
    size_t off = 0;
    auto alloc = [&](size_t bytes) {
        void* p = ws + off;
        off += (bytes + 255) & ~(size_t)255;
        return p;
    };
    const size_t BT  = (size_t)B * T;      // 4608 (worst-case rows)
    const size_t BTH = BT * H;

    int*   ord   = (int*)alloc((size_t)B * S * 4);
    int*   Larr  = (int*)alloc(64);
    int*   boff  = (int*)alloc((B + 1) * 4);
    int*   rowb  = (int*)alloc(BT * 4);
    int*   ttarr = (int*)alloc(BT * 4);
    float* x     = (float*)alloc(BTH * 4);
    unsigned short* xb   = (unsigned short*)alloc(BTH * 2);
    unsigned short* reg1 = (unsigned short*)alloc(BT * FF * 2);
    float* Bbuf  = (float*)alloc(BTH * 4);     // split-K partial z0
    float* part1 = (float*)alloc(BTH * 4);     // split-K partial z1
    unsigned short* wt = (unsigned short*)alloc((size_t)10354688 * 2);

    unsigned short* qkb  = reg1;                       // [BT][1536]
    unsigned short* Vtb  = reg1 + BT * 1536;           // [B][NH][DH][T]
    unsigned short* ctxb = reg1 + BT * 1536 + BTH;     // [BT][H]
    unsigned short* hb   = reg1;                       // [BT][FF] (FFN phase)
    unsigned short* key1b = reg1;                      // [BT][1536] (head phase)
    unsigned short* val1b = reg1 + BT * 1536;          // [BT][1024]
    float* valf = x;                                   // [BT][512] f32 (x dead by then)

    unsigned short* wt_qkv = wt;                       // [2304][768]
    unsigned short* wt_o  = wt + (size_t)2304 * 768;   // [768][768]
    unsigned short* wt_f1 = wt_o + (size_t)768 * 768;  // [3072][768]
    unsigned short* wt_f2 = wt_f1 + (size_t)3072 * 768;// [768][3072]
    unsigned short* wt_head = wt + (size_t)7077888;
    unsigned short* wt_kv1 = wt_head;                  // [2560][768]
    unsigned short* wt_k2 = wt_head + (size_t)2560 * 768;   // [512][1536]
    unsigned short* wt_v2 = wt_k2 + (size_t)512 * 1536;     // [512][1024]

    const int Mrows = (int)BT;  // worst-case 4608; true Mtot read on device
    const size_t HH = (size_t)H * H;
    const int BIG = 1 << 30;
    const int* mtotp = boff + B;

    hipLaunchKernelGGL(order_kernel, dim3(B), dim3(S), 0, stream, attn_mask, ord, Larr);
    hipLaunchKernelGGL(scan_kernel, dim3(1), dim3(256), 0, stream, Larr, boff, rowb);
    hipLaunchKernelGGL(embed_kernel, dim3(T, B), dim3(256), 0, stream,
                       input_ids, token_type, ord, Larr, boff, word_emb, pos_emb, type_emb,
                       memory, emb_ln_s, emb_ln_b, x, xb, ttarr);

    for (int l = 0; l < NL; ++l) {
        TTab tab;
        tab.d[0] = { q_w + l * HH,              0u,                              H,  H,  0    };
        tab.d[1] = { k_w + l * HH,              (unsigned)(768 * 768),           H,  H,  576  };
        tab.d[2] = { v_w + l * HH,              (unsigned)(1536 * 768),          H,  H,  1152 };
        tab.d[3] = { o_w + l * HH,              (unsigned)(2304 * 768),          H,  H,  1728 };
        tab.d[4] = { f_w1 + (size_t)l * H * FF, (unsigned)(3072 * 768),          H,  FF, 2304 };
        tab.d[5] = { f_w2 + (size_t)l * FF * H, (unsigned)(6144 * 768),          FF, H,  4608 };
        int ntiles = 6912;
        if (l == NL - 1) {
            tab.d[6] = { key_w1, 7077888u,                     H,     2 * H, 6912 };
            tab.d[7] = { val_w1, 7077888u + 1536u * 768u,      H,     2 * E, 8064 };
            tab.d[8] = { key_w2, 9043968u,                     2 * H, E,     8832 };
            tab.d[9] = { val_w2, 9830400u,                     2 * E, E,     9600 };
            tab.n = 10;
            ntiles = 10112;
        } else {
            tab.n = 6;
        }
        hipLaunchKernelGGL(transpose_all, dim3(ntiles), dim3(256), 0, stream, tab, wt);

        mfma_gemm<ACT_NONE, EPI_QKV, 1><<<dim3(18, 36), 256, 0, stream>>>(
            xb, wt_qkv, q_b + (size_t)l * H, k_b + (size_t)l * H, v_b + (size_t)l * H,
            768, 1536, nullptr, nullptr, qkb, nullptr, Vtb, 0, boff, rowb, Mrows, 2304, H);
        hipLaunchKernelGGL(attn_mfma, dim3(864), dim3(256), 0, stream,
                           qkb, Vtb, Larr, boff, ctxb);
        mfma_gemm<ACT_NONE, EPI_F32, 2><<<dim3(6, 36, 2), 256, 0, stream>>>(
            ctxb, wt_o, o_b + (size_t)l * H, nullptr, nullptr, BIG, BIG,
            Bbuf, part1, nullptr, nullptr, nullptr, 0, boff, rowb, Mrows, H, H);
        hipLaunchKernelGGL(lnres_kernel, dim3((int)BT), dim3(256), 0, stream,
                           x, Bbuf, part1, ln1_s + (size_t)l * H, ln1_b + (size_t)l * H, xb, mtotp);
        mfma_gemm<ACT_GELU, EPI_BF16, 1><<<dim3(24, 36), 256, 0, stream>>>(
            xb, wt_f1, f_b1 + (size_t)l * FF, nullptr, nullptr, BIG, BIG,
            nullptr, nullptr, hb, nullptr, nullptr, 0, boff, rowb, Mrows, FF, H);
        mfma_gemm<ACT_NONE, EPI_F32, 2><<<dim3(6, 36, 2), 256, 0, stream>>>(
            hb, wt_f2, f_b2 + (size_t)l * H, nullptr, nullptr, BIG, BIG,
            Bbuf, part1, nullptr, nullptr, nullptr, 0, boff, rowb, Mrows, H, FF);
        hipLaunchKernelGGL(lnres_kernel, dim3((int)BT), dim3(256), 0, stream,
                           x, Bbuf, part1, ln2_s + (size_t)l * H, ln2_b + (size_t)l * H, xb, mtotp);
    }

    // fused key1|val1 GEMM: N=2560, split epilogue
    mfma_gemm<ACT_RELU, EPI_SPLIT2, 1><<<dim3(20, 36), 256, 0, stream>>>(
        xb, wt_kv1, key_b1, val_b1, nullptr, 1536, BIG,
        nullptr, nullptr, key1b, val1b, nullptr, 1024, boff, rowb, Mrows, 2560, H);
    // key2: split-K, raw logits; sigmoid applied in pool
    mfma_gemm<ACT_NONE, EPI_F32, 2><<<dim3(4, 36, 2), 256, 0, stream>>>(
        key1b, wt_k2, key_b2, nullptr, nullptr, BIG, BIG,
        Bbuf, part1, nullptr, nullptr, nullptr, 0, boff, rowb, Mrows, 512, 1536);
    // val2: unsplit, tanh epilogue
    mfma_gemm<ACT_TANH, EPI_F32, 1><<<dim3(4, 36), 256, 0, stream>>>(
        val1b, wt_v2, val_b2, nullptr, nullptr, BIG, BIG,
        valf, nullptr, nullptr, nullptr, nullptr, 0, boff, rowb, Mrows, 512, 1024);
    hipLaunchKernelGGL(pool_kernel, dim3(B, E / 32), dim3(256), 0, stream,
                       Bbuf, part1, valf, ttarr, boff, out);
}

// Round 11
// 500.495 us; speedup vs baseline: 1.1774x; 1.1246x over previous
//
#include <hip/hip_runtime.h>
#include <hip/hip_bf16.h>

#define B 8
#define S 512
#define MM 64
#define T 576          // S + MM
#define H 768
#define NH 12
#define DH 64
#define FF 3072
#define E 512
#define NL 2

typedef __attribute__((ext_vector_type(8))) short bf16x8;
typedef __attribute__((ext_vector_type(4))) float f32x4;

__device__ inline unsigned short bf16_rne(float f) {
    unsigned u = __builtin_bit_cast(unsigned, f);
    unsigned r = u + 0x7FFFu + ((u >> 16) & 1u);
    return (unsigned short)(r >> 16);
}

__device__ inline f32x4 mfma16(bf16x8 a, bf16x8 b, f32x4 c) {
    return __builtin_amdgcn_mfma_f32_16x16x32_bf16(a, b, c, 0, 0, 0);
}

__device__ inline void load_lds16(const void* g, void* l) {
    __builtin_amdgcn_global_load_lds((const __attribute__((address_space(1))) void*)g,
                                     (__attribute__((address_space(3))) void*)l, 16, 0, 0);
}

// ---------------- order / argsort ----------------
__global__ void order_kernel(const int* __restrict__ mask, int* __restrict__ ord,
                             int* __restrict__ Larr) {
    __shared__ int ps[S];
    int b = blockIdx.x;
    int t = threadIdx.x;
    int mv = (mask[b * S + t] != 0) ? 1 : 0;
    ps[t] = mv;
    __syncthreads();
    for (int off = 1; off < S; off <<= 1) {
        int v = ps[t];
        int add = (t >= off) ? ps[t - off] : 0;
        __syncthreads();
        ps[t] = v + add;
        __syncthreads();
    }
    int L = ps[S - 1];
    int rank = mv ? (ps[t] - 1) : (L + (t - ps[t]));
    ord[b * S + rank] = t;
    if (t == 0) Larr[b] = L;
}

// ---------------- compact-offset scan ----------------
__global__ void scan_kernel(const int* __restrict__ Larr, int* __restrict__ boff,
                            int* __restrict__ rowb) {
    __shared__ int sb[B + 1];
    if (threadIdx.x == 0) {
        int acc = 0;
        for (int b = 0; b < B; ++b) { sb[b] = acc; boff[b] = acc; acc += Larr[b] + MM; }
        sb[B] = acc; boff[B] = acc;
    }
    __syncthreads();
    for (int r = threadIdx.x; r < B * T; r += blockDim.x) {
        int bb = 0;
        #pragma unroll
        for (int b2 = 1; b2 < B; ++b2) bb += (r >= sb[b2]) ? 1 : 0;
        rowb[r] = bb;
    }
}

// ---------------- embedding + LN (COMPACT rows) ----------------
__global__ void embed_kernel(const int* __restrict__ ids, const int* __restrict__ toktype,
                             const int* __restrict__ ord, const int* __restrict__ Larr,
                             const int* __restrict__ boff,
                             const float* __restrict__ word_emb, const float* __restrict__ pos_emb,
                             const float* __restrict__ type_emb, const float* __restrict__ memory,
                             const float* __restrict__ lns, const float* __restrict__ lnb,
                             float* __restrict__ x, unsigned short* __restrict__ xb,
                             int* __restrict__ ttarr) {
    int t = blockIdx.x;
    int b = blockIdx.y;
    int Lb = Larr[b];
    if (t >= Lb + MM) return;
    int row = boff[b] + t;
    int tid = threadIdx.x;
    int tt;
    const float* src;
    if (t < Lb) {
        int sp = ord[b * S + t];
        tt = toktype[b * S + sp];
        src = &word_emb[(size_t)ids[b * S + sp] * H];
    } else {
        tt = 1;
        src = &memory[(size_t)(t - Lb) * H];
    }
    __shared__ float rowv[H];
    __shared__ float r1[256], r2[256];
    float lsum = 0.f, lsq = 0.f;
    for (int hh = tid; hh < H; hh += 256) {
        float v = src[hh] + pos_emb[(size_t)t * H + hh] + type_emb[(size_t)tt * H + hh];
        rowv[hh] = v;
        lsum += v;
        lsq += v * v;
    }
    r1[tid] = lsum; r2[tid] = lsq;
    __syncthreads();
    for (int s = 128; s > 0; s >>= 1) {
        if (tid < s) { r1[tid] += r1[tid + s]; r2[tid] += r2[tid + s]; }
        __syncthreads();
    }
    float mu = r1[0] / H;
    float var = r2[0] / H - mu * mu;
    float inv = rsqrtf(var + 1e-12f);
    for (int hh = tid; hh < H; hh += 256) {
        float v = (rowv[hh] - mu) * inv * lns[hh] + lnb[hh];
        x[(size_t)row * H + hh] = v;
        xb[(size_t)row * H + hh] = bf16_rne(v);
    }
    if (tid == 0) ttarr[row] = tt;
}

// ---------------- activations ----------------
#define ACT_NONE 0
#define ACT_RELU 1
#define ACT_GELU 2
#define ACT_SIGMOID 3
#define ACT_TANH 4

template <int ACT>
__device__ inline float apply_act(float v) {
    if constexpr (ACT == ACT_RELU) return fmaxf(v, 0.f);
    else if constexpr (ACT == ACT_GELU) {
        float y = v * 0.70710678118654752f;
        float a = fabsf(y);
        float t = 1.f / (1.f + 0.3275911f * a);
        float poly = t * (0.254829592f + t * (-0.284496736f + t * (1.421413741f +
                     t * (-1.453152027f + t * 1.061405429f))));
        float e = poly * exp2f(-a * a * 1.4426950408889634f);
        float erfv = 1.f - e;
        erfv = (y < 0.f) ? -erfv : erfv;
        return 0.5f * v * (1.f + erfv);
    }
    else if constexpr (ACT == ACT_SIGMOID) return 1.f / (1.f + expf(-v));
    else if constexpr (ACT == ACT_TANH) return tanhf(v);
    else return v;
}

// ---------------- fused weight transpose set ----------------
struct TDesc { const float* src; unsigned dstoff; int Kd; int Nd; int tile0; };
struct TTab { TDesc d[10]; int n; };

__global__ __launch_bounds__(256) void transpose_all(TTab tab, unsigned short* __restrict__ dstbase) {
    int tile = blockIdx.x;
    int mi = 0;
    #pragma unroll
    for (int i = 1; i < 10; ++i)
        if (i < tab.n && tab.d[i].tile0 <= tile) mi = i;
    TDesc d = tab.d[mi];
    int rel = tile - d.tile0;
    int tilesK = d.Kd >> 5;
    int kt = rel % tilesK, nt = rel / tilesK;
    __shared__ float ts[32][33];
    int k0 = kt * 32, n0 = nt * 32;
    int tx = threadIdx.x & 31, ty = threadIdx.x >> 5;  // 32 x 8
    #pragma unroll
    for (int r = 0; r < 4; ++r) {
        int kk = ty + r * 8;
        ts[kk][tx] = d.src[(size_t)(k0 + kk) * d.Nd + n0 + tx];
    }
    __syncthreads();
    unsigned short* Wt = dstbase + d.dstoff;
    #pragma unroll
    for (int r = 0; r < 4; ++r) {
        int nn = ty + r * 8;
        Wt[(size_t)(n0 + nn) * d.Kd + k0 + tx] = bf16_rne(ts[tx][nn]);
    }
}

// ---------------- MFMA GEMM (compact rows; IDENTITY block mapping) ----------------
// NO XCD swizzle: retired blocks (bm >= Mtot) are the dispatch-order suffix,
// uniformly spread mod-8 across XCDs -> load balance under compaction.
// Each XCD also sees a fixed subset of bn-columns (nwg%8==0) -> W L2 locality.
#define EPI_F32   0
#define EPI_BF16  1
#define EPI_QKV   2
#define EPI_SPLIT2 3

template <int ACT, int EPI, int NSPLIT>
__global__ __launch_bounds__(256) void mfma_gemm(
    const unsigned short* __restrict__ A, const unsigned short* __restrict__ Bt,
    const float* __restrict__ b0, const float* __restrict__ b1, const float* __restrict__ b2,
    int sp1, int sp2,
    float* __restrict__ Cf, float* __restrict__ Cf2,
    unsigned short* __restrict__ Cb, unsigned short* __restrict__ Cb2,
    unsigned short* __restrict__ Vt, int n2w,
    const int* __restrict__ boffs, const int* __restrict__ rowb,
    int Mdim, int Ndim, int Kdim) {
    __shared__ unsigned short As[2][128 * 32];
    __shared__ unsigned short Bs[2][128 * 32];

    const int bn = blockIdx.x * 128, bm = blockIdx.y * 128;

    const int Mtot = boffs[B];
    if (bm >= Mtot) return;              // compacted: blocks past live rows retire

    const int z = (NSPLIT > 1) ? blockIdx.z : 0;
    const int Klocal = Kdim / NSPLIT;
    const int koff = z * Klocal;

    const int tid = threadIdx.x;
    const int w = tid >> 6, lane = tid & 63;
    const int lr = lane & 15, g = lane >> 4;
    const int wr = w >> 1, wc = w & 1;
    f32x4 acc[4][4] = {};

    const int srow = w * 32 + (lane >> 2);
    const int kc = (((lane & 3) ^ ((lane >> 4) & 3)) * 8);
    const unsigned short* ga0 = A + (size_t)(bm + srow) * Kdim + kc;
    const unsigned short* ga1 = A + (size_t)(bm + srow + 16) * Kdim + kc;
    const unsigned short* gb0 = Bt + (size_t)(bn + srow) * Kdim + kc;
    const unsigned short* gb1 = Bt + (size_t)(bn + srow + 16) * Kdim + kc;
    const int d0 = (w * 32) * 32, d1 = (w * 32 + 16) * 32;

    const int sw = ((g ^ ((lr >> 2) & 3)) & 3) * 8;

    auto stage = [&](int pp, int k0) {
        load_lds16(ga0 + k0, &As[pp][d0]);
        load_lds16(ga1 + k0, &As[pp][d1]);
        load_lds16(gb0 + k0, &Bs[pp][d0]);
        load_lds16(gb1 + k0, &Bs[pp][d1]);
    };
    auto compute = [&](int pp) {
        bf16x8 af[4], bfr[4];
        #pragma unroll
        for (int i = 0; i < 4; ++i)
            af[i] = *(const bf16x8*)&As[pp][(wr * 64 + i * 16 + lr) * 32 + sw];
        #pragma unroll
        for (int j = 0; j < 4; ++j)
            bfr[j] = *(const bf16x8*)&Bs[pp][(wc * 64 + j * 16 + lr) * 32 + sw];
        __builtin_amdgcn_s_setprio(1);
        #pragma unroll
        for (int i = 0; i < 4; ++i)
            #pragma unroll
            for (int j = 0; j < 4; ++j)
                acc[i][j] = mfma16(af[i], bfr[j], acc[i][j]);
        __builtin_amdgcn_s_setprio(0);
    };

    const int nk = Klocal >> 5;
    stage(0, koff);
    int p = 0;
    for (int s = 0; s < nk; ++s) {
        if (s + 1 < nk) {
            stage(p ^ 1, koff + (s + 1) * 32);
            asm volatile("s_waitcnt vmcnt(4)" ::: "memory");
        } else {
            asm volatile("s_waitcnt vmcnt(0)" ::: "memory");
        }
        __builtin_amdgcn_s_barrier();
        __builtin_amdgcn_sched_barrier(0);
        compute(p);
        __builtin_amdgcn_sched_barrier(0);
        __builtin_amdgcn_s_barrier();
        __builtin_amdgcn_sched_barrier(0);
        p ^= 1;
    }

    float* Cdst = (NSPLIT > 1 && z == 1) ? Cf2 : Cf;
    #pragma unroll
    for (int i = 0; i < 4; ++i) {
        const int row0 = bm + wr * 64 + i * 16 + 4 * g;
        #pragma unroll
        for (int j = 0; j < 4; ++j) {
            const int col = bn + wc * 64 + j * 16 + lr;
            float bv = (NSPLIT > 1 && z == 1) ? 0.f
                     : ((col < sp1) ? b0[col] : (col < sp2 ? b1[col - sp1] : b2[col - sp2]));
            float vv[4];
            #pragma unroll
            for (int r = 0; r < 4; ++r) vv[r] = apply_act<ACT>(acc[i][j][r] + bv);
            if constexpr (EPI == EPI_F32) {
                #pragma unroll
                for (int r = 0; r < 4; ++r) Cdst[(size_t)(row0 + r) * Ndim + col] = vv[r];
            } else if constexpr (EPI == EPI_BF16) {
                #pragma unroll
                for (int r = 0; r < 4; ++r) Cb[(size_t)(row0 + r) * Ndim + col] = bf16_rne(vv[r]);
            } else if constexpr (EPI == EPI_QKV) {
                if (col < 1536) {
                    #pragma unroll
                    for (int r = 0; r < 4; ++r) Cb[(size_t)(row0 + r) * 1536 + col] = bf16_rne(vv[r]);
                } else {
                    int c2 = col - 1536;
                    int hh2 = c2 >> 6, dd = c2 & 63;
                    int bb = rowb[row0];
                    if (row0 + 3 < Mtot && rowb[row0 + 3] == bb) {
                        int t0 = row0 - boffs[bb];
                        unsigned lo = (unsigned)bf16_rne(vv[0]) | ((unsigned)bf16_rne(vv[1]) << 16);
                        unsigned hi = (unsigned)bf16_rne(vv[2]) | ((unsigned)bf16_rne(vv[3]) << 16);
                        size_t idxv = (((size_t)bb * NH + hh2) * DH + dd) * T + t0;
                        *(uint2*)&Vt[idxv] = make_uint2(lo, hi);
                    } else {
                        #pragma unroll
                        for (int r = 0; r < 4; ++r) {
                            int rr = row0 + r;
                            if (rr < Mtot) {
                                int b2 = rowb[rr];
                                int t2 = rr - boffs[b2];
                                Vt[(((size_t)b2 * NH + hh2) * DH + dd) * T + t2] = bf16_rne(vv[r]);
                            }
                        }
                    }
                }
            } else {  // EPI_SPLIT2
                if (col < sp1) {
                    #pragma unroll
                    for (int r = 0; r < 4; ++r) Cb[(size_t)(row0 + r) * sp1 + col] = bf16_rne(vv[r]);
                } else {
                    #pragma unroll
                    for (int r = 0; r < 4; ++r)
                        Cb2[(size_t)(row0 + r) * n2w + (col - sp1)] = bf16_rne(vv[r]);
                }
            }
        }
    }
}

// ---------------- MFMA flash attention (compact rows) ----------------
#define C2 0.180336880111116670f      // 0.125 * log2(e)
#define MB2 14426.950408889634f       // 10000 * log2(e)

__global__ __launch_bounds__(256) void attn_mfma(
    const unsigned short* __restrict__ QK, const unsigned short* __restrict__ Vt,
    const int* __restrict__ Larr, const int* __restrict__ boffs,
    unsigned short* __restrict__ ctxb) {
    const int n = blockIdx.x;
    const int xcd = n & 7, k = n >> 3;
    const int p = xcd * 12 + k / 9, qt = k % 9;
    const int b = p / NH, h = p % NH;
    const int LbMM = Larr[b] + MM;
    if (qt * 64 >= LbMM) return;
    const int w = threadIdx.x >> 6, lane = threadIdx.x & 63;
    const int q0 = qt * 64 + w * 16;
    if (q0 >= LbMM) return;
    const int base = boffs[b];
    const int lr = lane & 15, g = lane >> 4;
    __shared__ unsigned short P[4][16][72];
    const unsigned short* qrow = QK + (size_t)(base + q0 + lr) * 1536 + h * 64;
    bf16x8 qf0 = *(const bf16x8*)(qrow + 8 * g);
    bf16x8 qf1 = *(const bf16x8*)(qrow + 32 + 8 * g);
    f32x4 ctx[4] = {};
    float m_run = -1e30f, l_run = 0.f;
    const size_t vbase = ((size_t)b * NH + h) * DH;
    for (int kt = 0; kt < LbMM; kt += 64) {
        f32x4 sf[4];
        #pragma unroll
        for (int i = 0; i < 4; ++i) {
            const unsigned short* krow =
                QK + (size_t)(base + kt + 16 * i + lr) * 1536 + 768 + h * 64;
            bf16x8 kf0 = *(const bf16x8*)(krow + 8 * g);
            bf16x8 kf1 = *(const bf16x8*)(krow + 32 + 8 * g);
            f32x4 s = {};
            s = mfma16(kf0, qf0, s);
            s = mfma16(kf1, qf1, s);
            sf[i] = s;
        }
        float tmax = -1e30f;
        #pragma unroll
        for (int i = 0; i < 4; ++i)
            #pragma unroll
            for (int r = 0; r < 4; ++r) {
                int key = kt + 16 * i + 4 * g + r;
                float v = sf[i][r] * C2 + (key < LbMM ? 0.f : -MB2);
                sf[i][r] = v;
                tmax = fmaxf(tmax, v);
            }
        tmax = fmaxf(tmax, __shfl_xor(tmax, 16));
        tmax = fmaxf(tmax, __shfl_xor(tmax, 32));
        float m_new = fmaxf(m_run, tmax);
        float scale = exp2f(m_run - m_new);
        m_run = m_new;
        float psum = 0.f;
        #pragma unroll
        for (int i = 0; i < 4; ++i)
            #pragma unroll
            for (int r = 0; r < 4; ++r) {
                float pv = exp2f(sf[i][r] - m_new);
                sf[i][r] = pv;
                psum += pv;
            }
        l_run = l_run * scale + psum;
        float f0 = __shfl(scale, 4 * g + 0);
        float f1 = __shfl(scale, 4 * g + 1);
        float f2 = __shfl(scale, 4 * g + 2);
        float f3 = __shfl(scale, 4 * g + 3);
        #pragma unroll
        for (int j = 0; j < 4; ++j) {
            ctx[j][0] *= f0; ctx[j][1] *= f1; ctx[j][2] *= f2; ctx[j][3] *= f3;
        }
        #pragma unroll
        for (int i = 0; i < 4; ++i) {
            unsigned lo = (unsigned)bf16_rne(sf[i][0]) | ((unsigned)bf16_rne(sf[i][1]) << 16);
            unsigned hi = (unsigned)bf16_rne(sf[i][2]) | ((unsigned)bf16_rne(sf[i][3]) << 16);
            *(unsigned*)&P[w][lr][16 * i + 4 * g] = lo;
            *(unsigned*)&P[w][lr][16 * i + 4 * g + 2] = hi;
        }
        asm volatile("s_waitcnt lgkmcnt(0)" ::: "memory");
        __builtin_amdgcn_sched_barrier(0);
        #pragma unroll
        for (int s2 = 0; s2 < 2; ++s2) {
            bf16x8 pa = *(const bf16x8*)&P[w][lr][32 * s2 + 8 * g];
            #pragma unroll
            for (int j = 0; j < 4; ++j) {
                const unsigned short* vrow =
                    Vt + (vbase + 16 * j + lr) * T + kt + 32 * s2 + 8 * g;
                bf16x8 vf = *(const bf16x8*)vrow;
                ctx[j] = mfma16(pa, vf, ctx[j]);
            }
        }
        asm volatile("s_waitcnt lgkmcnt(0)" ::: "memory");
        __builtin_amdgcn_sched_barrier(0);
    }
    l_run += __shfl_xor(l_run, 16);
    l_run += __shfl_xor(l_run, 32);
    float inv = 1.f / l_run;
    float i0 = __shfl(inv, 4 * g + 0);
    float i1 = __shfl(inv, 4 * g + 1);
    float i2 = __shfl(inv, 4 * g + 2);
    float i3 = __shfl(inv, 4 * g + 3);
    float sc[4] = {i0, i1, i2, i3};
    #pragma unroll
    for (int j = 0; j < 4; ++j)
        #pragma unroll
        for (int r = 0; r < 4; ++r) {
            int rl = q0 + 4 * g + r;
            if (rl < LbMM)
                ctxb[(size_t)(base + rl) * H + h * 64 + 16 * j + lr] =
                    bf16_rne(ctx[j][r] * sc[r]);
        }
}

// ---------------- residual + LN (delta = d1 + d2), float4, compact early-exit ----------------
__global__ void lnres_kernel(float* __restrict__ x, const float* __restrict__ d1,
                             const float* __restrict__ d2,
                             const float* __restrict__ s, const float* __restrict__ bvec,
                             unsigned short* __restrict__ xb, const int* __restrict__ mtotp) {
    int r = blockIdx.x;
    if (r >= mtotp[0]) return;
    int tid = threadIdx.x;
    __shared__ float4 row[H / 4];
    __shared__ float r1[256], r2[256];
    float lsum = 0.f, lsq = 0.f;
    size_t off4 = (size_t)r * (H / 4);
    const float4* x4 = (const float4*)x;
    const float4* d14 = (const float4*)d1;
    const float4* d24 = (const float4*)d2;
    if (tid < H / 4) {
        float4 a = x4[off4 + tid], bb = d14[off4 + tid], cc = d24[off4 + tid];
        float4 v = make_float4(a.x + bb.x + cc.x, a.y + bb.y + cc.y,
                               a.z + bb.z + cc.z, a.w + bb.w + cc.w);
        row[tid] = v;
        lsum = v.x + v.y + v.z + v.w;
        lsq = v.x * v.x + v.y * v.y + v.z * v.z + v.w * v.w;
    }
    r1[tid] = lsum; r2[tid] = lsq;
    __syncthreads();
    for (int ss = 128; ss > 0; ss >>= 1) {
        if (tid < ss) { r1[tid] += r1[tid + ss]; r2[tid] += r2[tid + ss]; }
        __syncthreads();
    }
    float mu = r1[0] / H;
    float var = r2[0] / H - mu * mu;
    float inv = rsqrtf(var + 1e-12f);
    if (tid < H / 4) {
        float4 v = row[tid];
        const float4 sv = ((const float4*)s)[tid];
        const float4 bv = ((const float4*)bvec)[tid];
        float4 o = make_float4((v.x - mu) * inv * sv.x + bv.x,
                               (v.y - mu) * inv * sv.y + bv.y,
                               (v.z - mu) * inv * sv.z + bv.z,
                               (v.w - mu) * inv * sv.w + bv.w);
        ((float4*)x)[off4 + tid] = o;
        ushort4 ob = make_ushort4(bf16_rne(o.x), bf16_rne(o.y), bf16_rne(o.z), bf16_rne(o.w));
        *(ushort4*)&xb[(size_t)r * H + tid * 4] = ob;
    }
}

// ---------------- masked softmax pooling (compact rows) ----------------
__global__ __launch_bounds__(256) void pool_kernel(
    const float* __restrict__ w0, const float* __restrict__ w1,
    const float* __restrict__ value, const int* __restrict__ ttarr,
    const int* __restrict__ boffs, float* __restrict__ out) {
    int b = blockIdx.x;
    int le = threadIdx.x & 31;
    int e = blockIdx.y * 32 + le;
    int tg = threadIdx.x >> 5;  // 0..7
    int base = boffs[b];
    int nrow = boffs[b + 1] - base;
    __shared__ int ttl[T];
    __shared__ float red[8][33];
    for (int t = threadIdx.x; t < nrow; t += 256) ttl[t] = ttarr[base + t];
    __syncthreads();
    float mx = -1e30f;
    for (int t = tg; t < nrow; t += 8) {
        if (ttl[t] == 1) continue;
        size_t idx = (size_t)(base + t) * E + e;
        float w = 1.f / (1.f + expf(-(w0[idx] + w1[idx])));
        mx = fmaxf(mx, w);
    }
    red[tg][le] = mx;
    __syncthreads();
    #pragma unroll
    for (int i = 0; i < 8; ++i) mx = fmaxf(mx, red[i][le]);
    float den = 0.f, num = 0.f;
    for (int t = tg; t < nrow; t += 8) {
        if (ttl[t] == 1) continue;
        size_t idx = (size_t)(base + t) * E + e;
        float w = 1.f / (1.f + expf(-(w0[idx] + w1[idx])));
        float ew = expf(w - mx);
        den += ew;
        num = fmaf(ew, value[idx], num);
    }
    __syncthreads();
    red[tg][le] = den;
    __syncthreads();
    float dtot = 0.f;
    #pragma unroll
    for (int i = 0; i < 8; ++i) dtot += red[i][le];
    __syncthreads();
    red[tg][le] = num;
    __syncthreads();
    float ntot = 0.f;
    #pragma unroll
    for (int i = 0; i < 8; ++i) ntot += red[i][le];
    if (tg == 0) out[(size_t)b * E + e] = fmaxf(ntot / dtot, 0.f);
}

// ---------------- host-side launch ----------------
extern "C" void kernel_launch(void* const* d_in, const int* in_sizes, int n_in,
                              void* d_out, int out_size, void* d_ws, size_t ws_size,
                              hipStream_t stream) {
    const int*   input_ids  = (const int*)d_in[0];
    const int*   token_type = (const int*)d_in[1];
    const int*   attn_mask  = (const int*)d_in[2];
    const float* word_emb   = (const float*)d_in[3];
    const float* pos_emb    = (const float*)d_in[4];
    const float* type_emb   = (const float*)d_in[5];
    const float* emb_ln_s   = (const float*)d_in[6];
    const float* emb_ln_b   = (const float*)d_in[7];
    const float* memory     = (const float*)d_in[8];
    const float* q_w  = (const float*)d_in[9];
    const float* q_b  = (const float*)d_in[10];
    const float* k_w  = (const float*)d_in[11];
    const float* k_b  = (const float*)d_in[12];
    const float* v_w  = (const float*)d_in[13];
    const float* v_b  = (const float*)d_in[14];
    const float* o_w  = (const float*)d_in[15];
    const float* o_b  = (const float*)d_in[16];
    const float* ln1_s = (const float*)d_in[17];
    const float* ln1_b = (const float*)d_in[18];
    const float* f_w1  = (const float*)d_in[19];
    const float* f_b1  = (const float*)d_in[20];
    const float* f_w2  = (const float*)d_in[21];
    const float* f_b2  = (const float*)d_in[22];
    const float* ln2_s = (const float*)d_in[23];
    const float* ln2_b = (const float*)d_in[24];
    const float* key_w1 = (const float*)d_in[25];
    const float* key_b1 = (const float*)d_in[26];
    const float* key_w2 = (const float*)d_in[27];
    const float* key_b2 = (const float*)d_in[28];
    const float* val_w1 = (const float*)d_in[29];
    const float* val_b1 = (const float*)d_in[30];
    const float* val_w2 = (const float*)d_in[31];
    const float* val_b2 = (const float*)d_in[32];
    float* out = (float*)d_out;

    char* ws = (char*)d_ws;
    size_t off = 0;
    auto alloc = [&](size_t bytes) {
        void* p = ws + off;
        off += (bytes + 255) & ~(size_t)255;
        return p;
    };
    const size_t BT  = (size_t)B * T;      // 4608 (worst-case rows)
    const size_t BTH = BT * H;

    int*   ord   = (int*)alloc((size_t)B * S * 4);
    int*   Larr  = (int*)alloc(64);
    int*   boff  = (int*)alloc((B + 1) * 4);
    int*   rowb  = (int*)alloc(BT * 4);
    int*   ttarr = (int*)alloc(BT * 4);
    float* x     = (float*)alloc(BTH * 4);
    unsigned short* xb   = (unsigned short*)alloc(BTH * 2);
    unsigned short* reg1 = (unsigned short*)alloc(BT * FF * 2);
    float* Bbuf  = (float*)alloc(BTH * 4);
    float* part1 = (float*)alloc(BTH * 4);
    unsigned short* wt = (unsigned short*)alloc((size_t)10354688 * 2);

    unsigned short* qkb  = reg1;                       // [BT][1536]
    unsigned short* Vtb  = reg1 + BT * 1536;           // [B][NH][DH][T]
    unsigned short* ctxb = reg1 + BT * 1536 + BTH;     // [BT][H]
    unsigned short* hb   = reg1;                       // [BT][FF] (FFN phase)
    unsigned short* key1b = reg1;                      // [BT][1536] (head phase)
    unsigned short* val1b = reg1 + BT * 1536;          // [BT][1024]
    float* valf = x;                                   // [BT][512] f32 (x dead by then)

    unsigned short* wt_qkv = wt;                       // [2304][768]
    unsigned short* wt_o  = wt + (size_t)2304 * 768;   // [768][768]
    unsigned short* wt_f1 = wt_o + (size_t)768 * 768;  // [3072][768]
    unsigned short* wt_f2 = wt_f1 + (size_t)3072 * 768;// [768][3072]
    unsigned short* wt_head = wt + (size_t)7077888;
    unsigned short* wt_kv1 = wt_head;                  // [2560][768]
    unsigned short* wt_k2 = wt_head + (size_t)2560 * 768;   // [512][1536]
    unsigned short* wt_v2 = wt_k2 + (size_t)512 * 1536;     // [512][1024]

    const int Mrows = (int)BT;
    const size_t HH = (size_t)H * H;
    const int BIG = 1 << 30;
    const int* mtotp = boff + B;

    hipLaunchKernelGGL(order_kernel, dim3(B), dim3(S), 0, stream, attn_mask, ord, Larr);
    hipLaunchKernelGGL(scan_kernel, dim3(1), dim3(256), 0, stream, Larr, boff, rowb);
    hipLaunchKernelGGL(embed_kernel, dim3(T, B), dim3(256), 0, stream,
                       input_ids, token_type, ord, Larr, boff, word_emb, pos_emb, type_emb,
                       memory, emb_ln_s, emb_ln_b, x, xb, ttarr);

    for (int l = 0; l < NL; ++l) {
        TTab tab;
        tab.d[0] = { q_w + l * HH,              0u,                              H,  H,  0    };
        tab.d[1] = { k_w + l * HH,              (unsigned)(768 * 768),           H,  H,  576  };
        tab.d[2] = { v_w + l * HH,              (unsigned)(1536 * 768),          H,  H,  1152 };
        tab.d[3] = { o_w + l * HH,              (unsigned)(2304 * 768),          H,  H,  1728 };
        tab.d[4] = { f_w1 + (size_t)l * H * FF, (unsigned)(3072 * 768),          H,  FF, 2304 };
        tab.d[5] = { f_w2 + (size_t)l * FF * H, (unsigned)(6144 * 768),          FF, H,  4608 };
        int ntiles = 6912;
        if (l == NL - 1) {
            tab.d[6] = { key_w1, 7077888u,                     H,     2 * H, 6912 };
            tab.d[7] = { val_w1, 7077888u + 1536u * 768u,      H,     2 * E, 8064 };
            tab.d[8] = { key_w2, 9043968u,                     2 * H, E,     8832 };
            tab.d[9] = { val_w2, 9830400u,                     2 * E, E,     9600 };
            tab.n = 10;
            ntiles = 10112;
        } else {
            tab.n = 6;
        }
        hipLaunchKernelGGL(transpose_all, dim3(ntiles), dim3(256), 0, stream, tab, wt);

        mfma_gemm<ACT_NONE, EPI_QKV, 1><<<dim3(18, 36), 256, 0, stream>>>(
            xb, wt_qkv, q_b + (size_t)l * H, k_b + (size_t)l * H, v_b + (size_t)l * H,
            768, 1536, nullptr, nullptr, qkb, nullptr, Vtb, 0, boff, rowb, Mrows, 2304, H);
        hipLaunchKernelGGL(attn_mfma, dim3(864), dim3(256), 0, stream,
                           qkb, Vtb, Larr, boff, ctxb);
        mfma_gemm<ACT_NONE, EPI_F32, 2><<<dim3(6, 36, 2), 256, 0, stream>>>(
            ctxb, wt_o, o_b + (size_t)l * H, nullptr, nullptr, BIG, BIG,
            Bbuf, part1, nullptr, nullptr, nullptr, 0, boff, rowb, Mrows, H, H);
        hipLaunchKernelGGL(lnres_kernel, dim3((int)BT), dim3(256), 0, stream,
                           x, Bbuf, part1, ln1_s + (size_t)l * H, ln1_b + (size_t)l * H, xb, mtotp);
        mfma_gemm<ACT_GELU, EPI_BF16, 1><<<dim3(24, 36), 256, 0, stream>>>(
            xb, wt_f1, f_b1 + (size_t)l * FF, nullptr, nullptr, BIG, BIG,
            nullptr, nullptr, hb, nullptr, nullptr, 0, boff, rowb, Mrows, FF, H);
        mfma_gemm<ACT_NONE, EPI_F32, 2><<<dim3(6, 36, 2), 256, 0, stream>>>(
            hb, wt_f2, f_b2 + (size_t)l * H, nullptr, nullptr, BIG, BIG,
            Bbuf, part1, nullptr, nullptr, nullptr, 0, boff, rowb, Mrows, H, FF);
        hipLaunchKernelGGL(lnres_kernel, dim3((int)BT), dim3(256), 0, stream,
                           x, Bbuf, part1, ln2_s + (size_t)l * H, ln2_b + (size_t)l * H, xb, mtotp);
    }

    // fused key1|val1 GEMM: N=2560, split epilogue
    mfma_gemm<ACT_RELU, EPI_SPLIT2, 1><<<dim3(20, 36), 256, 0, stream>>>(
        xb, wt_kv1, key_b1, val_b1, nullptr, 1536, BIG,
        nullptr, nullptr, key1b, val1b, nullptr, 1024, boff, rowb, Mrows, 2560, H);
    // key2: split-K, raw logits; sigmoid applied in pool
    mfma_gemm<ACT_NONE, EPI_F32, 2><<<dim3(4, 36, 2), 256, 0, stream>>>(
        key1b, wt_k2, key_b2, nullptr, nullptr, BIG, BIG,
        Bbuf, part1, nullptr, nullptr, nullptr, 0, boff, rowb, Mrows, 512, 1536);
    // val2: unsplit, tanh epilogue
    mfma_gemm<ACT_TANH, EPI_F32, 1><<<dim3(4, 36), 256, 0, stream>>>(
        val1b, wt_v2, val_b2, nullptr, nullptr, BIG, BIG,
        valf, nullptr, nullptr, nullptr, nullptr, 0, boff, rowb, Mrows, 512, 1024);
    hipLaunchKernelGGL(pool_kernel, dim3(B, E / 32), dim3(256), 0, stream,
                       Bbuf, part1, valf, ttarr, boff, out);
}

// Round 12
// 474.691 us; speedup vs baseline: 1.2414x; 1.0544x over previous
//
#include <hip/hip_runtime.h>
#include <hip/hip_bf16.h>

#define B 8
#define S 512
#define MM 64
#define T 576          // S + MM
#define H 768
#define NH 12
#define DH 64
#define FF 3072
#define E 512
#define NL 2

typedef __attribute__((ext_vector_type(8))) short bf16x8;
typedef __attribute__((ext_vector_type(4))) float f32x4;

__device__ inline unsigned short bf16_rne(float f) {
    unsigned u = __builtin_bit_cast(unsigned, f);
    unsigned r = u + 0x7FFFu + ((u >> 16) & 1u);
    return (unsigned short)(r >> 16);
}

__device__ inline f32x4 mfma16(bf16x8 a, bf16x8 b, f32x4 c) {
    return __builtin_amdgcn_mfma_f32_16x16x32_bf16(a, b, c, 0, 0, 0);
}

__device__ inline void load_lds16(const void* g, void* l) {
    __builtin_amdgcn_global_load_lds((const __attribute__((address_space(1))) void*)g,
                                     (__attribute__((address_space(3))) void*)l, 16, 0, 0);
}

// ---------------- order / argsort ----------------
__global__ void order_kernel(const int* __restrict__ mask, int* __restrict__ ord,
                             int* __restrict__ Larr) {
    __shared__ int ps[S];
    int b = blockIdx.x;
    int t = threadIdx.x;
    int mv = (mask[b * S + t] != 0) ? 1 : 0;
    ps[t] = mv;
    __syncthreads();
    for (int off = 1; off < S; off <<= 1) {
        int v = ps[t];
        int add = (t >= off) ? ps[t - off] : 0;
        __syncthreads();
        ps[t] = v + add;
        __syncthreads();
    }
    int L = ps[S - 1];
    int rank = mv ? (ps[t] - 1) : (L + (t - ps[t]));
    ord[b * S + rank] = t;
    if (t == 0) Larr[b] = L;
}

// ---------------- compact-offset scan ----------------
__global__ void scan_kernel(const int* __restrict__ Larr, int* __restrict__ boff,
                            int* __restrict__ rowb) {
    __shared__ int sb[B + 1];
    if (threadIdx.x == 0) {
        int acc = 0;
        for (int b = 0; b < B; ++b) { sb[b] = acc; boff[b] = acc; acc += Larr[b] + MM; }
        sb[B] = acc; boff[B] = acc;
    }
    __syncthreads();
    for (int r = threadIdx.x; r < B * T; r += blockDim.x) {
        int bb = 0;
        #pragma unroll
        for (int b2 = 1; b2 < B; ++b2) bb += (r >= sb[b2]) ? 1 : 0;
        rowb[r] = bb;
    }
}

// ---------------- embedding + LN (COMPACT rows) ----------------
__global__ void embed_kernel(const int* __restrict__ ids, const int* __restrict__ toktype,
                             const int* __restrict__ ord, const int* __restrict__ Larr,
                             const int* __restrict__ boff,
                             const float* __restrict__ word_emb, const float* __restrict__ pos_emb,
                             const float* __restrict__ type_emb, const float* __restrict__ memory,
                             const float* __restrict__ lns, const float* __restrict__ lnb,
                             float* __restrict__ x, unsigned short* __restrict__ xb,
                             int* __restrict__ ttarr) {
    int t = blockIdx.x;
    int b = blockIdx.y;
    int Lb = Larr[b];
    if (t >= Lb + MM) return;
    int row = boff[b] + t;
    int tid = threadIdx.x;
    int tt;
    const float* src;
    if (t < Lb) {
        int sp = ord[b * S + t];
        tt = toktype[b * S + sp];
        src = &word_emb[(size_t)ids[b * S + sp] * H];
    } else {
        tt = 1;
        src = &memory[(size_t)(t - Lb) * H];
    }
    __shared__ float rowv[H];
    __shared__ float r1[256], r2[256];
    float lsum = 0.f, lsq = 0.f;
    for (int hh = tid; hh < H; hh += 256) {
        float v = src[hh] + pos_emb[(size_t)t * H + hh] + type_emb[(size_t)tt * H + hh];
        rowv[hh] = v;
        lsum += v;
        lsq += v * v;
    }
    r1[tid] = lsum; r2[tid] = lsq;
    __syncthreads();
    for (int s = 128; s > 0; s >>= 1) {
        if (tid < s) { r1[tid] += r1[tid + s]; r2[tid] += r2[tid + s]; }
        __syncthreads();
    }
    float mu = r1[0] / H;
    float var = r2[0] / H - mu * mu;
    float inv = rsqrtf(var + 1e-12f);
    for (int hh = tid; hh < H; hh += 256) {
        float v = (rowv[hh] - mu) * inv * lns[hh] + lnb[hh];
        x[(size_t)row * H + hh] = v;
        xb[(size_t)row * H + hh] = bf16_rne(v);
    }
    if (tid == 0) ttarr[row] = tt;
}

// ---------------- activations ----------------
#define ACT_NONE 0
#define ACT_RELU 1
#define ACT_GELU 2
#define ACT_SIGMOID 3
#define ACT_TANH 4

template <int ACT>
__device__ inline float apply_act(float v) {
    if constexpr (ACT == ACT_RELU) return fmaxf(v, 0.f);
    else if constexpr (ACT == ACT_GELU) {
        float y = v * 0.70710678118654752f;
        float a = fabsf(y);
        float t = 1.f / (1.f + 0.3275911f * a);
        float poly = t * (0.254829592f + t * (-0.284496736f + t * (1.421413741f +
                     t * (-1.453152027f + t * 1.061405429f))));
        float e = poly * exp2f(-a * a * 1.4426950408889634f);
        float erfv = 1.f - e;
        erfv = (y < 0.f) ? -erfv : erfv;
        return 0.5f * v * (1.f + erfv);
    }
    else if constexpr (ACT == ACT_SIGMOID) return 1.f / (1.f + expf(-v));
    else if constexpr (ACT == ACT_TANH) return tanhf(v);
    else return v;
}

// ---------------- fused weight transpose (ALL weights, one launch) ----------------
struct TDesc { const float* src; unsigned dstoff; int Kd; int Nd; int tile0; };
struct TTab { TDesc d[16]; int n; };

__global__ __launch_bounds__(256) void transpose_all(TTab tab, unsigned short* __restrict__ dstbase) {
    int tile = blockIdx.x;
    int mi = 0;
    #pragma unroll
    for (int i = 1; i < 16; ++i)
        if (i < tab.n && tab.d[i].tile0 <= tile) mi = i;
    TDesc d = tab.d[mi];
    int rel = tile - d.tile0;
    int tilesK = d.Kd >> 5;
    int kt = rel % tilesK, nt = rel / tilesK;
    __shared__ float ts[32][33];
    int k0 = kt * 32, n0 = nt * 32;
    int tx = threadIdx.x & 31, ty = threadIdx.x >> 5;  // 32 x 8
    #pragma unroll
    for (int r = 0; r < 4; ++r) {
        int kk = ty + r * 8;
        ts[kk][tx] = d.src[(size_t)(k0 + kk) * d.Nd + n0 + tx];
    }
    __syncthreads();
    unsigned short* Wt = dstbase + d.dstoff;
    #pragma unroll
    for (int r = 0; r < 4; ++r) {
        int nn = ty + r * 8;
        Wt[(size_t)(n0 + nn) * d.Kd + k0 + tx] = bf16_rne(ts[tx][nn]);
    }
}

// ---------------- MFMA GEMM (compact rows; identity mapping; NSPLIT up to 4) ----------------
#define EPI_F32   0
#define EPI_BF16  1
#define EPI_QKV   2
#define EPI_SPLIT2 3

template <int ACT, int EPI, int NSPLIT>
__global__ __launch_bounds__(256) void mfma_gemm(
    const unsigned short* __restrict__ A, const unsigned short* __restrict__ Bt,
    const float* __restrict__ b0, const float* __restrict__ b1, const float* __restrict__ b2,
    int sp1, int sp2,
    float* __restrict__ Cf, float* __restrict__ Cf2,
    float* __restrict__ Cf3, float* __restrict__ Cf4,
    unsigned short* __restrict__ Cb, unsigned short* __restrict__ Cb2,
    unsigned short* __restrict__ Vt, int n2w,
    const int* __restrict__ boffs, const int* __restrict__ rowb,
    int Mdim, int Ndim, int Kdim) {
    __shared__ unsigned short As[2][128 * 32];
    __shared__ unsigned short Bs[2][128 * 32];

    const int bn = blockIdx.x * 128, bm = blockIdx.y * 128;

    const int Mtot = boffs[B];
    if (bm >= Mtot) return;              // compacted: suffix blocks retire (uniform mod-8)

    const int z = (NSPLIT > 1) ? blockIdx.z : 0;
    const int Klocal = Kdim / NSPLIT;
    const int koff = z * Klocal;

    const int tid = threadIdx.x;
    const int w = tid >> 6, lane = tid & 63;
    const int lr = lane & 15, g = lane >> 4;
    const int wr = w >> 1, wc = w & 1;
    f32x4 acc[4][4] = {};

    const int srow = w * 32 + (lane >> 2);
    const int kc = (((lane & 3) ^ ((lane >> 4) & 3)) * 8);
    const unsigned short* ga0 = A + (size_t)(bm + srow) * Kdim + kc;
    const unsigned short* ga1 = A + (size_t)(bm + srow + 16) * Kdim + kc;
    const unsigned short* gb0 = Bt + (size_t)(bn + srow) * Kdim + kc;
    const unsigned short* gb1 = Bt + (size_t)(bn + srow + 16) * Kdim + kc;
    const int d0 = (w * 32) * 32, d1 = (w * 32 + 16) * 32;

    const int sw = ((g ^ ((lr >> 2) & 3)) & 3) * 8;

    auto stage = [&](int pp, int k0) {
        load_lds16(ga0 + k0, &As[pp][d0]);
        load_lds16(ga1 + k0, &As[pp][d1]);
        load_lds16(gb0 + k0, &Bs[pp][d0]);
        load_lds16(gb1 + k0, &Bs[pp][d1]);
    };
    auto compute = [&](int pp) {
        bf16x8 af[4], bfr[4];
        #pragma unroll
        for (int i = 0; i < 4; ++i)
            af[i] = *(const bf16x8*)&As[pp][(wr * 64 + i * 16 + lr) * 32 + sw];
        #pragma unroll
        for (int j = 0; j < 4; ++j)
            bfr[j] = *(const bf16x8*)&Bs[pp][(wc * 64 + j * 16 + lr) * 32 + sw];
        __builtin_amdgcn_s_setprio(1);
        #pragma unroll
        for (int i = 0; i < 4; ++i)
            #pragma unroll
            for (int j = 0; j < 4; ++j)
                acc[i][j] = mfma16(af[i], bfr[j], acc[i][j]);
        __builtin_amdgcn_s_setprio(0);
    };

    const int nk = Klocal >> 5;
    stage(0, koff);
    int p = 0;
    for (int s = 0; s < nk; ++s) {
        if (s + 1 < nk) {
            stage(p ^ 1, koff + (s + 1) * 32);
            asm volatile("s_waitcnt vmcnt(4)" ::: "memory");
        } else {
            asm volatile("s_waitcnt vmcnt(0)" ::: "memory");
        }
        __builtin_amdgcn_s_barrier();
        __builtin_amdgcn_sched_barrier(0);
        compute(p);
        __builtin_amdgcn_sched_barrier(0);
        __builtin_amdgcn_s_barrier();
        __builtin_amdgcn_sched_barrier(0);
        p ^= 1;
    }

    float* Cdst = (z == 0) ? Cf : (z == 1) ? Cf2 : (z == 2) ? Cf3 : Cf4;
    #pragma unroll
    for (int i = 0; i < 4; ++i) {
        const int row0 = bm + wr * 64 + i * 16 + 4 * g;
        #pragma unroll
        for (int j = 0; j < 4; ++j) {
            const int col = bn + wc * 64 + j * 16 + lr;
            float bv = (NSPLIT > 1 && z != 0) ? 0.f
                     : ((col < sp1) ? b0[col] : (col < sp2 ? b1[col - sp1] : b2[col - sp2]));
            float vv[4];
            #pragma unroll
            for (int r = 0; r < 4; ++r) vv[r] = apply_act<ACT>(acc[i][j][r] + bv);
            if constexpr (EPI == EPI_F32) {
                #pragma unroll
                for (int r = 0; r < 4; ++r) Cdst[(size_t)(row0 + r) * Ndim + col] = vv[r];
            } else if constexpr (EPI == EPI_BF16) {
                #pragma unroll
                for (int r = 0; r < 4; ++r) Cb[(size_t)(row0 + r) * Ndim + col] = bf16_rne(vv[r]);
            } else if constexpr (EPI == EPI_QKV) {
                if (col < 1536) {
                    #pragma unroll
                    for (int r = 0; r < 4; ++r) Cb[(size_t)(row0 + r) * 1536 + col] = bf16_rne(vv[r]);
                } else {
                    int c2 = col - 1536;
                    int hh2 = c2 >> 6, dd = c2 & 63;
                    int bb = rowb[row0];
                    if (row0 + 3 < Mtot && rowb[row0 + 3] == bb) {
                        int t0 = row0 - boffs[bb];
                        unsigned lo = (unsigned)bf16_rne(vv[0]) | ((unsigned)bf16_rne(vv[1]) << 16);
                        unsigned hi = (unsigned)bf16_rne(vv[2]) | ((unsigned)bf16_rne(vv[3]) << 16);
                        size_t idxv = (((size_t)bb * NH + hh2) * DH + dd) * T + t0;
                        *(uint2*)&Vt[idxv] = make_uint2(lo, hi);
                    } else {
                        #pragma unroll
                        for (int r = 0; r < 4; ++r) {
                            int rr = row0 + r;
                            if (rr < Mtot) {
                                int b2 = rowb[rr];
                                int t2 = rr - boffs[b2];
                                Vt[(((size_t)b2 * NH + hh2) * DH + dd) * T + t2] = bf16_rne(vv[r]);
                            }
                        }
                    }
                }
            } else {  // EPI_SPLIT2
                if (col < sp1) {
                    #pragma unroll
                    for (int r = 0; r < 4; ++r) Cb[(size_t)(row0 + r) * sp1 + col] = bf16_rne(vv[r]);
                } else {
                    #pragma unroll
                    for (int r = 0; r < 4; ++r)
                        Cb2[(size_t)(row0 + r) * n2w + (col - sp1)] = bf16_rne(vv[r]);
                }
            }
        }
    }
}

// ---------------- MFMA flash attention (compact rows) ----------------
#define C2 0.180336880111116670f      // 0.125 * log2(e)
#define MB2 14426.950408889634f       // 10000 * log2(e)

__global__ __launch_bounds__(256) void attn_mfma(
    const unsigned short* __restrict__ QK, const unsigned short* __restrict__ Vt,
    const int* __restrict__ Larr, const int* __restrict__ boffs,
    unsigned short* __restrict__ ctxb) {
    const int n = blockIdx.x;
    const int xcd = n & 7, k = n >> 3;
    const int p = xcd * 12 + k / 9, qt = k % 9;
    const int b = p / NH, h = p % NH;
    const int LbMM = Larr[b] + MM;
    if (qt * 64 >= LbMM) return;
    const int w = threadIdx.x >> 6, lane = threadIdx.x & 63;
    const int q0 = qt * 64 + w * 16;
    if (q0 >= LbMM) return;
    const int base = boffs[b];
    const int lr = lane & 15, g = lane >> 4;
    __shared__ unsigned short P[4][16][72];
    const unsigned short* qrow = QK + (size_t)(base + q0 + lr) * 1536 + h * 64;
    bf16x8 qf0 = *(const bf16x8*)(qrow + 8 * g);
    bf16x8 qf1 = *(const bf16x8*)(qrow + 32 + 8 * g);
    f32x4 ctx[4] = {};
    float m_run = -1e30f, l_run = 0.f;
    const size_t vbase = ((size_t)b * NH + h) * DH;
    for (int kt = 0; kt < LbMM; kt += 64) {
        f32x4 sf[4];
        #pragma unroll
        for (int i = 0; i < 4; ++i) {
            const unsigned short* krow =
                QK + (size_t)(base + kt + 16 * i + lr) * 1536 + 768 + h * 64;
            bf16x8 kf0 = *(const bf16x8*)(krow + 8 * g);
            bf16x8 kf1 = *(const bf16x8*)(krow + 32 + 8 * g);
            f32x4 s = {};
            s = mfma16(kf0, qf0, s);
            s = mfma16(kf1, qf1, s);
            sf[i] = s;
        }
        float tmax = -1e30f;
        #pragma unroll
        for (int i = 0; i < 4; ++i)
            #pragma unroll
            for (int r = 0; r < 4; ++r) {
                int key = kt + 16 * i + 4 * g + r;
                float v = sf[i][r] * C2 + (key < LbMM ? 0.f : -MB2);
                sf[i][r] = v;
                tmax = fmaxf(tmax, v);
            }
        tmax = fmaxf(tmax, __shfl_xor(tmax, 16));
        tmax = fmaxf(tmax, __shfl_xor(tmax, 32));
        float m_new = fmaxf(m_run, tmax);
        float scale = exp2f(m_run - m_new);
        m_run = m_new;
        float psum = 0.f;
        #pragma unroll
        for (int i = 0; i < 4; ++i)
            #pragma unroll
            for (int r = 0; r < 4; ++r) {
                float pv = exp2f(sf[i][r] - m_new);
                sf[i][r] = pv;
                psum += pv;
            }
        l_run = l_run * scale + psum;
        float f0 = __shfl(scale, 4 * g + 0);
        float f1 = __shfl(scale, 4 * g + 1);
        float f2 = __shfl(scale, 4 * g + 2);
        float f3 = __shfl(scale, 4 * g + 3);
        #pragma unroll
        for (int j = 0; j < 4; ++j) {
            ctx[j][0] *= f0; ctx[j][1] *= f1; ctx[j][2] *= f2; ctx[j][3] *= f3;
        }
        #pragma unroll
        for (int i = 0; i < 4; ++i) {
            unsigned lo = (unsigned)bf16_rne(sf[i][0]) | ((unsigned)bf16_rne(sf[i][1]) << 16);
            unsigned hi = (unsigned)bf16_rne(sf[i][2]) | ((unsigned)bf16_rne(sf[i][3]) << 16);
            *(unsigned*)&P[w][lr][16 * i + 4 * g] = lo;
            *(unsigned*)&P[w][lr][16 * i + 4 * g + 2] = hi;
        }
        asm volatile("s_waitcnt lgkmcnt(0)" ::: "memory");
        __builtin_amdgcn_sched_barrier(0);
        #pragma unroll
        for (int s2 = 0; s2 < 2; ++s2) {
            bf16x8 pa = *(const bf16x8*)&P[w][lr][32 * s2 + 8 * g];
            #pragma unroll
            for (int j = 0; j < 4; ++j) {
                const unsigned short* vrow =
                    Vt + (vbase + 16 * j + lr) * T + kt + 32 * s2 + 8 * g;
                bf16x8 vf = *(const bf16x8*)vrow;
                ctx[j] = mfma16(pa, vf, ctx[j]);
            }
        }
        asm volatile("s_waitcnt lgkmcnt(0)" ::: "memory");
        __builtin_amdgcn_sched_barrier(0);
    }
    l_run += __shfl_xor(l_run, 16);
    l_run += __shfl_xor(l_run, 32);
    float inv = 1.f / l_run;
    float i0 = __shfl(inv, 4 * g + 0);
    float i1 = __shfl(inv, 4 * g + 1);
    float i2 = __shfl(inv, 4 * g + 2);
    float i3 = __shfl(inv, 4 * g + 3);
    float sc[4] = {i0, i1, i2, i3};
    #pragma unroll
    for (int j = 0; j < 4; ++j)
        #pragma unroll
        for (int r = 0; r < 4; ++r) {
            int rl = q0 + 4 * g + r;
            if (rl < LbMM)
                ctxb[(size_t)(base + rl) * H + h * 64 + 16 * j + lr] =
                    bf16_rne(ctx[j][r] * sc[r]);
        }
}

// ---------------- residual + LN (delta = d1+d2+d3+d4), float4, compact ----------------
__global__ void lnres_kernel(float* __restrict__ x, const float* __restrict__ d1,
                             const float* __restrict__ d2, const float* __restrict__ d3,
                             const float* __restrict__ d4,
                             const float* __restrict__ s, const float* __restrict__ bvec,
                             unsigned short* __restrict__ xb, const int* __restrict__ mtotp) {
    int r = blockIdx.x;
    if (r >= mtotp[0]) return;
    int tid = threadIdx.x;
    __shared__ float4 row[H / 4];
    __shared__ float r1[256], r2[256];
    float lsum = 0.f, lsq = 0.f;
    size_t off4 = (size_t)r * (H / 4);
    if (tid < H / 4) {
        float4 a = ((const float4*)x)[off4 + tid];
        float4 p1 = ((const float4*)d1)[off4 + tid];
        float4 p2 = ((const float4*)d2)[off4 + tid];
        float4 p3 = ((const float4*)d3)[off4 + tid];
        float4 p4 = ((const float4*)d4)[off4 + tid];
        float4 v = make_float4(a.x + p1.x + p2.x + p3.x + p4.x,
                               a.y + p1.y + p2.y + p3.y + p4.y,
                               a.z + p1.z + p2.z + p3.z + p4.z,
                               a.w + p1.w + p2.w + p3.w + p4.w);
        row[tid] = v;
        lsum = v.x + v.y + v.z + v.w;
        lsq = v.x * v.x + v.y * v.y + v.z * v.z + v.w * v.w;
    }
    r1[tid] = lsum; r2[tid] = lsq;
    __syncthreads();
    for (int ss = 128; ss > 0; ss >>= 1) {
        if (tid < ss) { r1[tid] += r1[tid + ss]; r2[tid] += r2[tid + ss]; }
        __syncthreads();
    }
    float mu = r1[0] / H;
    float var = r2[0] / H - mu * mu;
    float inv = rsqrtf(var + 1e-12f);
    if (tid < H / 4) {
        float4 v = row[tid];
        const float4 sv = ((const float4*)s)[tid];
        const float4 bv = ((const float4*)bvec)[tid];
        float4 o = make_float4((v.x - mu) * inv * sv.x + bv.x,
                               (v.y - mu) * inv * sv.y + bv.y,
                               (v.z - mu) * inv * sv.z + bv.z,
                               (v.w - mu) * inv * sv.w + bv.w);
        ((float4*)x)[off4 + tid] = o;
        ushort4 ob = make_ushort4(bf16_rne(o.x), bf16_rne(o.y), bf16_rne(o.z), bf16_rne(o.w));
        *(ushort4*)&xb[(size_t)r * H + tid * 4] = ob;
    }
}

// ---------------- masked softmax pooling (4-way split partials; sigma/tanh here) ----------------
__global__ __launch_bounds__(256) void pool_kernel(
    const float* __restrict__ w0, const float* __restrict__ w1,
    const float* __restrict__ w2, const float* __restrict__ w3,
    const float* __restrict__ v0, const float* __restrict__ v1,
    const float* __restrict__ v2, const float* __restrict__ v3,
    const int* __restrict__ ttarr, const int* __restrict__ boffs,
    float* __restrict__ out) {
    int b = blockIdx.x;
    int le = threadIdx.x & 31;
    int e = blockIdx.y * 32 + le;
    int tg = threadIdx.x >> 5;  // 0..7
    int base = boffs[b];
    int nrow = boffs[b + 1] - base;
    __shared__ int ttl[T];
    __shared__ float red[8][33];
    for (int t = threadIdx.x; t < nrow; t += 256) ttl[t] = ttarr[base + t];
    __syncthreads();
    float mx = -1e30f;
    for (int t = tg; t < nrow; t += 8) {
        if (ttl[t] == 1) continue;
        size_t idx = (size_t)(base + t) * E + e;
        float w = 1.f / (1.f + expf(-(w0[idx] + w1[idx] + w2[idx] + w3[idx])));
        mx = fmaxf(mx, w);
    }
    red[tg][le] = mx;
    __syncthreads();
    #pragma unroll
    for (int i = 0; i < 8; ++i) mx = fmaxf(mx, red[i][le]);
    float den = 0.f, num = 0.f;
    for (int t = tg; t < nrow; t += 8) {
        if (ttl[t] == 1) continue;
        size_t idx = (size_t)(base + t) * E + e;
        float w = 1.f / (1.f + expf(-(w0[idx] + w1[idx] + w2[idx] + w3[idx])));
        float vval = tanhf(v0[idx] + v1[idx] + v2[idx] + v3[idx]);
        float ew = expf(w - mx);
        den += ew;
        num = fmaf(ew, vval, num);
    }
    __syncthreads();
    red[tg][le] = den;
    __syncthreads();
    float dtot = 0.f;
    #pragma unroll
    for (int i = 0; i < 8; ++i) dtot += red[i][le];
    __syncthreads();
    red[tg][le] = num;
    __syncthreads();
    float ntot = 0.f;
    #pragma unroll
    for (int i = 0; i < 8; ++i) ntot += red[i][le];
    if (tg == 0) out[(size_t)b * E + e] = fmaxf(ntot / dtot, 0.f);
}

// ---------------- host-side launch ----------------
extern "C" void kernel_launch(void* const* d_in, const int* in_sizes, int n_in,
                              void* d_out, int out_size, void* d_ws, size_t ws_size,
                              hipStream_t stream) {
    const int*   input_ids  = (const int*)d_in[0];
    const int*   token_type = (const int*)d_in[1];
    const int*   attn_mask  = (const int*)d_in[2];
    const float* word_emb   = (const float*)d_in[3];
    const float* pos_emb    = (const float*)d_in[4];
    const float* type_emb   = (const float*)d_in[5];
    const float* emb_ln_s   = (const float*)d_in[6];
    const float* emb_ln_b   = (const float*)d_in[7];
    const float* memory     = (const float*)d_in[8];
    const float* q_w  = (const float*)d_in[9];
    const float* q_b  = (const float*)d_in[10];
    const float* k_w  = (const float*)d_in[11];
    const float* k_b  = (const float*)d_in[12];
    const float* v_w  = (const float*)d_in[13];
    const float* v_b  = (const float*)d_in[14];
    const float* o_w  = (const float*)d_in[15];
    const float* o_b  = (const float*)d_in[16];
    const float* ln1_s = (const float*)d_in[17];
    const float* ln1_b = (const float*)d_in[18];
    const float* f_w1  = (const float*)d_in[19];
    const float* f_b1  = (const float*)d_in[20];
    const float* f_w2  = (const float*)d_in[21];
    const float* f_b2  = (const float*)d_in[22];
    const float* ln2_s = (const float*)d_in[23];
    const float* ln2_b = (const float*)d_in[24];
    const float* key_w1 = (const float*)d_in[25];
    const float* key_b1 = (const float*)d_in[26];
    const float* key_w2 = (const float*)d_in[27];
    const float* key_b2 = (const float*)d_in[28];
    const float* val_w1 = (const float*)d_in[29];
    const float* val_b1 = (const float*)d_in[30];
    const float* val_w2 = (const float*)d_in[31];
    const float* val_b2 = (const float*)d_in[32];
    float* out = (float*)d_out;

    char* ws = (char*)d_ws;
    size_t off = 0;
    auto alloc = [&](size_t bytes) {
        void* p = ws + off;
        off += (bytes + 255) & ~(size_t)255;
        return p;
    };
    const size_t BT  = (size_t)B * T;      // 4608 (worst-case rows)
    const size_t BTH = BT * H;

    int*   ord   = (int*)alloc((size_t)B * S * 4);
    int*   Larr  = (int*)alloc(64);
    int*   boff  = (int*)alloc((B + 1) * 4);
    int*   rowb  = (int*)alloc(BT * 4);
    int*   ttarr = (int*)alloc(BT * 4);
    float* x     = (float*)alloc(BTH * 4);
    unsigned short* xb   = (unsigned short*)alloc(BTH * 2);
    unsigned short* reg1 = (unsigned short*)alloc(BT * FF * 2);
    float* P0 = (float*)alloc(BTH * 4);
    float* P1 = (float*)alloc(BTH * 4);
    float* P2 = (float*)alloc(BTH * 4);
    float* P3 = (float*)alloc(BTH * 4);
    float* V0 = (float*)alloc(BT * E * 4);
    float* V1 = (float*)alloc(BT * E * 4);
    float* V2 = (float*)alloc(BT * E * 4);
    float* V3 = (float*)alloc(BT * E * 4);
    // wt: layer0 (7,077,888) + layer1 (7,077,888) + head (3,276,800)
    unsigned short* wt = (unsigned short*)alloc((size_t)17432576 * 2);

    unsigned short* qkb  = reg1;                       // [BT][1536]
    unsigned short* Vtb  = reg1 + BT * 1536;           // [B][NH][DH][T]
    unsigned short* ctxb = reg1 + BT * 1536 + BTH;     // [BT][H]
    unsigned short* hb   = reg1;                       // [BT][FF] (FFN phase)
    unsigned short* key1b = reg1;                      // [BT][1536] (head phase)
    unsigned short* val1b = reg1 + BT * 1536;          // [BT][1024]

    unsigned short* wt_head = wt + (size_t)14155776;
    unsigned short* wt_kv1 = wt_head;                       // [2560][768]
    unsigned short* wt_k2 = wt_head + (size_t)2560 * 768;   // [512][1536]
    unsigned short* wt_v2 = wt_k2 + (size_t)512 * 1536;     // [512][1024]

    const int Mrows = (int)BT;
    const size_t HH = (size_t)H * H;
    const int BIG = 1 << 30;
    const int* mtotp = boff + B;

    hipLaunchKernelGGL(order_kernel, dim3(B), dim3(S), 0, stream, attn_mask, ord, Larr);
    hipLaunchKernelGGL(scan_kernel, dim3(1), dim3(256), 0, stream, Larr, boff, rowb);

    // one upfront transpose for ALL weights (2 layers + head)
    {
        TTab tab;
        tab.n = 16;
        for (int l = 0; l < NL; ++l) {
            unsigned base = (unsigned)(l * 7077888);
            int t0 = l * 6912;
            tab.d[l * 6 + 0] = { q_w + l * HH,              base,                        H,  H,  t0        };
            tab.d[l * 6 + 1] = { k_w + l * HH,              base + 768u * 768u,          H,  H,  t0 + 576  };
            tab.d[l * 6 + 2] = { v_w + l * HH,              base + 1536u * 768u,         H,  H,  t0 + 1152 };
            tab.d[l * 6 + 3] = { o_w + l * HH,              base + 2304u * 768u,         H,  H,  t0 + 1728 };
            tab.d[l * 6 + 4] = { f_w1 + (size_t)l * H * FF, base + 3072u * 768u,         H,  FF, t0 + 2304 };
            tab.d[l * 6 + 5] = { f_w2 + (size_t)l * FF * H, base + 6144u * 768u,         FF, H,  t0 + 4608 };
        }
        tab.d[12] = { key_w1, 14155776u,                    H,     2 * H, 13824 };
        tab.d[13] = { val_w1, 14155776u + 1536u * 768u,     H,     2 * E, 14976 };
        tab.d[14] = { key_w2, 16121856u,                    2 * H, E,     15744 };
        tab.d[15] = { val_w2, 16908288u,                    2 * E, E,     16512 };
        hipLaunchKernelGGL(transpose_all, dim3(17024), dim3(256), 0, stream, tab, wt);
    }

    hipLaunchKernelGGL(embed_kernel, dim3(T, B), dim3(256), 0, stream,
                       input_ids, token_type, ord, Larr, boff, word_emb, pos_emb, type_emb,
                       memory, emb_ln_s, emb_ln_b, x, xb, ttarr);

    for (int l = 0; l < NL; ++l) {
        unsigned short* wt_l   = wt + (size_t)l * 7077888;
        unsigned short* wt_qkv = wt_l;
        unsigned short* wt_o   = wt_l + (size_t)2304 * 768;
        unsigned short* wt_f1  = wt_o + (size_t)768 * 768;
        unsigned short* wt_f2  = wt_f1 + (size_t)3072 * 768;

        mfma_gemm<ACT_NONE, EPI_QKV, 1><<<dim3(18, 36), 256, 0, stream>>>(
            xb, wt_qkv, q_b + (size_t)l * H, k_b + (size_t)l * H, v_b + (size_t)l * H,
            768, 1536, nullptr, nullptr, nullptr, nullptr, qkb, nullptr, Vtb, 0,
            boff, rowb, Mrows, 2304, H);
        hipLaunchKernelGGL(attn_mfma, dim3(864), dim3(256), 0, stream,
                           qkb, Vtb, Larr, boff, ctxb);
        mfma_gemm<ACT_NONE, EPI_F32, 4><<<dim3(6, 36, 4), 256, 0, stream>>>(
            ctxb, wt_o, o_b + (size_t)l * H, nullptr, nullptr, BIG, BIG,
            P0, P1, P2, P3, nullptr, nullptr, nullptr, 0, boff, rowb, Mrows, H, H);
        hipLaunchKernelGGL(lnres_kernel, dim3((int)BT), dim3(256), 0, stream,
                           x, P0, P1, P2, P3, ln1_s + (size_t)l * H, ln1_b + (size_t)l * H,
                           xb, mtotp);
        mfma_gemm<ACT_GELU, EPI_BF16, 1><<<dim3(24, 36), 256, 0, stream>>>(
            xb, wt_f1, f_b1 + (size_t)l * FF, nullptr, nullptr, BIG, BIG,
            nullptr, nullptr, nullptr, nullptr, hb, nullptr, nullptr, 0,
            boff, rowb, Mrows, FF, H);
        mfma_gemm<ACT_NONE, EPI_F32, 4><<<dim3(6, 36, 4), 256, 0, stream>>>(
            hb, wt_f2, f_b2 + (size_t)l * H, nullptr, nullptr, BIG, BIG,
            P0, P1, P2, P3, nullptr, nullptr, nullptr, 0, boff, rowb, Mrows, H, FF);
        hipLaunchKernelGGL(lnres_kernel, dim3((int)BT), dim3(256), 0, stream,
                           x, P0, P1, P2, P3, ln2_s + (size_t)l * H, ln2_b + (size_t)l * H,
                           xb, mtotp);
    }

    // fused key1|val1 GEMM: N=2560, split epilogue
    mfma_gemm<ACT_RELU, EPI_SPLIT2, 1><<<dim3(20, 36), 256, 0, stream>>>(
        xb, wt_kv1, key_b1, val_b1, nullptr, 1536, BIG,
        nullptr, nullptr, nullptr, nullptr, key1b, val1b, nullptr, 1024,
        boff, rowb, Mrows, 2560, H);
    // key2: 4-way split-K raw logits; sigmoid in pool
    mfma_gemm<ACT_NONE, EPI_F32, 4><<<dim3(4, 36, 4), 256, 0, stream>>>(
        key1b, wt_k2, key_b2, nullptr, nullptr, BIG, BIG,
        P0, P1, P2, P3, nullptr, nullptr, nullptr, 0, boff, rowb, Mrows, 512, 1536);
    // val2: 4-way split-K raw; tanh in pool
    mfma_gemm<ACT_NONE, EPI_F32, 4><<<dim3(4, 36, 4), 256, 0, stream>>>(
        val1b, wt_v2, val_b2, nullptr, nullptr, BIG, BIG,
        V0, V1, V2, V3, nullptr, nullptr, nullptr, 0, boff, rowb, Mrows, 512, 1024);
    hipLaunchKernelGGL(pool_kernel, dim3(B, E / 32), dim3(256), 0, stream,
                       P0, P1, P2, P3, V0, V1, V2, V3, ttarr, boff, out);
}

// Round 13
// 463.474 us; speedup vs baseline: 1.2714x; 1.0242x over previous
//
#include <hip/hip_runtime.h>
#include <hip/hip_bf16.h>

#define B 8
#define S 512
#define MM 64
#define T 576          // S + MM
#define H 768
#define NH 12
#define DH 64
#define FF 3072
#define E 512
#define NL 2

typedef __attribute__((ext_vector_type(8))) short bf16x8;
typedef __attribute__((ext_vector_type(4))) float f32x4;

__device__ inline unsigned short bf16_rne(float f) {
    unsigned u = __builtin_bit_cast(unsigned, f);
    unsigned r = u + 0x7FFFu + ((u >> 16) & 1u);
    return (unsigned short)(r >> 16);
}

__device__ inline f32x4 mfma16(bf16x8 a, bf16x8 b, f32x4 c) {
    return __builtin_amdgcn_mfma_f32_16x16x32_bf16(a, b, c, 0, 0, 0);
}

__device__ inline void load_lds16(const void* g, void* l) {
    __builtin_amdgcn_global_load_lds((const __attribute__((address_space(1))) void*)g,
                                     (__attribute__((address_space(3))) void*)l, 16, 0, 0);
}

// ---------------- order / argsort ----------------
__global__ void order_kernel(const int* __restrict__ mask, int* __restrict__ ord,
                             int* __restrict__ Larr) {
    __shared__ int ps[S];
    int b = blockIdx.x;
    int t = threadIdx.x;
    int mv = (mask[b * S + t] != 0) ? 1 : 0;
    ps[t] = mv;
    __syncthreads();
    for (int off = 1; off < S; off <<= 1) {
        int v = ps[t];
        int add = (t >= off) ? ps[t - off] : 0;
        __syncthreads();
        ps[t] = v + add;
        __syncthreads();
    }
    int L = ps[S - 1];
    int rank = mv ? (ps[t] - 1) : (L + (t - ps[t]));
    ord[b * S + rank] = t;
    if (t == 0) Larr[b] = L;
}

// ---------------- embedding + LN (COMPACT rows; inline boff; (0,0) block writes tables) ----------------
__global__ void embed_kernel(const int* __restrict__ ids, const int* __restrict__ toktype,
                             const int* __restrict__ ord, const int* __restrict__ Larr,
                             int* __restrict__ boff, int* __restrict__ rowb,
                             const float* __restrict__ word_emb, const float* __restrict__ pos_emb,
                             const float* __restrict__ type_emb, const float* __restrict__ memory,
                             const float* __restrict__ lns, const float* __restrict__ lnb,
                             float* __restrict__ x, unsigned short* __restrict__ xb,
                             int* __restrict__ ttarr) {
    int t = blockIdx.x;
    int b = blockIdx.y;
    // compute prefix offsets inline from Larr (cheap, deterministic everywhere)
    int pre[B + 1];
    {
        int acc = 0;
        #pragma unroll
        for (int b2 = 0; b2 < B; ++b2) { pre[b2] = acc; acc += Larr[b2] + MM; }
        pre[B] = acc;
    }
    int Lb = Larr[b];
    int tid = threadIdx.x;
    // designated block publishes boff/rowb for downstream kernels
    if (t == 0 && b == 0) {
        if (tid <= B) boff[tid] = pre[tid];
        for (int r = tid; r < B * T; r += 256) {
            int bb = 0;
            #pragma unroll
            for (int b2 = 1; b2 < B; ++b2) bb += (r >= pre[b2]) ? 1 : 0;
            rowb[r] = bb;
        }
    }
    if (t >= Lb + MM) return;
    int row = pre[b] + t;
    int tt;
    const float* src;
    if (t < Lb) {
        int sp = ord[b * S + t];
        tt = toktype[b * S + sp];
        src = &word_emb[(size_t)ids[b * S + sp] * H];
    } else {
        tt = 1;
        src = &memory[(size_t)(t - Lb) * H];
    }
    __shared__ float rowv[H];
    __shared__ float r1[256], r2[256];
    float lsum = 0.f, lsq = 0.f;
    for (int hh = tid; hh < H; hh += 256) {
        float v = src[hh] + pos_emb[(size_t)t * H + hh] + type_emb[(size_t)tt * H + hh];
        rowv[hh] = v;
        lsum += v;
        lsq += v * v;
    }
    r1[tid] = lsum; r2[tid] = lsq;
    __syncthreads();
    for (int s = 128; s > 0; s >>= 1) {
        if (tid < s) { r1[tid] += r1[tid + s]; r2[tid] += r2[tid + s]; }
        __syncthreads();
    }
    float mu = r1[0] / H;
    float var = r2[0] / H - mu * mu;
    float inv = rsqrtf(var + 1e-12f);
    for (int hh = tid; hh < H; hh += 256) {
        float v = (rowv[hh] - mu) * inv * lns[hh] + lnb[hh];
        x[(size_t)row * H + hh] = v;
        xb[(size_t)row * H + hh] = bf16_rne(v);
    }
    if (tid == 0) ttarr[row] = tt;
}

// ---------------- activations ----------------
#define ACT_NONE 0
#define ACT_RELU 1
#define ACT_GELU 2
#define ACT_SIGMOID 3
#define ACT_TANH 4

template <int ACT>
__device__ inline float apply_act(float v) {
    if constexpr (ACT == ACT_RELU) return fmaxf(v, 0.f);
    else if constexpr (ACT == ACT_GELU) {
        float y = v * 0.70710678118654752f;
        float a = fabsf(y);
        float t = 1.f / (1.f + 0.3275911f * a);
        float poly = t * (0.254829592f + t * (-0.284496736f + t * (1.421413741f +
                     t * (-1.453152027f + t * 1.061405429f))));
        float e = poly * exp2f(-a * a * 1.4426950408889634f);
        float erfv = 1.f - e;
        erfv = (y < 0.f) ? -erfv : erfv;
        return 0.5f * v * (1.f + erfv);
    }
    else if constexpr (ACT == ACT_SIGMOID) return 1.f / (1.f + expf(-v));
    else if constexpr (ACT == ACT_TANH) return tanhf(v);
    else return v;
}

// ---------------- fused weight transpose (ALL weights, one launch) ----------------
struct TDesc { const float* src; unsigned dstoff; int Kd; int Nd; int tile0; };
struct TTab { TDesc d[16]; int n; };

__global__ __launch_bounds__(256) void transpose_all(TTab tab, unsigned short* __restrict__ dstbase) {
    int tile = blockIdx.x;
    int mi = 0;
    #pragma unroll
    for (int i = 1; i < 16; ++i)
        if (i < tab.n && tab.d[i].tile0 <= tile) mi = i;
    TDesc d = tab.d[mi];
    int rel = tile - d.tile0;
    int tilesK = d.Kd >> 5;
    int kt = rel % tilesK, nt = rel / tilesK;
    __shared__ float ts[32][33];
    int k0 = kt * 32, n0 = nt * 32;
    int tx = threadIdx.x & 31, ty = threadIdx.x >> 5;  // 32 x 8
    #pragma unroll
    for (int r = 0; r < 4; ++r) {
        int kk = ty + r * 8;
        ts[kk][tx] = d.src[(size_t)(k0 + kk) * d.Nd + n0 + tx];
    }
    __syncthreads();
    unsigned short* Wt = dstbase + d.dstoff;
    #pragma unroll
    for (int r = 0; r < 4; ++r) {
        int nn = ty + r * 8;
        Wt[(size_t)(n0 + nn) * d.Kd + k0 + tx] = bf16_rne(ts[tx][nn]);
    }
}

// ---------------- MFMA GEMM (compact rows; identity mapping; NSPLIT up to 4) ----------------
#define EPI_F32   0
#define EPI_BF16  1
#define EPI_QKV   2
#define EPI_SPLIT2 3

template <int ACT, int EPI, int NSPLIT>
__global__ __launch_bounds__(256) void mfma_gemm(
    const unsigned short* __restrict__ A, const unsigned short* __restrict__ Bt,
    const float* __restrict__ b0, const float* __restrict__ b1, const float* __restrict__ b2,
    int sp1, int sp2,
    float* __restrict__ Cf, float* __restrict__ Cf2,
    float* __restrict__ Cf3, float* __restrict__ Cf4,
    unsigned short* __restrict__ Cb, unsigned short* __restrict__ Cb2,
    unsigned short* __restrict__ Vt, int n2w,
    const int* __restrict__ boffs, const int* __restrict__ rowb,
    int Mdim, int Ndim, int Kdim) {
    __shared__ unsigned short As[2][128 * 32];
    __shared__ unsigned short Bs[2][128 * 32];

    const int bn = blockIdx.x * 128, bm = blockIdx.y * 128;

    const int Mtot = boffs[B];
    if (bm >= Mtot) return;

    const int z = (NSPLIT > 1) ? blockIdx.z : 0;
    const int Klocal = Kdim / NSPLIT;
    const int koff = z * Klocal;

    const int tid = threadIdx.x;
    const int w = tid >> 6, lane = tid & 63;
    const int lr = lane & 15, g = lane >> 4;
    const int wr = w >> 1, wc = w & 1;
    f32x4 acc[4][4] = {};

    const int srow = w * 32 + (lane >> 2);
    const int kc = (((lane & 3) ^ ((lane >> 4) & 3)) * 8);
    const unsigned short* ga0 = A + (size_t)(bm + srow) * Kdim + kc;
    const unsigned short* ga1 = A + (size_t)(bm + srow + 16) * Kdim + kc;
    const unsigned short* gb0 = Bt + (size_t)(bn + srow) * Kdim + kc;
    const unsigned short* gb1 = Bt + (size_t)(bn + srow + 16) * Kdim + kc;
    const int d0 = (w * 32) * 32, d1 = (w * 32 + 16) * 32;

    const int sw = ((g ^ ((lr >> 2) & 3)) & 3) * 8;

    auto stage = [&](int pp, int k0) {
        load_lds16(ga0 + k0, &As[pp][d0]);
        load_lds16(ga1 + k0, &As[pp][d1]);
        load_lds16(gb0 + k0, &Bs[pp][d0]);
        load_lds16(gb1 + k0, &Bs[pp][d1]);
    };
    auto compute = [&](int pp) {
        bf16x8 af[4], bfr[4];
        #pragma unroll
        for (int i = 0; i < 4; ++i)
            af[i] = *(const bf16x8*)&As[pp][(wr * 64 + i * 16 + lr) * 32 + sw];
        #pragma unroll
        for (int j = 0; j < 4; ++j)
            bfr[j] = *(const bf16x8*)&Bs[pp][(wc * 64 + j * 16 + lr) * 32 + sw];
        __builtin_amdgcn_s_setprio(1);
        #pragma unroll
        for (int i = 0; i < 4; ++i)
            #pragma unroll
            for (int j = 0; j < 4; ++j)
                acc[i][j] = mfma16(af[i], bfr[j], acc[i][j]);
        __builtin_amdgcn_s_setprio(0);
    };

    const int nk = Klocal >> 5;
    stage(0, koff);
    int p = 0;
    for (int s = 0; s < nk; ++s) {
        if (s + 1 < nk) {
            stage(p ^ 1, koff + (s + 1) * 32);
            asm volatile("s_waitcnt vmcnt(4)" ::: "memory");
        } else {
            asm volatile("s_waitcnt vmcnt(0)" ::: "memory");
        }
        __builtin_amdgcn_s_barrier();
        __builtin_amdgcn_sched_barrier(0);
        compute(p);
        __builtin_amdgcn_sched_barrier(0);
        __builtin_amdgcn_s_barrier();
        __builtin_amdgcn_sched_barrier(0);
        p ^= 1;
    }

    float* Cdst = (z == 0) ? Cf : (z == 1) ? Cf2 : (z == 2) ? Cf3 : Cf4;
    #pragma unroll
    for (int i = 0; i < 4; ++i) {
        const int row0 = bm + wr * 64 + i * 16 + 4 * g;
        #pragma unroll
        for (int j = 0; j < 4; ++j) {
            const int col = bn + wc * 64 + j * 16 + lr;
            float bv = (NSPLIT > 1 && z != 0) ? 0.f
                     : ((col < sp1) ? b0[col] : (col < sp2 ? b1[col - sp1] : b2[col - sp2]));
            float vv[4];
            #pragma unroll
            for (int r = 0; r < 4; ++r) vv[r] = apply_act<ACT>(acc[i][j][r] + bv);
            if constexpr (EPI == EPI_F32) {
                #pragma unroll
                for (int r = 0; r < 4; ++r) Cdst[(size_t)(row0 + r) * Ndim + col] = vv[r];
            } else if constexpr (EPI == EPI_BF16) {
                #pragma unroll
                for (int r = 0; r < 4; ++r) Cb[(size_t)(row0 + r) * Ndim + col] = bf16_rne(vv[r]);
            } else if constexpr (EPI == EPI_QKV) {
                if (col < 1536) {
                    #pragma unroll
                    for (int r = 0; r < 4; ++r) Cb[(size_t)(row0 + r) * 1536 + col] = bf16_rne(vv[r]);
                } else {
                    int c2 = col - 1536;
                    int hh2 = c2 >> 6, dd = c2 & 63;
                    int bb = rowb[row0];
                    if (row0 + 3 < Mtot && rowb[row0 + 3] == bb) {
                        int t0 = row0 - boffs[bb];
                        unsigned lo = (unsigned)bf16_rne(vv[0]) | ((unsigned)bf16_rne(vv[1]) << 16);
                        unsigned hi = (unsigned)bf16_rne(vv[2]) | ((unsigned)bf16_rne(vv[3]) << 16);
                        size_t idxv = (((size_t)bb * NH + hh2) * DH + dd) * T + t0;
                        *(uint2*)&Vt[idxv] = make_uint2(lo, hi);
                    } else {
                        #pragma unroll
                        for (int r = 0; r < 4; ++r) {
                            int rr = row0 + r;
                            if (rr < Mtot) {
                                int b2 = rowb[rr];
                                int t2 = rr - boffs[b2];
                                Vt[(((size_t)b2 * NH + hh2) * DH + dd) * T + t2] = bf16_rne(vv[r]);
                            }
                        }
                    }
                }
            } else {  // EPI_SPLIT2
                if (col < sp1) {
                    #pragma unroll
                    for (int r = 0; r < 4; ++r) Cb[(size_t)(row0 + r) * sp1 + col] = bf16_rne(vv[r]);
                } else {
                    #pragma unroll
                    for (int r = 0; r < 4; ++r)
                        Cb2[(size_t)(row0 + r) * n2w + (col - sp1)] = bf16_rne(vv[r]);
                }
            }
        }
    }
}

// ---------------- combined key2 || val2 GEMM (z<4: key2 K=1536; z>=4: val2 K=1024) ----------------
__global__ __launch_bounds__(256) void head2_gemm(
    const unsigned short* __restrict__ Ak, const unsigned short* __restrict__ Btk,
    const float* __restrict__ biask,
    const unsigned short* __restrict__ Av, const unsigned short* __restrict__ Btv,
    const float* __restrict__ biasv,
    float* __restrict__ P0, float* __restrict__ P1, float* __restrict__ P2, float* __restrict__ P3,
    float* __restrict__ V0, float* __restrict__ V1, float* __restrict__ V2, float* __restrict__ V3,
    const int* __restrict__ boffs) {
    __shared__ unsigned short As[2][128 * 32];
    __shared__ unsigned short Bs[2][128 * 32];

    const int bn = blockIdx.x * 128, bm = blockIdx.y * 128;
    const int Mtot = boffs[B];
    if (bm >= Mtot) return;

    const int z = blockIdx.z;
    const int isval = z >> 2, zk = z & 3;
    const unsigned short* A  = isval ? Av : Ak;
    const unsigned short* Bt = isval ? Btv : Btk;
    const float* bias = isval ? biasv : biask;
    const int Kdim = isval ? 1024 : 1536;
    const int Klocal = Kdim >> 2;
    const int koff = zk * Klocal;
    float* Cdst = isval ? ((zk == 0) ? V0 : (zk == 1) ? V1 : (zk == 2) ? V2 : V3)
                        : ((zk == 0) ? P0 : (zk == 1) ? P1 : (zk == 2) ? P2 : P3);

    const int tid = threadIdx.x;
    const int w = tid >> 6, lane = tid & 63;
    const int lr = lane & 15, g = lane >> 4;
    const int wr = w >> 1, wc = w & 1;
    f32x4 acc[4][4] = {};

    const int srow = w * 32 + (lane >> 2);
    const int kc = (((lane & 3) ^ ((lane >> 4) & 3)) * 8);
    const unsigned short* ga0 = A + (size_t)(bm + srow) * Kdim + kc;
    const unsigned short* ga1 = A + (size_t)(bm + srow + 16) * Kdim + kc;
    const unsigned short* gb0 = Bt + (size_t)(bn + srow) * Kdim + kc;
    const unsigned short* gb1 = Bt + (size_t)(bn + srow + 16) * Kdim + kc;
    const int d0 = (w * 32) * 32, d1 = (w * 32 + 16) * 32;
    const int sw = ((g ^ ((lr >> 2) & 3)) & 3) * 8;

    auto stage = [&](int pp, int k0) {
        load_lds16(ga0 + k0, &As[pp][d0]);
        load_lds16(ga1 + k0, &As[pp][d1]);
        load_lds16(gb0 + k0, &Bs[pp][d0]);
        load_lds16(gb1 + k0, &Bs[pp][d1]);
    };
    auto compute = [&](int pp) {
        bf16x8 af[4], bfr[4];
        #pragma unroll
        for (int i = 0; i < 4; ++i)
            af[i] = *(const bf16x8*)&As[pp][(wr * 64 + i * 16 + lr) * 32 + sw];
        #pragma unroll
        for (int j = 0; j < 4; ++j)
            bfr[j] = *(const bf16x8*)&Bs[pp][(wc * 64 + j * 16 + lr) * 32 + sw];
        __builtin_amdgcn_s_setprio(1);
        #pragma unroll
        for (int i = 0; i < 4; ++i)
            #pragma unroll
            for (int j = 0; j < 4; ++j)
                acc[i][j] = mfma16(af[i], bfr[j], acc[i][j]);
        __builtin_amdgcn_s_setprio(0);
    };

    const int nk = Klocal >> 5;
    stage(0, koff);
    int p = 0;
    for (int s = 0; s < nk; ++s) {
        if (s + 1 < nk) {
            stage(p ^ 1, koff + (s + 1) * 32);
            asm volatile("s_waitcnt vmcnt(4)" ::: "memory");
        } else {
            asm volatile("s_waitcnt vmcnt(0)" ::: "memory");
        }
        __builtin_amdgcn_s_barrier();
        __builtin_amdgcn_sched_barrier(0);
        compute(p);
        __builtin_amdgcn_sched_barrier(0);
        __builtin_amdgcn_s_barrier();
        __builtin_amdgcn_sched_barrier(0);
        p ^= 1;
    }

    #pragma unroll
    for (int i = 0; i < 4; ++i) {
        const int row0 = bm + wr * 64 + i * 16 + 4 * g;
        #pragma unroll
        for (int j = 0; j < 4; ++j) {
            const int col = bn + wc * 64 + j * 16 + lr;
            float bv = (zk == 0) ? bias[col] : 0.f;
            #pragma unroll
            for (int r = 0; r < 4; ++r)
                Cdst[(size_t)(row0 + r) * E + col] = acc[i][j][r] + bv;
        }
    }
}

// ---------------- MFMA flash attention (compact rows) ----------------
#define C2 0.180336880111116670f      // 0.125 * log2(e)
#define MB2 14426.950408889634f       // 10000 * log2(e)

__global__ __launch_bounds__(256) void attn_mfma(
    const unsigned short* __restrict__ QK, const unsigned short* __restrict__ Vt,
    const int* __restrict__ Larr, const int* __restrict__ boffs,
    unsigned short* __restrict__ ctxb) {
    const int n = blockIdx.x;
    const int xcd = n & 7, k = n >> 3;
    const int p = xcd * 12 + k / 9, qt = k % 9;
    const int b = p / NH, h = p % NH;
    const int LbMM = Larr[b] + MM;
    if (qt * 64 >= LbMM) return;
    const int w = threadIdx.x >> 6, lane = threadIdx.x & 63;
    const int q0 = qt * 64 + w * 16;
    if (q0 >= LbMM) return;
    const int base = boffs[b];
    const int lr = lane & 15, g = lane >> 4;
    __shared__ unsigned short P[4][16][72];
    const unsigned short* qrow = QK + (size_t)(base + q0 + lr) * 1536 + h * 64;
    bf16x8 qf0 = *(const bf16x8*)(qrow + 8 * g);
    bf16x8 qf1 = *(const bf16x8*)(qrow + 32 + 8 * g);
    f32x4 ctx[4] = {};
    float m_run = -1e30f, l_run = 0.f;
    const size_t vbase = ((size_t)b * NH + h) * DH;
    for (int kt = 0; kt < LbMM; kt += 64) {
        f32x4 sf[4];
        #pragma unroll
        for (int i = 0; i < 4; ++i) {
            const unsigned short* krow =
                QK + (size_t)(base + kt + 16 * i + lr) * 1536 + 768 + h * 64;
            bf16x8 kf0 = *(const bf16x8*)(krow + 8 * g);
            bf16x8 kf1 = *(const bf16x8*)(krow + 32 + 8 * g);
            f32x4 s = {};
            s = mfma16(kf0, qf0, s);
            s = mfma16(kf1, qf1, s);
            sf[i] = s;
        }
        float tmax = -1e30f;
        #pragma unroll
        for (int i = 0; i < 4; ++i)
            #pragma unroll
            for (int r = 0; r < 4; ++r) {
                int key = kt + 16 * i + 4 * g + r;
                float v = sf[i][r] * C2 + (key < LbMM ? 0.f : -MB2);
                sf[i][r] = v;
                tmax = fmaxf(tmax, v);
            }
        tmax = fmaxf(tmax, __shfl_xor(tmax, 16));
        tmax = fmaxf(tmax, __shfl_xor(tmax, 32));
        float m_new = fmaxf(m_run, tmax);
        float scale = exp2f(m_run - m_new);
        m_run = m_new;
        float psum = 0.f;
        #pragma unroll
        for (int i = 0; i < 4; ++i)
            #pragma unroll
            for (int r = 0; r < 4; ++r) {
                float pv = exp2f(sf[i][r] - m_new);
                sf[i][r] = pv;
                psum += pv;
            }
        l_run = l_run * scale + psum;
        float f0 = __shfl(scale, 4 * g + 0);
        float f1 = __shfl(scale, 4 * g + 1);
        float f2 = __shfl(scale, 4 * g + 2);
        float f3 = __shfl(scale, 4 * g + 3);
        #pragma unroll
        for (int j = 0; j < 4; ++j) {
            ctx[j][0] *= f0; ctx[j][1] *= f1; ctx[j][2] *= f2; ctx[j][3] *= f3;
        }
        #pragma unroll
        for (int i = 0; i < 4; ++i) {
            unsigned lo = (unsigned)bf16_rne(sf[i][0]) | ((unsigned)bf16_rne(sf[i][1]) << 16);
            unsigned hi = (unsigned)bf16_rne(sf[i][2]) | ((unsigned)bf16_rne(sf[i][3]) << 16);
            *(unsigned*)&P[w][lr][16 * i + 4 * g] = lo;
            *(unsigned*)&P[w][lr][16 * i + 4 * g + 2] = hi;
        }
        asm volatile("s_waitcnt lgkmcnt(0)" ::: "memory");
        __builtin_amdgcn_sched_barrier(0);
        #pragma unroll
        for (int s2 = 0; s2 < 2; ++s2) {
            bf16x8 pa = *(const bf16x8*)&P[w][lr][32 * s2 + 8 * g];
            #pragma unroll
            for (int j = 0; j < 4; ++j) {
                const unsigned short* vrow =
                    Vt + (vbase + 16 * j + lr) * T + kt + 32 * s2 + 8 * g;
                bf16x8 vf = *(const bf16x8*)vrow;
                ctx[j] = mfma16(pa, vf, ctx[j]);
            }
        }
        asm volatile("s_waitcnt lgkmcnt(0)" ::: "memory");
        __builtin_amdgcn_sched_barrier(0);
    }
    l_run += __shfl_xor(l_run, 16);
    l_run += __shfl_xor(l_run, 32);
    float inv = 1.f / l_run;
    float i0 = __shfl(inv, 4 * g + 0);
    float i1 = __shfl(inv, 4 * g + 1);
    float i2 = __shfl(inv, 4 * g + 2);
    float i3 = __shfl(inv, 4 * g + 3);
    float sc[4] = {i0, i1, i2, i3};
    #pragma unroll
    for (int j = 0; j < 4; ++j)
        #pragma unroll
        for (int r = 0; r < 4; ++r) {
            int rl = q0 + 4 * g + r;
            if (rl < LbMM)
                ctxb[(size_t)(base + rl) * H + h * 64 + 16 * j + lr] =
                    bf16_rne(ctx[j][r] * sc[r]);
        }
}

// ---------------- residual + LN (delta = d1+d2+d3+d4), float4, compact ----------------
__global__ void lnres_kernel(float* __restrict__ x, const float* __restrict__ d1,
                             const float* __restrict__ d2, const float* __restrict__ d3,
                             const float* __restrict__ d4,
                             const float* __restrict__ s, const float* __restrict__ bvec,
                             unsigned short* __restrict__ xb, const int* __restrict__ mtotp) {
    int r = blockIdx.x;
    if (r >= mtotp[0]) return;
    int tid = threadIdx.x;
    __shared__ float4 row[H / 4];
    __shared__ float r1[256], r2[256];
    float lsum = 0.f, lsq = 0.f;
    size_t off4 = (size_t)r * (H / 4);
    if (tid < H / 4) {
        float4 a = ((const float4*)x)[off4 + tid];
        float4 p1 = ((const float4*)d1)[off4 + tid];
        float4 p2 = ((const float4*)d2)[off4 + tid];
        float4 p3 = ((const float4*)d3)[off4 + tid];
        float4 p4 = ((const float4*)d4)[off4 + tid];
        float4 v = make_float4(a.x + p1.x + p2.x + p3.x + p4.x,
                               a.y + p1.y + p2.y + p3.y + p4.y,
                               a.z + p1.z + p2.z + p3.z + p4.z,
                               a.w + p1.w + p2.w + p3.w + p4.w);
        row[tid] = v;
        lsum = v.x + v.y + v.z + v.w;
        lsq = v.x * v.x + v.y * v.y + v.z * v.z + v.w * v.w;
    }
    r1[tid] = lsum; r2[tid] = lsq;
    __syncthreads();
    for (int ss = 128; ss > 0; ss >>= 1) {
        if (tid < ss) { r1[tid] += r1[tid + ss]; r2[tid] += r2[tid + ss]; }
        __syncthreads();
    }
    float mu = r1[0] / H;
    float var = r2[0] / H - mu * mu;
    float inv = rsqrtf(var + 1e-12f);
    if (tid < H / 4) {
        float4 v = row[tid];
        const float4 sv = ((const float4*)s)[tid];
        const float4 bv = ((const float4*)bvec)[tid];
        float4 o = make_float4((v.x - mu) * inv * sv.x + bv.x,
                               (v.y - mu) * inv * sv.y + bv.y,
                               (v.z - mu) * inv * sv.z + bv.z,
                               (v.w - mu) * inv * sv.w + bv.w);
        ((float4*)x)[off4 + tid] = o;
        ushort4 ob = make_ushort4(bf16_rne(o.x), bf16_rne(o.y), bf16_rne(o.z), bf16_rne(o.w));
        *(ushort4*)&xb[(size_t)r * H + tid * 4] = ob;
    }
}

// ---------------- masked softmax pooling (4-way split partials; sigma/tanh here) ----------------
__global__ __launch_bounds__(256) void pool_kernel(
    const float* __restrict__ w0, const float* __restrict__ w1,
    const float* __restrict__ w2, const float* __restrict__ w3,
    const float* __restrict__ v0, const float* __restrict__ v1,
    const float* __restrict__ v2, const float* __restrict__ v3,
    const int* __restrict__ ttarr, const int* __restrict__ boffs,
    float* __restrict__ out) {
    int b = blockIdx.x;
    int le = threadIdx.x & 31;
    int e = blockIdx.y * 32 + le;
    int tg = threadIdx.x >> 5;  // 0..7
    int base = boffs[b];
    int nrow = boffs[b + 1] - base;
    __shared__ int ttl[T];
    __shared__ float red[8][33];
    for (int t = threadIdx.x; t < nrow; t += 256) ttl[t] = ttarr[base + t];
    __syncthreads();
    float mx = -1e30f;
    for (int t = tg; t < nrow; t += 8) {
        if (ttl[t] == 1) continue;
        size_t idx = (size_t)(base + t) * E + e;
        float w = 1.f / (1.f + expf(-(w0[idx] + w1[idx] + w2[idx] + w3[idx])));
        mx = fmaxf(mx, w);
    }
    red[tg][le] = mx;
    __syncthreads();
    #pragma unroll
    for (int i = 0; i < 8; ++i) mx = fmaxf(mx, red[i][le]);
    float den = 0.f, num = 0.f;
    for (int t = tg; t < nrow; t += 8) {
        if (ttl[t] == 1) continue;
        size_t idx = (size_t)(base + t) * E + e;
        float w = 1.f / (1.f + expf(-(w0[idx] + w1[idx] + w2[idx] + w3[idx])));
        float vval = tanhf(v0[idx] + v1[idx] + v2[idx] + v3[idx]);
        float ew = expf(w - mx);
        den += ew;
        num = fmaf(ew, vval, num);
    }
    __syncthreads();
    red[tg][le] = den;
    __syncthreads();
    float dtot = 0.f;
    #pragma unroll
    for (int i = 0; i < 8; ++i) dtot += red[i][le];
    __syncthreads();
    red[tg][le] = num;
    __syncthreads();
    float ntot = 0.f;
    #pragma unroll
    for (int i = 0; i < 8; ++i) ntot += red[i][le];
    if (tg == 0) out[(size_t)b * E + e] = fmaxf(ntot / dtot, 0.f);
}

// ---------------- host-side launch ----------------
extern "C" void kernel_launch(void* const* d_in, const int* in_sizes, int n_in,
                              void* d_out, int out_size, void* d_ws, size_t ws_size,
                              hipStream_t stream) {
    const int*   input_ids  = (const int*)d_in[0];
    const int*   token_type = (const int*)d_in[1];
    const int*   attn_mask  = (const int*)d_in[2];
    const float* word_emb   = (const float*)d_in[3];
    const float* pos_emb    = (const float*)d_in[4];
    const float* type_emb   = (const float*)d_in[5];
    const float* emb_ln_s   = (const float*)d_in[6];
    const float* emb_ln_b   = (const float*)d_in[7];
    const float* memory     = (const float*)d_in[8];
    const float* q_w  = (const float*)d_in[9];
    const float* q_b  = (const float*)d_in[10];
    const float* k_w  = (const float*)d_in[11];
    const float* k_b  = (const float*)d_in[12];
    const float* v_w  = (const float*)d_in[13];
    const float* v_b  = (const float*)d_in[14];
    const float* o_w  = (const float*)d_in[15];
    const float* o_b  = (const float*)d_in[16];
    const float* ln1_s = (const float*)d_in[17];
    const float* ln1_b = (const float*)d_in[18];
    const float* f_w1  = (const float*)d_in[19];
    const float* f_b1  = (const float*)d_in[20];
    const float* f_w2  = (const float*)d_in[21];
    const float* f_b2  = (const float*)d_in[22];
    const float* ln2_s = (const float*)d_in[23];
    const float* ln2_b = (const float*)d_in[24];
    const float* key_w1 = (const float*)d_in[25];
    const float* key_b1 = (const float*)d_in[26];
    const float* key_w2 = (const float*)d_in[27];
    const float* key_b2 = (const float*)d_in[28];
    const float* val_w1 = (const float*)d_in[29];
    const float* val_b1 = (const float*)d_in[30];
    const float* val_w2 = (const float*)d_in[31];
    const float* val_b2 = (const float*)d_in[32];
    float* out = (float*)d_out;

    char* ws = (char*)d_ws;
    size_t off = 0;
    auto alloc = [&](size_t bytes) {
        void* p = ws + off;
        off += (bytes + 255) & ~(size_t)255;
        return p;
    };
    const size_t BT  = (size_t)B * T;      // 4608 (worst-case rows)
    const size_t BTH = BT * H;

    int*   ord   = (int*)alloc((size_t)B * S * 4);
    int*   Larr  = (int*)alloc(64);
    int*   boff  = (int*)alloc((B + 1) * 4);
    int*   rowb  = (int*)alloc(BT * 4);
    int*   ttarr = (int*)alloc(BT * 4);
    float* x     = (float*)alloc(BTH * 4);
    unsigned short* xb   = (unsigned short*)alloc(BTH * 2);
    unsigned short* reg1 = (unsigned short*)alloc(BT * FF * 2);
    float* P0 = (float*)alloc(BTH * 4);
    float* P1 = (float*)alloc(BTH * 4);
    float* P2 = (float*)alloc(BTH * 4);
    float* P3 = (float*)alloc(BTH * 4);
    float* V0 = (float*)alloc(BT * E * 4);
    float* V1 = (float*)alloc(BT * E * 4);
    float* V2 = (float*)alloc(BT * E * 4);
    float* V3 = (float*)alloc(BT * E * 4);
    unsigned short* wt = (unsigned short*)alloc((size_t)17432576 * 2);

    unsigned short* qkb  = reg1;                       // [BT][1536]
    unsigned short* Vtb  = reg1 + BT * 1536;           // [B][NH][DH][T]
    unsigned short* ctxb = reg1 + BT * 1536 + BTH;     // [BT][H]
    unsigned short* hb   = reg1;                       // [BT][FF] (FFN phase)
    unsigned short* key1b = reg1;                      // [BT][1536] (head phase)
    unsigned short* val1b = reg1 + BT * 1536;          // [BT][1024]

    unsigned short* wt_head = wt + (size_t)14155776;
    unsigned short* wt_kv1 = wt_head;                       // [2560][768]
    unsigned short* wt_k2 = wt_head + (size_t)2560 * 768;   // [512][1536]
    unsigned short* wt_v2 = wt_k2 + (size_t)512 * 1536;     // [512][1024]

    const int Mrows = (int)BT;
    const size_t HH = (size_t)H * H;
    const int BIG = 1 << 30;
    const int* mtotp = boff + B;

    hipLaunchKernelGGL(order_kernel, dim3(B), dim3(S), 0, stream, attn_mask, ord, Larr);

    // one upfront transpose for ALL weights (2 layers + head)
    {
        TTab tab;
        tab.n = 16;
        for (int l = 0; l < NL; ++l) {
            unsigned base = (unsigned)(l * 7077888);
            int t0 = l * 6912;
            tab.d[l * 6 + 0] = { q_w + l * HH,              base,                        H,  H,  t0        };
            tab.d[l * 6 + 1] = { k_w + l * HH,              base + 768u * 768u,          H,  H,  t0 + 576  };
            tab.d[l * 6 + 2] = { v_w + l * HH,              base + 1536u * 768u,         H,  H,  t0 + 1152 };
            tab.d[l * 6 + 3] = { o_w + l * HH,              base + 2304u * 768u,         H,  H,  t0 + 1728 };
            tab.d[l * 6 + 4] = { f_w1 + (size_t)l * H * FF, base + 3072u * 768u,         H,  FF, t0 + 2304 };
            tab.d[l * 6 + 5] = { f_w2 + (size_t)l * FF * H, base + 6144u * 768u,         FF, H,  t0 + 4608 };
        }
        tab.d[12] = { key_w1, 14155776u,                    H,     2 * H, 13824 };
        tab.d[13] = { val_w1, 14155776u + 1536u * 768u,     H,     2 * E, 14976 };
        tab.d[14] = { key_w2, 16121856u,                    2 * H, E,     15744 };
        tab.d[15] = { val_w2, 16908288u,                    2 * E, E,     16512 };
        hipLaunchKernelGGL(transpose_all, dim3(17024), dim3(256), 0, stream, tab, wt);
    }

    hipLaunchKernelGGL(embed_kernel, dim3(T, B), dim3(256), 0, stream,
                       input_ids, token_type, ord, Larr, boff, rowb,
                       word_emb, pos_emb, type_emb,
                       memory, emb_ln_s, emb_ln_b, x, xb, ttarr);

    for (int l = 0; l < NL; ++l) {
        unsigned short* wt_l   = wt + (size_t)l * 7077888;
        unsigned short* wt_qkv = wt_l;
        unsigned short* wt_o   = wt_l + (size_t)2304 * 768;
        unsigned short* wt_f1  = wt_o + (size_t)768 * 768;
        unsigned short* wt_f2  = wt_f1 + (size_t)3072 * 768;

        mfma_gemm<ACT_NONE, EPI_QKV, 1><<<dim3(18, 36), 256, 0, stream>>>(
            xb, wt_qkv, q_b + (size_t)l * H, k_b + (size_t)l * H, v_b + (size_t)l * H,
            768, 1536, nullptr, nullptr, nullptr, nullptr, qkb, nullptr, Vtb, 0,
            boff, rowb, Mrows, 2304, H);
        hipLaunchKernelGGL(attn_mfma, dim3(864), dim3(256), 0, stream,
                           qkb, Vtb, Larr, boff, ctxb);
        mfma_gemm<ACT_NONE, EPI_F32, 4><<<dim3(6, 36, 4), 256, 0, stream>>>(
            ctxb, wt_o, o_b + (size_t)l * H, nullptr, nullptr, BIG, BIG,
            P0, P1, P2, P3, nullptr, nullptr, nullptr, 0, boff, rowb, Mrows, H, H);
        hipLaunchKernelGGL(lnres_kernel, dim3((int)BT), dim3(256), 0, stream,
                           x, P0, P1, P2, P3, ln1_s + (size_t)l * H, ln1_b + (size_t)l * H,
                           xb, mtotp);
        mfma_gemm<ACT_GELU, EPI_BF16, 1><<<dim3(24, 36), 256, 0, stream>>>(
            xb, wt_f1, f_b1 + (size_t)l * FF, nullptr, nullptr, BIG, BIG,
            nullptr, nullptr, nullptr, nullptr, hb, nullptr, nullptr, 0,
            boff, rowb, Mrows, FF, H);
        mfma_gemm<ACT_NONE, EPI_F32, 4><<<dim3(6, 36, 4), 256, 0, stream>>>(
            hb, wt_f2, f_b2 + (size_t)l * H, nullptr, nullptr, BIG, BIG,
            P0, P1, P2, P3, nullptr, nullptr, nullptr, 0, boff, rowb, Mrows, H, FF);
        hipLaunchKernelGGL(lnres_kernel, dim3((int)BT), dim3(256), 0, stream,
                           x, P0, P1, P2, P3, ln2_s + (size_t)l * H, ln2_b + (size_t)l * H,
                           xb, mtotp);
    }

    // fused key1|val1 GEMM: N=2560, split epilogue
    mfma_gemm<ACT_RELU, EPI_SPLIT2, 1><<<dim3(20, 36), 256, 0, stream>>>(
        xb, wt_kv1, key_b1, val_b1, nullptr, 1536, BIG,
        nullptr, nullptr, nullptr, nullptr, key1b, val1b, nullptr, 1024,
        boff, rowb, Mrows, 2560, H);
    // combined key2 || val2 (one dispatch, 8 z-planes)
    head2_gemm<<<dim3(4, 36, 8), 256, 0, stream>>>(
        key1b, wt_k2, key_b2, val1b, wt_v2, val_b2,
        P0, P1, P2, P3, V0, V1, V2, V3, boff);
    hipLaunchKernelGGL(pool_kernel, dim3(B, E / 32), dim3(256), 0, stream,
                       P0, P1, P2, P3, V0, V1, V2, V3, ttarr, boff, out);
}

// Round 14
// 450.679 us; speedup vs baseline: 1.3075x; 1.0284x over previous
//
#include <hip/hip_runtime.h>
#include <hip/hip_bf16.h>

#define B 8
#define S 512
#define MM 64
#define T 576          // S + MM
#define H 768
#define NH 12
#define DH 64
#define FF 3072
#define E 512
#define NL 2

typedef __attribute__((ext_vector_type(8))) short bf16x8;
typedef __attribute__((ext_vector_type(4))) float f32x4;

__device__ inline unsigned short bf16_rne(float f) {
    unsigned u = __builtin_bit_cast(unsigned, f);
    unsigned r = u + 0x7FFFu + ((u >> 16) & 1u);
    return (unsigned short)(r >> 16);
}

__device__ inline f32x4 mfma16(bf16x8 a, bf16x8 b, f32x4 c) {
    return __builtin_amdgcn_mfma_f32_16x16x32_bf16(a, b, c, 0, 0, 0);
}

__device__ inline void load_lds16(const void* g, void* l) {
    __builtin_amdgcn_global_load_lds((const __attribute__((address_space(1))) void*)g,
                                     (__attribute__((address_space(3))) void*)l, 16, 0, 0);
}

// ---------------- embedding + LN (COMPACT rows; inline boff; (0,0) block writes tables) ----------------
__global__ void embed_kernel(const int* __restrict__ ids, const int* __restrict__ toktype,
                             const int* __restrict__ ord, const int* __restrict__ Larr,
                             int* __restrict__ boff, int* __restrict__ rowb,
                             const float* __restrict__ word_emb, const float* __restrict__ pos_emb,
                             const float* __restrict__ type_emb, const float* __restrict__ memory,
                             const float* __restrict__ lns, const float* __restrict__ lnb,
                             float* __restrict__ x, unsigned short* __restrict__ xb,
                             int* __restrict__ ttarr) {
    int t = blockIdx.x;
    int b = blockIdx.y;
    int pre[B + 1];
    {
        int acc = 0;
        #pragma unroll
        for (int b2 = 0; b2 < B; ++b2) { pre[b2] = acc; acc += Larr[b2] + MM; }
        pre[B] = acc;
    }
    int Lb = Larr[b];
    int tid = threadIdx.x;
    if (t == 0 && b == 0) {
        if (tid <= B) boff[tid] = pre[tid];
        for (int r = tid; r < B * T; r += 256) {
            int bb = 0;
            #pragma unroll
            for (int b2 = 1; b2 < B; ++b2) bb += (r >= pre[b2]) ? 1 : 0;
            rowb[r] = bb;
        }
    }
    if (t >= Lb + MM) return;
    int row = pre[b] + t;
    int tt;
    const float* src;
    if (t < Lb) {
        int sp = ord[b * S + t];
        tt = toktype[b * S + sp];
        src = &word_emb[(size_t)ids[b * S + sp] * H];
    } else {
        tt = 1;
        src = &memory[(size_t)(t - Lb) * H];
    }
    __shared__ float rowv[H];
    __shared__ float r1[256], r2[256];
    float lsum = 0.f, lsq = 0.f;
    for (int hh = tid; hh < H; hh += 256) {
        float v = src[hh] + pos_emb[(size_t)t * H + hh] + type_emb[(size_t)tt * H + hh];
        rowv[hh] = v;
        lsum += v;
        lsq += v * v;
    }
    r1[tid] = lsum; r2[tid] = lsq;
    __syncthreads();
    for (int s = 128; s > 0; s >>= 1) {
        if (tid < s) { r1[tid] += r1[tid + s]; r2[tid] += r2[tid + s]; }
        __syncthreads();
    }
    float mu = r1[0] / H;
    float var = r2[0] / H - mu * mu;
    float inv = rsqrtf(var + 1e-12f);
    for (int hh = tid; hh < H; hh += 256) {
        float v = (rowv[hh] - mu) * inv * lns[hh] + lnb[hh];
        x[(size_t)row * H + hh] = v;
        xb[(size_t)row * H + hh] = bf16_rne(v);
    }
    if (tid == 0) ttarr[row] = tt;
}

// ---------------- activations ----------------
#define ACT_NONE 0
#define ACT_RELU 1
#define ACT_GELU 2
#define ACT_SIGMOID 3
#define ACT_TANH 4

template <int ACT>
__device__ inline float apply_act(float v) {
    if constexpr (ACT == ACT_RELU) return fmaxf(v, 0.f);
    else if constexpr (ACT == ACT_GELU) {
        float y = v * 0.70710678118654752f;
        float a = fabsf(y);
        float t = 1.f / (1.f + 0.3275911f * a);
        float poly = t * (0.254829592f + t * (-0.284496736f + t * (1.421413741f +
                     t * (-1.453152027f + t * 1.061405429f))));
        float e = poly * exp2f(-a * a * 1.4426950408889634f);
        float erfv = 1.f - e;
        erfv = (y < 0.f) ? -erfv : erfv;
        return 0.5f * v * (1.f + erfv);
    }
    else if constexpr (ACT == ACT_SIGMOID) return 1.f / (1.f + expf(-v));
    else if constexpr (ACT == ACT_TANH) return tanhf(v);
    else return v;
}

// ---------------- fused weight transpose + mask-order (one launch) ----------------
// tiles [0, NT_TILES): weight transpose; tiles [NT_TILES, NT_TILES+B): order scan per batch.
#define NT_TILES 17024
struct TDesc { const float* src; unsigned dstoff; int Kd; int Nd; int tile0; };
struct TTab { TDesc d[16]; int n; };

__global__ __launch_bounds__(256) void transpose_all(TTab tab, unsigned short* __restrict__ dstbase,
                                                     const int* __restrict__ mask,
                                                     int* __restrict__ ord, int* __restrict__ Larr) {
    int tile = blockIdx.x;
    int tid = threadIdx.x;
    if (tile >= NT_TILES) {
        // ---- order block for batch b: stable argsort of (1-mask) via 256-thread scan over 512 ----
        int b = tile - NT_TILES;
        __shared__ int ps[S];
        int m0 = (mask[b * S + tid] != 0) ? 1 : 0;
        int m1 = (mask[b * S + tid + 256] != 0) ? 1 : 0;
        ps[tid] = m0; ps[tid + 256] = m1;
        __syncthreads();
        for (int off2 = 1; off2 < S; off2 <<= 1) {
            int a0 = (tid >= off2) ? ps[tid - off2] : 0;
            int a1 = (tid + 256 >= off2) ? ps[tid + 256 - off2] : 0;
            __syncthreads();
            ps[tid] += a0; ps[tid + 256] += a1;
            __syncthreads();
        }
        int L = ps[S - 1];
        int r0 = m0 ? (ps[tid] - 1) : (L + (tid - ps[tid]));
        int r1 = m1 ? (ps[tid + 256] - 1) : (L + (tid + 256 - ps[tid + 256]));
        ord[b * S + r0] = tid;
        ord[b * S + r1] = tid + 256;
        if (tid == 0) Larr[b] = L;
        return;
    }
    int mi = 0;
    #pragma unroll
    for (int i = 1; i < 16; ++i)
        if (i < tab.n && tab.d[i].tile0 <= tile) mi = i;
    TDesc d = tab.d[mi];
    int rel = tile - d.tile0;
    int tilesK = d.Kd >> 5;
    int kt = rel % tilesK, nt = rel / tilesK;
    __shared__ float ts[32][33];
    int k0 = kt * 32, n0 = nt * 32;
    int tx = tid & 31, ty = tid >> 5;  // 32 x 8
    #pragma unroll
    for (int r = 0; r < 4; ++r) {
        int kk = ty + r * 8;
        ts[kk][tx] = d.src[(size_t)(k0 + kk) * d.Nd + n0 + tx];
    }
    __syncthreads();
    unsigned short* Wt = dstbase + d.dstoff;
    #pragma unroll
    for (int r = 0; r < 4; ++r) {
        int nn = ty + r * 8;
        Wt[(size_t)(n0 + nn) * d.Kd + k0 + tx] = bf16_rne(ts[tx][nn]);
    }
}

// ---------------- MFMA GEMM (compact rows; identity mapping; TRIPLE buffer, 1 barrier/step) ----------------
#define EPI_F32   0
#define EPI_BF16  1
#define EPI_QKV   2
#define EPI_SPLIT2 3

template <int ACT, int EPI, int NSPLIT>
__global__ __launch_bounds__(256) void mfma_gemm(
    const unsigned short* __restrict__ A, const unsigned short* __restrict__ Bt,
    const float* __restrict__ b0, const float* __restrict__ b1, const float* __restrict__ b2,
    int sp1, int sp2,
    float* __restrict__ Cf, float* __restrict__ Cf2,
    float* __restrict__ Cf3, float* __restrict__ Cf4,
    unsigned short* __restrict__ Cb, unsigned short* __restrict__ Cb2,
    unsigned short* __restrict__ Vt, int n2w,
    const int* __restrict__ boffs, const int* __restrict__ rowb,
    int Mdim, int Ndim, int Kdim) {
    __shared__ unsigned short As[3][128 * 32];
    __shared__ unsigned short Bs[3][128 * 32];

    const int bn = blockIdx.x * 128, bm = blockIdx.y * 128;

    const int Mtot = boffs[B];
    if (bm >= Mtot) return;

    const int z = (NSPLIT > 1) ? blockIdx.z : 0;
    const int Klocal = Kdim / NSPLIT;
    const int koff = z * Klocal;

    const int tid = threadIdx.x;
    const int w = tid >> 6, lane = tid & 63;
    const int lr = lane & 15, g = lane >> 4;
    const int wr = w >> 1, wc = w & 1;
    f32x4 acc[4][4] = {};

    const int srow = w * 32 + (lane >> 2);
    const int kc = (((lane & 3) ^ ((lane >> 4) & 3)) * 8);
    const unsigned short* ga0 = A + (size_t)(bm + srow) * Kdim + kc;
    const unsigned short* ga1 = A + (size_t)(bm + srow + 16) * Kdim + kc;
    const unsigned short* gb0 = Bt + (size_t)(bn + srow) * Kdim + kc;
    const unsigned short* gb1 = Bt + (size_t)(bn + srow + 16) * Kdim + kc;
    const int d0 = (w * 32) * 32, d1 = (w * 32 + 16) * 32;

    const int sw = ((g ^ ((lr >> 2) & 3)) & 3) * 8;

    auto stage = [&](int pp, int k0) {
        load_lds16(ga0 + k0, &As[pp][d0]);
        load_lds16(ga1 + k0, &As[pp][d1]);
        load_lds16(gb0 + k0, &Bs[pp][d0]);
        load_lds16(gb1 + k0, &Bs[pp][d1]);
    };
    auto compute = [&](int pp) {
        bf16x8 af[4], bfr[4];
        #pragma unroll
        for (int i = 0; i < 4; ++i)
            af[i] = *(const bf16x8*)&As[pp][(wr * 64 + i * 16 + lr) * 32 + sw];
        #pragma unroll
        for (int j = 0; j < 4; ++j)
            bfr[j] = *(const bf16x8*)&Bs[pp][(wc * 64 + j * 16 + lr) * 32 + sw];
        __builtin_amdgcn_s_setprio(1);
        #pragma unroll
        for (int i = 0; i < 4; ++i)
            #pragma unroll
            for (int j = 0; j < 4; ++j)
                acc[i][j] = mfma16(af[i], bfr[j], acc[i][j]);
        __builtin_amdgcn_s_setprio(0);
    };

    // Triple-buffered, ONE barrier per k-step.
    // Safety: stage at iter s+1 targets buffer (s+2)%3, last read in compute(s-1);
    // any wave issuing that stage has passed barrier(s), which implies all waves
    // finished compute(s-1) (compute(s-1) precedes barrier(s) in program order).
    const int nk = Klocal >> 5;
    stage(0, koff);
    int p = 0;
    for (int s = 0; s < nk; ++s) {
        if (s + 1 < nk) {
            int pn = p + 1; if (pn == 3) pn = 0;
            stage(pn, koff + (s + 1) * 32);
            asm volatile("s_waitcnt vmcnt(4)" ::: "memory");
        } else {
            asm volatile("s_waitcnt vmcnt(0)" ::: "memory");
        }
        __builtin_amdgcn_s_barrier();
        __builtin_amdgcn_sched_barrier(0);
        compute(p);
        __builtin_amdgcn_sched_barrier(0);
        p = (p == 2) ? 0 : p + 1;
    }

    float* Cdst = (z == 0) ? Cf : (z == 1) ? Cf2 : (z == 2) ? Cf3 : Cf4;
    #pragma unroll
    for (int i = 0; i < 4; ++i) {
        const int row0 = bm + wr * 64 + i * 16 + 4 * g;
        #pragma unroll
        for (int j = 0; j < 4; ++j) {
            const int col = bn + wc * 64 + j * 16 + lr;
            float bv = (NSPLIT > 1 && z != 0) ? 0.f
                     : ((col < sp1) ? b0[col] : (col < sp2 ? b1[col - sp1] : b2[col - sp2]));
            float vv[4];
            #pragma unroll
            for (int r = 0; r < 4; ++r) vv[r] = apply_act<ACT>(acc[i][j][r] + bv);
            if constexpr (EPI == EPI_F32) {
                #pragma unroll
                for (int r = 0; r < 4; ++r) Cdst[(size_t)(row0 + r) * Ndim + col] = vv[r];
            } else if constexpr (EPI == EPI_BF16) {
                #pragma unroll
                for (int r = 0; r < 4; ++r) Cb[(size_t)(row0 + r) * Ndim + col] = bf16_rne(vv[r]);
            } else if constexpr (EPI == EPI_QKV) {
                if (col < 1536) {
                    #pragma unroll
                    for (int r = 0; r < 4; ++r) Cb[(size_t)(row0 + r) * 1536 + col] = bf16_rne(vv[r]);
                } else {
                    int c2 = col - 1536;
                    int hh2 = c2 >> 6, dd = c2 & 63;
                    int bb = rowb[row0];
                    if (row0 + 3 < Mtot && rowb[row0 + 3] == bb) {
                        int t0 = row0 - boffs[bb];
                        unsigned lo = (unsigned)bf16_rne(vv[0]) | ((unsigned)bf16_rne(vv[1]) << 16);
                        unsigned hi = (unsigned)bf16_rne(vv[2]) | ((unsigned)bf16_rne(vv[3]) << 16);
                        size_t idxv = (((size_t)bb * NH + hh2) * DH + dd) * T + t0;
                        *(uint2*)&Vt[idxv] = make_uint2(lo, hi);
                    } else {
                        #pragma unroll
                        for (int r = 0; r < 4; ++r) {
                            int rr = row0 + r;
                            if (rr < Mtot) {
                                int b2 = rowb[rr];
                                int t2 = rr - boffs[b2];
                                Vt[(((size_t)b2 * NH + hh2) * DH + dd) * T + t2] = bf16_rne(vv[r]);
                            }
                        }
                    }
                }
            } else {  // EPI_SPLIT2
                if (col < sp1) {
                    #pragma unroll
                    for (int r = 0; r < 4; ++r) Cb[(size_t)(row0 + r) * sp1 + col] = bf16_rne(vv[r]);
                } else {
                    #pragma unroll
                    for (int r = 0; r < 4; ++r)
                        Cb2[(size_t)(row0 + r) * n2w + (col - sp1)] = bf16_rne(vv[r]);
                }
            }
        }
    }
}

// ---------------- combined key2 || val2 GEMM (triple buffer, 1 barrier/step) ----------------
__global__ __launch_bounds__(256) void head2_gemm(
    const unsigned short* __restrict__ Ak, const unsigned short* __restrict__ Btk,
    const float* __restrict__ biask,
    const unsigned short* __restrict__ Av, const unsigned short* __restrict__ Btv,
    const float* __restrict__ biasv,
    float* __restrict__ P0, float* __restrict__ P1, float* __restrict__ P2, float* __restrict__ P3,
    float* __restrict__ V0, float* __restrict__ V1, float* __restrict__ V2, float* __restrict__ V3,
    const int* __restrict__ boffs) {
    __shared__ unsigned short As[3][128 * 32];
    __shared__ unsigned short Bs[3][128 * 32];

    const int bn = blockIdx.x * 128, bm = blockIdx.y * 128;
    const int Mtot = boffs[B];
    if (bm >= Mtot) return;

    const int z = blockIdx.z;
    const int isval = z >> 2, zk = z & 3;
    const unsigned short* A  = isval ? Av : Ak;
    const unsigned short* Bt = isval ? Btv : Btk;
    const float* bias = isval ? biasv : biask;
    const int Kdim = isval ? 1024 : 1536;
    const int Klocal = Kdim >> 2;
    const int koff = zk * Klocal;
    float* Cdst = isval ? ((zk == 0) ? V0 : (zk == 1) ? V1 : (zk == 2) ? V2 : V3)
                        : ((zk == 0) ? P0 : (zk == 1) ? P1 : (zk == 2) ? P2 : P3);

    const int tid = threadIdx.x;
    const int w = tid >> 6, lane = tid & 63;
    const int lr = lane & 15, g = lane >> 4;
    const int wr = w >> 1, wc = w & 1;
    f32x4 acc[4][4] = {};

    const int srow = w * 32 + (lane >> 2);
    const int kc = (((lane & 3) ^ ((lane >> 4) & 3)) * 8);
    const unsigned short* ga0 = A + (size_t)(bm + srow) * Kdim + kc;
    const unsigned short* ga1 = A + (size_t)(bm + srow + 16) * Kdim + kc;
    const unsigned short* gb0 = Bt + (size_t)(bn + srow) * Kdim + kc;
    const unsigned short* gb1 = Bt + (size_t)(bn + srow + 16) * Kdim + kc;
    const int d0 = (w * 32) * 32, d1 = (w * 32 + 16) * 32;
    const int sw = ((g ^ ((lr >> 2) & 3)) & 3) * 8;

    auto stage = [&](int pp, int k0) {
        load_lds16(ga0 + k0, &As[pp][d0]);
        load_lds16(ga1 + k0, &As[pp][d1]);
        load_lds16(gb0 + k0, &Bs[pp][d0]);
        load_lds16(gb1 + k0, &Bs[pp][d1]);
    };
    auto compute = [&](int pp) {
        bf16x8 af[4], bfr[4];
        #pragma unroll
        for (int i = 0; i < 4; ++i)
            af[i] = *(const bf16x8*)&As[pp][(wr * 64 + i * 16 + lr) * 32 + sw];
        #pragma unroll
        for (int j = 0; j < 4; ++j)
            bfr[j] = *(const bf16x8*)&Bs[pp][(wc * 64 + j * 16 + lr) * 32 + sw];
        __builtin_amdgcn_s_setprio(1);
        #pragma unroll
        for (int i = 0; i < 4; ++i)
            #pragma unroll
            for (int j = 0; j < 4; ++j)
                acc[i][j] = mfma16(af[i], bfr[j], acc[i][j]);
        __builtin_amdgcn_s_setprio(0);
    };

    const int nk = Klocal >> 5;
    stage(0, koff);
    int p = 0;
    for (int s = 0; s < nk; ++s) {
        if (s + 1 < nk) {
            int pn = p + 1; if (pn == 3) pn = 0;
            stage(pn, koff + (s + 1) * 32);
            asm volatile("s_waitcnt vmcnt(4)" ::: "memory");
        } else {
            asm volatile("s_waitcnt vmcnt(0)" ::: "memory");
        }
        __builtin_amdgcn_s_barrier();
        __builtin_amdgcn_sched_barrier(0);
        compute(p);
        __builtin_amdgcn_sched_barrier(0);
        p = (p == 2) ? 0 : p + 1;
    }

    #pragma unroll
    for (int i = 0; i < 4; ++i) {
        const int row0 = bm + wr * 64 + i * 16 + 4 * g;
        #pragma unroll
        for (int j = 0; j < 4; ++j) {
            const int col = bn + wc * 64 + j * 16 + lr;
            float bv = (zk == 0) ? bias[col] : 0.f;
            #pragma unroll
            for (int r = 0; r < 4; ++r)
                Cdst[(size_t)(row0 + r) * E + col] = acc[i][j][r] + bv;
        }
    }
}

// ---------------- MFMA flash attention (compact rows) ----------------
#define C2 0.180336880111116670f      // 0.125 * log2(e)
#define MB2 14426.950408889634f       // 10000 * log2(e)

__global__ __launch_bounds__(256) void attn_mfma(
    const unsigned short* __restrict__ QK, const unsigned short* __restrict__ Vt,
    const int* __restrict__ Larr, const int* __restrict__ boffs,
    unsigned short* __restrict__ ctxb) {
    const int n = blockIdx.x;
    const int xcd = n & 7, k = n >> 3;
    const int p = xcd * 12 + k / 9, qt = k % 9;
    const int b = p / NH, h = p % NH;
    const int LbMM = Larr[b] + MM;
    if (qt * 64 >= LbMM) return;
    const int w = threadIdx.x >> 6, lane = threadIdx.x & 63;
    const int q0 = qt * 64 + w * 16;
    if (q0 >= LbMM) return;
    const int base = boffs[b];
    const int lr = lane & 15, g = lane >> 4;
    __shared__ unsigned short P[4][16][72];
    const unsigned short* qrow = QK + (size_t)(base + q0 + lr) * 1536 + h * 64;
    bf16x8 qf0 = *(const bf16x8*)(qrow + 8 * g);
    bf16x8 qf1 = *(const bf16x8*)(qrow + 32 + 8 * g);
    f32x4 ctx[4] = {};
    float m_run = -1e30f, l_run = 0.f;
    const size_t vbase = ((size_t)b * NH + h) * DH;
    for (int kt = 0; kt < LbMM; kt += 64) {
        f32x4 sf[4];
        #pragma unroll
        for (int i = 0; i < 4; ++i) {
            const unsigned short* krow =
                QK + (size_t)(base + kt + 16 * i + lr) * 1536 + 768 + h * 64;
            bf16x8 kf0 = *(const bf16x8*)(krow + 8 * g);
            bf16x8 kf1 = *(const bf16x8*)(krow + 32 + 8 * g);
            f32x4 s = {};
            s = mfma16(kf0, qf0, s);
            s = mfma16(kf1, qf1, s);
            sf[i] = s;
        }
        float tmax = -1e30f;
        #pragma unroll
        for (int i = 0; i < 4; ++i)
            #pragma unroll
            for (int r = 0; r < 4; ++r) {
                int key = kt + 16 * i + 4 * g + r;
                float v = sf[i][r] * C2 + (key < LbMM ? 0.f : -MB2);
                sf[i][r] = v;
                tmax = fmaxf(tmax, v);
            }
        tmax = fmaxf(tmax, __shfl_xor(tmax, 16));
        tmax = fmaxf(tmax, __shfl_xor(tmax, 32));
        float m_new = fmaxf(m_run, tmax);
        float scale = exp2f(m_run - m_new);
        m_run = m_new;
        float psum = 0.f;
        #pragma unroll
        for (int i = 0; i < 4; ++i)
            #pragma unroll
            for (int r = 0; r < 4; ++r) {
                float pv = exp2f(sf[i][r] - m_new);
                sf[i][r] = pv;
                psum += pv;
            }
        l_run = l_run * scale + psum;
        float f0 = __shfl(scale, 4 * g + 0);
        float f1 = __shfl(scale, 4 * g + 1);
        float f2 = __shfl(scale, 4 * g + 2);
        float f3 = __shfl(scale, 4 * g + 3);
        #pragma unroll
        for (int j = 0; j < 4; ++j) {
            ctx[j][0] *= f0; ctx[j][1] *= f1; ctx[j][2] *= f2; ctx[j][3] *= f3;
        }
        #pragma unroll
        for (int i = 0; i < 4; ++i) {
            unsigned lo = (unsigned)bf16_rne(sf[i][0]) | ((unsigned)bf16_rne(sf[i][1]) << 16);
            unsigned hi = (unsigned)bf16_rne(sf[i][2]) | ((unsigned)bf16_rne(sf[i][3]) << 16);
            *(unsigned*)&P[w][lr][16 * i + 4 * g] = lo;
            *(unsigned*)&P[w][lr][16 * i + 4 * g + 2] = hi;
        }
        asm volatile("s_waitcnt lgkmcnt(0)" ::: "memory");
        __builtin_amdgcn_sched_barrier(0);
        #pragma unroll
        for (int s2 = 0; s2 < 2; ++s2) {
            bf16x8 pa = *(const bf16x8*)&P[w][lr][32 * s2 + 8 * g];
            #pragma unroll
            for (int j = 0; j < 4; ++j) {
                const unsigned short* vrow =
                    Vt + (vbase + 16 * j + lr) * T + kt + 32 * s2 + 8 * g;
                bf16x8 vf = *(const bf16x8*)vrow;
                ctx[j] = mfma16(pa, vf, ctx[j]);
            }
        }
        asm volatile("s_waitcnt lgkmcnt(0)" ::: "memory");
        __builtin_amdgcn_sched_barrier(0);
    }
    l_run += __shfl_xor(l_run, 16);
    l_run += __shfl_xor(l_run, 32);
    float inv = 1.f / l_run;
    float i0 = __shfl(inv, 4 * g + 0);
    float i1 = __shfl(inv, 4 * g + 1);
    float i2 = __shfl(inv, 4 * g + 2);
    float i3 = __shfl(inv, 4 * g + 3);
    float sc[4] = {i0, i1, i2, i3};
    #pragma unroll
    for (int j = 0; j < 4; ++j)
        #pragma unroll
        for (int r = 0; r < 4; ++r) {
            int rl = q0 + 4 * g + r;
            if (rl < LbMM)
                ctxb[(size_t)(base + rl) * H + h * 64 + 16 * j + lr] =
                    bf16_rne(ctx[j][r] * sc[r]);
        }
}

// ---------------- residual + LN (delta = d1+d2+d3+d4), float4, compact ----------------
__global__ void lnres_kernel(float* __restrict__ x, const float* __restrict__ d1,
                             const float* __restrict__ d2, const float* __restrict__ d3,
                             const float* __restrict__ d4,
                             const float* __restrict__ s, const float* __restrict__ bvec,
                             unsigned short* __restrict__ xb, const int* __restrict__ mtotp) {
    int r = blockIdx.x;
    if (r >= mtotp[0]) return;
    int tid = threadIdx.x;
    __shared__ float4 row[H / 4];
    __shared__ float r1[256], r2[256];
    float lsum = 0.f, lsq = 0.f;
    size_t off4 = (size_t)r * (H / 4);
    if (tid < H / 4) {
        float4 a = ((const float4*)x)[off4 + tid];
        float4 p1 = ((const float4*)d1)[off4 + tid];
        float4 p2 = ((const float4*)d2)[off4 + tid];
        float4 p3 = ((const float4*)d3)[off4 + tid];
        float4 p4 = ((const float4*)d4)[off4 + tid];
        float4 v = make_float4(a.x + p1.x + p2.x + p3.x + p4.x,
                               a.y + p1.y + p2.y + p3.y + p4.y,
                               a.z + p1.z + p2.z + p3.z + p4.z,
                               a.w + p1.w + p2.w + p3.w + p4.w);
        row[tid] = v;
        lsum = v.x + v.y + v.z + v.w;
        lsq = v.x * v.x + v.y * v.y + v.z * v.z + v.w * v.w;
    }
    r1[tid] = lsum; r2[tid] = lsq;
    __syncthreads();
    for (int ss = 128; ss > 0; ss >>= 1) {
        if (tid < ss) { r1[tid] += r1[tid + ss]; r2[tid] += r2[tid + ss]; }
        __syncthreads();
    }
    float mu = r1[0] / H;
    float var = r2[0] / H - mu * mu;
    float inv = rsqrtf(var + 1e-12f);
    if (tid < H / 4) {
        float4 v = row[tid];
        const float4 sv = ((const float4*)s)[tid];
        const float4 bv = ((const float4*)bvec)[tid];
        float4 o = make_float4((v.x - mu) * inv * sv.x + bv.x,
                               (v.y - mu) * inv * sv.y + bv.y,
                               (v.z - mu) * inv * sv.z + bv.z,
                               (v.w - mu) * inv * sv.w + bv.w);
        ((float4*)x)[off4 + tid] = o;
        ushort4 ob = make_ushort4(bf16_rne(o.x), bf16_rne(o.y), bf16_rne(o.z), bf16_rne(o.w));
        *(ushort4*)&xb[(size_t)r * H + tid * 4] = ob;
    }
}

// ---------------- masked softmax pooling (4-way split partials; sigma/tanh here) ----------------
__global__ __launch_bounds__(256) void pool_kernel(
    const float* __restrict__ w0, const float* __restrict__ w1,
    const float* __restrict__ w2, const float* __restrict__ w3,
    const float* __restrict__ v0, const float* __restrict__ v1,
    const float* __restrict__ v2, const float* __restrict__ v3,
    const int* __restrict__ ttarr, const int* __restrict__ boffs,
    float* __restrict__ out) {
    int b = blockIdx.x;
    int le = threadIdx.x & 31;
    int e = blockIdx.y * 32 + le;
    int tg = threadIdx.x >> 5;  // 0..7
    int base = boffs[b];
    int nrow = boffs[b + 1] - base;
    __shared__ int ttl[T];
    __shared__ float red[8][33];
    for (int t = threadIdx.x; t < nrow; t += 256) ttl[t] = ttarr[base + t];
    __syncthreads();
    float mx = -1e30f;
    for (int t = tg; t < nrow; t += 8) {
        if (ttl[t] == 1) continue;
        size_t idx = (size_t)(base + t) * E + e;
        float w = 1.f / (1.f + expf(-(w0[idx] + w1[idx] + w2[idx] + w3[idx])));
        mx = fmaxf(mx, w);
    }
    red[tg][le] = mx;
    __syncthreads();
    #pragma unroll
    for (int i = 0; i < 8; ++i) mx = fmaxf(mx, red[i][le]);
    float den = 0.f, num = 0.f;
    for (int t = tg; t < nrow; t += 8) {
        if (ttl[t] == 1) continue;
        size_t idx = (size_t)(base + t) * E + e;
        float w = 1.f / (1.f + expf(-(w0[idx] + w1[idx] + w2[idx] + w3[idx])));
        float vval = tanhf(v0[idx] + v1[idx] + v2[idx] + v3[idx]);
        float ew = expf(w - mx);
        den += ew;
        num = fmaf(ew, vval, num);
    }
    __syncthreads();
    red[tg][le] = den;
    __syncthreads();
    float dtot = 0.f;
    #pragma unroll
    for (int i = 0; i < 8; ++i) dtot += red[i][le];
    __syncthreads();
    red[tg][le] = num;
    __syncthreads();
    float ntot = 0.f;
    #pragma unroll
    for (int i = 0; i < 8; ++i) ntot += red[i][le];
    if (tg == 0) out[(size_t)b * E + e] = fmaxf(ntot / dtot, 0.f);
}

// ---------------- host-side launch ----------------
extern "C" void kernel_launch(void* const* d_in, const int* in_sizes, int n_in,
                              void* d_out, int out_size, void* d_ws, size_t ws_size,
                              hipStream_t stream) {
    const int*   input_ids  = (const int*)d_in[0];
    const int*   token_type = (const int*)d_in[1];
    const int*   attn_mask  = (const int*)d_in[2];
    const float* word_emb   = (const float*)d_in[3];
    const float* pos_emb    = (const float*)d_in[4];
    const float* type_emb   = (const float*)d_in[5];
    const float* emb_ln_s   = (const float*)d_in[6];
    const float* emb_ln_b   = (const float*)d_in[7];
    const float* memory     = (const float*)d_in[8];
    const float* q_w  = (const float*)d_in[9];
    const float* q_b  = (const float*)d_in[10];
    const float* k_w  = (const float*)d_in[11];
    const float* k_b  = (const float*)d_in[12];
    const float* v_w  = (const float*)d_in[13];
    const float* v_b  = (const float*)d_in[14];
    const float* o_w  = (const float*)d_in[15];
    const float* o_b  = (const float*)d_in[16];
    const float* ln1_s = (const float*)d_in[17];
    const float* ln1_b = (const float*)d_in[18];
    const float* f_w1  = (const float*)d_in[19];
    const float* f_b1  = (const float*)d_in[20];
    const float* f_w2  = (const float*)d_in[21];
    const float* f_b2  = (const float*)d_in[22];
    const float* ln2_s = (const float*)d_in[23];
    const float* ln2_b = (const float*)d_in[24];
    const float* key_w1 = (const float*)d_in[25];
    const float* key_b1 = (const float*)d_in[26];
    const float* key_w2 = (const float*)d_in[27];
    const float* key_b2 = (const float*)d_in[28];
    const float* val_w1 = (const float*)d_in[29];
    const float* val_b1 = (const float*)d_in[30];
    const float* val_w2 = (const float*)d_in[31];
    const float* val_b2 = (const float*)d_in[32];
    float* out = (float*)d_out;

    char* ws = (char*)d_ws;
    size_t off = 0;
    auto alloc = [&](size_t bytes) {
        void* p = ws + off;
        off += (bytes + 255) & ~(size_t)255;
        return p;
    };
    const size_t BT  = (size_t)B * T;      // 4608 (worst-case rows)
    const size_t BTH = BT * H;

    int*   ord   = (int*)alloc((size_t)B * S * 4);
    int*   Larr  = (int*)alloc(64);
    int*   boff  = (int*)alloc((B + 1) * 4);
    int*   rowb  = (int*)alloc(BT * 4);
    int*   ttarr = (int*)alloc(BT * 4);
    float* x     = (float*)alloc(BTH * 4);
    unsigned short* xb   = (unsigned short*)alloc(BTH * 2);
    unsigned short* reg1 = (unsigned short*)alloc(BT * FF * 2);
    float* P0 = (float*)alloc(BTH * 4);
    float* P1 = (float*)alloc(BTH * 4);
    float* P2 = (float*)alloc(BTH * 4);
    float* P3 = (float*)alloc(BTH * 4);
    float* V0 = (float*)alloc(BT * E * 4);
    float* V1 = (float*)alloc(BT * E * 4);
    float* V2 = (float*)alloc(BT * E * 4);
    float* V3 = (float*)alloc(BT * E * 4);
    unsigned short* wt = (unsigned short*)alloc((size_t)17432576 * 2);

    unsigned short* qkb  = reg1;                       // [BT][1536]
    unsigned short* Vtb  = reg1 + BT * 1536;           // [B][NH][DH][T]
    unsigned short* ctxb = reg1 + BT * 1536 + BTH;     // [BT][H]
    unsigned short* hb   = reg1;                       // [BT][FF] (FFN phase)
    unsigned short* key1b = reg1;                      // [BT][1536] (head phase)
    unsigned short* val1b = reg1 + BT * 1536;          // [BT][1024]

    unsigned short* wt_head = wt + (size_t)14155776;
    unsigned short* wt_kv1 = wt_head;                       // [2560][768]
    unsigned short* wt_k2 = wt_head + (size_t)2560 * 768;   // [512][1536]
    unsigned short* wt_v2 = wt_k2 + (size_t)512 * 1536;     // [512][1024]

    const int Mrows = (int)BT;
    const size_t HH = (size_t)H * H;
    const int BIG = 1 << 30;
    const int* mtotp = boff + B;

    // one upfront launch: ALL weight transposes + mask order scans
    {
        TTab tab;
        tab.n = 16;
        for (int l = 0; l < NL; ++l) {
            unsigned base = (unsigned)(l * 7077888);
            int t0 = l * 6912;
            tab.d[l * 6 + 0] = { q_w + l * HH,              base,                        H,  H,  t0        };
            tab.d[l * 6 + 1] = { k_w + l * HH,              base + 768u * 768u,          H,  H,  t0 + 576  };
            tab.d[l * 6 + 2] = { v_w + l * HH,              base + 1536u * 768u,         H,  H,  t0 + 1152 };
            tab.d[l * 6 + 3] = { o_w + l * HH,              base + 2304u * 768u,         H,  H,  t0 + 1728 };
            tab.d[l * 6 + 4] = { f_w1 + (size_t)l * H * FF, base + 3072u * 768u,         H,  FF, t0 + 2304 };
            tab.d[l * 6 + 5] = { f_w2 + (size_t)l * FF * H, base + 6144u * 768u,         FF, H,  t0 + 4608 };
        }
        tab.d[12] = { key_w1, 14155776u,                    H,     2 * H, 13824 };
        tab.d[13] = { val_w1, 14155776u + 1536u * 768u,     H,     2 * E, 14976 };
        tab.d[14] = { key_w2, 16121856u,                    2 * H, E,     15744 };
        tab.d[15] = { val_w2, 16908288u,                    2 * E, E,     16512 };
        hipLaunchKernelGGL(transpose_all, dim3(NT_TILES + B), dim3(256), 0, stream,
                           tab, wt, attn_mask, ord, Larr);
    }

    hipLaunchKernelGGL(embed_kernel, dim3(T, B), dim3(256), 0, stream,
                       input_ids, token_type, ord, Larr, boff, rowb,
                       word_emb, pos_emb, type_emb,
                       memory, emb_ln_s, emb_ln_b, x, xb, ttarr);

    for (int l = 0; l < NL; ++l) {
        unsigned short* wt_l   = wt + (size_t)l * 7077888;
        unsigned short* wt_qkv = wt_l;
        unsigned short* wt_o   = wt_l + (size_t)2304 * 768;
        unsigned short* wt_f1  = wt_o + (size_t)768 * 768;
        unsigned short* wt_f2  = wt_f1 + (size_t)3072 * 768;

        mfma_gemm<ACT_NONE, EPI_QKV, 1><<<dim3(18, 36), 256, 0, stream>>>(
            xb, wt_qkv, q_b + (size_t)l * H, k_b + (size_t)l * H, v_b + (size_t)l * H,
            768, 1536, nullptr, nullptr, nullptr, nullptr, qkb, nullptr, Vtb, 0,
            boff, rowb, Mrows, 2304, H);
        hipLaunchKernelGGL(attn_mfma, dim3(864), dim3(256), 0, stream,
                           qkb, Vtb, Larr, boff, ctxb);
        mfma_gemm<ACT_NONE, EPI_F32, 4><<<dim3(6, 36, 4), 256, 0, stream>>>(
            ctxb, wt_o, o_b + (size_t)l * H, nullptr, nullptr, BIG, BIG,
            P0, P1, P2, P3, nullptr, nullptr, nullptr, 0, boff, rowb, Mrows, H, H);
        hipLaunchKernelGGL(lnres_kernel, dim3((int)BT), dim3(256), 0, stream,
                           x, P0, P1, P2, P3, ln1_s + (size_t)l * H, ln1_b + (size_t)l * H,
                           xb, mtotp);
        mfma_gemm<ACT_GELU, EPI_BF16, 1><<<dim3(24, 36), 256, 0, stream>>>(
            xb, wt_f1, f_b1 + (size_t)l * FF, nullptr, nullptr, BIG, BIG,
            nullptr, nullptr, nullptr, nullptr, hb, nullptr, nullptr, 0,
            boff, rowb, Mrows, FF, H);
        mfma_gemm<ACT_NONE, EPI_F32, 4><<<dim3(6, 36, 4), 256, 0, stream>>>(
            hb, wt_f2, f_b2 + (size_t)l * H, nullptr, nullptr, BIG, BIG,
            P0, P1, P2, P3, nullptr, nullptr, nullptr, 0, boff, rowb, Mrows, H, FF);
        hipLaunchKernelGGL(lnres_kernel, dim3((int)BT), dim3(256), 0, stream,
                           x, P0, P1, P2, P3, ln2_s + (size_t)l * H, ln2_b + (size_t)l * H,
                           xb, mtotp);
    }

    // fused key1|val1 GEMM: N=2560, split epilogue
    mfma_gemm<ACT_RELU, EPI_SPLIT2, 1><<<dim3(20, 36), 256, 0, stream>>>(
        xb, wt_kv1, key_b1, val_b1, nullptr, 1536, BIG,
        nullptr, nullptr, nullptr, nullptr, key1b, val1b, nullptr, 1024,
        boff, rowb, Mrows, 2560, H);
    // combined key2 || val2 (one dispatch, 8 z-planes)
    head2_gemm<<<dim3(4, 36, 8), 256, 0, stream>>>(
        key1b, wt_k2, key_b2, val1b, wt_v2, val_b2,
        P0, P1, P2, P3, V0, V1, V2, V3, boff);
    hipLaunchKernelGGL(pool_kernel, dim3(B, E / 32), dim3(256), 0, stream,
                       P0, P1, P2, P3, V0, V1, V2, V3, ttarr, boff, out);
}